// Round 7
// baseline (385.018 us; speedup 1.0000x reference)
//
#include <hip/hip_runtime.h>
#include <hip/hip_fp16.h>
#include <math.h>

#define N 4096
#define C 512
#define H 128
#define PAD 40  // ushort row pitch for 32-col MFMA LDS staging tiles
#define WP 136  // ushort row pitch for full-K (128 col) LDS tiles
#define FWP 136 // ushort row pitch for flash Q/P tiles
#define SP 136  // ushort row pitch for S-tile scan buffer (272 B, 16B-aligned)

typedef __attribute__((ext_vector_type(8))) short bf16x8;
typedef __attribute__((ext_vector_type(4))) float f32x4;

// ---------------- helpers ----------------

__device__ inline float wave_reduce_sum(float v) {
#pragma unroll
  for (int m = 32; m; m >>= 1) v += __shfl_xor(v, m);
  return v;
}

__device__ inline float lrelu(float v) { return v > 0.f ? v : 0.01f * v; }

__device__ inline bool better(float v, int j, float w, int k) {
  return (v > w) || (v == w && j < k);
}

__device__ inline void top3_ins(float v, int j, float& v0, int& j0,
                                float& v1, int& j1, float& v2, int& j2) {
  if (better(v, j, v0, j0)) { v2 = v1; j2 = j1; v1 = v0; j1 = j0; v0 = v; j0 = j; }
  else if (better(v, j, v1, j1)) { v2 = v1; j2 = j1; v1 = v; j1 = j; }
  else if (better(v, j, v2, j2)) { v2 = v; j2 = j; }
}

__device__ inline void ins5(float s, int j, float v[5], int jx[5]) {
  if (!better(s, j, v[4], jx[4])) return;
  if (better(s, j, v[0], jx[0])) {
    v[4]=v[3]; jx[4]=jx[3]; v[3]=v[2]; jx[3]=jx[2]; v[2]=v[1]; jx[2]=jx[1];
    v[1]=v[0]; jx[1]=jx[0]; v[0]=s; jx[0]=j;
  } else if (better(s, j, v[1], jx[1])) {
    v[4]=v[3]; jx[4]=jx[3]; v[3]=v[2]; jx[3]=jx[2]; v[2]=v[1]; jx[2]=jx[1];
    v[1]=s; jx[1]=j;
  } else if (better(s, j, v[2], jx[2])) {
    v[4]=v[3]; jx[4]=jx[3]; v[3]=v[2]; jx[3]=jx[2]; v[2]=s; jx[2]=j;
  } else if (better(s, j, v[3], jx[3])) {
    v[4]=v[3]; jx[4]=jx[3]; v[3]=s; jx[3]=j;
  } else {
    v[4]=s; jx[4]=j;
  }
}

__device__ inline unsigned short f2bf(float f) {
  unsigned u = __float_as_uint(f);
  unsigned r = u + 0x7fffu + ((u >> 16) & 1u);
  return (unsigned short)(r >> 16);
}
__device__ inline float bf2f(unsigned short h) {
  return __uint_as_float(((unsigned)h) << 16);
}

// ---------------- split fp32 -> bf16 hi/lo (+ row norms of x) ----------------
__global__ __launch_bounds__(256) void k_split(const float* __restrict__ in,
                                               unsigned short* __restrict__ hi,
                                               unsigned short* __restrict__ lo,
                                               float* __restrict__ nrm) {
  int t = threadIdx.x;
  int idx = (blockIdx.x * 256 + t) * 4;
  float4 v = *(const float4*)&in[idx];
  float vv[4] = {v.x, v.y, v.z, v.w};
  unsigned short h[4], l[4];
  float ss = 0.f;
#pragma unroll
  for (int c = 0; c < 4; c++) {
    ss += vv[c] * vv[c];
    h[c] = f2bf(vv[c]);
    l[c] = f2bf(vv[c] - bf2f(h[c]));
  }
  uint2 ph = {(unsigned)h[0] | ((unsigned)h[1] << 16),
              (unsigned)h[2] | ((unsigned)h[3] << 16)};
  uint2 pl = {(unsigned)l[0] | ((unsigned)l[1] << 16),
              (unsigned)l[2] | ((unsigned)l[3] << 16)};
  *(uint2*)&hi[idx] = ph;
  *(uint2*)&lo[idx] = pl;
  if (nrm) {
#pragma unroll
    for (int m = 16; m; m >>= 1) ss += __shfl_xor(ss, m);  // 32-lane row group
    if ((t & 31) == 0) nrm[idx >> 7] = sqrtf(ss);
  }
}

// transpose + split: in [R,128] fp32 -> thi/tlo [128,R] ushort
__global__ __launch_bounds__(256) void k_tsplit(const float* __restrict__ in,
                                                unsigned short* __restrict__ thi,
                                                unsigned short* __restrict__ tlo,
                                                int R) {
  __shared__ float tile[32][132];
  int r0 = blockIdx.x * 32, tid = threadIdx.x;
#pragma unroll
  for (int q = 0; q < 4; q++) {
    int f = q * 256 + tid;
    int row = f >> 5, ch = f & 31;
    *(float4*)&tile[row][ch * 4] = *(const float4*)&in[(size_t)(r0 + row) * 128 + ch * 4];
  }
  __syncthreads();
  int c = tid & 127, half = tid >> 7;
  unsigned short hh[16], ll[16];
#pragma unroll
  for (int rr = 0; rr < 16; rr++) {
    float v = tile[half * 16 + rr][c];
    hh[rr] = f2bf(v);
    ll[rr] = f2bf(v - bf2f(hh[rr]));
  }
  size_t off = (size_t)c * R + r0 + half * 16;
  uint4 ph0 = {(unsigned)hh[0] | ((unsigned)hh[1] << 16), (unsigned)hh[2] | ((unsigned)hh[3] << 16),
               (unsigned)hh[4] | ((unsigned)hh[5] << 16), (unsigned)hh[6] | ((unsigned)hh[7] << 16)};
  uint4 ph1 = {(unsigned)hh[8] | ((unsigned)hh[9] << 16), (unsigned)hh[10] | ((unsigned)hh[11] << 16),
               (unsigned)hh[12] | ((unsigned)hh[13] << 16), (unsigned)hh[14] | ((unsigned)hh[15] << 16)};
  uint4 pl0 = {(unsigned)ll[0] | ((unsigned)ll[1] << 16), (unsigned)ll[2] | ((unsigned)ll[3] << 16),
               (unsigned)ll[4] | ((unsigned)ll[5] << 16), (unsigned)ll[6] | ((unsigned)ll[7] << 16)};
  uint4 pl1 = {(unsigned)ll[8] | ((unsigned)ll[9] << 16), (unsigned)ll[10] | ((unsigned)ll[11] << 16),
               (unsigned)ll[12] | ((unsigned)ll[13] << 16), (unsigned)ll[14] | ((unsigned)ll[15] << 16)};
  *(uint4*)&thi[off] = ph0; *(uint4*)&thi[off + 8] = ph1;
  *(uint4*)&tlo[off] = pl0; *(uint4*)&tlo[off + 8] = pl1;
}

// ---------------- small kernels ----------------

__global__ __launch_bounds__(64) void k_colsum_s2c(
    const float* __restrict__ cm, const float* __restrict__ mv,
    float* __restrict__ colsum_c) {
  int c = blockIdx.x * 64 + threadIdx.x;
  int i0 = blockIdx.y * 256;
  float acc = 0.f;
  for (int i = i0; i < i0 + 256; i++) acc += cm[(size_t)i * C + c] * mv[i];
  atomicAdd(&colsum_c[c], acc);
}

__global__ __launch_bounds__(256) void k_colstats(const float* __restrict__ sc,
                                                  float* __restrict__ colmax,
                                                  float* __restrict__ colsum) {
  __shared__ float red[256];
  int c = blockIdx.x, t = threadIdx.x;
  float v[16];
  float m = -3e38f;
#pragma unroll
  for (int q = 0; q < 16; q++) {
    v[q] = sc[(size_t)(q * 256 + t) * C + c];
    m = fmaxf(m, v[q]);
  }
  red[t] = m; __syncthreads();
  for (int s = 128; s; s >>= 1) { if (t < s) red[t] = fmaxf(red[t], red[t + s]); __syncthreads(); }
  m = red[0]; __syncthreads();
  float sum = 0.f;
#pragma unroll
  for (int q = 0; q < 16; q++) sum += __expf(v[q] - m);
  red[t] = sum; __syncthreads();
  for (int s = 128; s; s >>= 1) { if (t < s) red[t] += red[t + s]; __syncthreads(); }
  if (t == 0) { colmax[c] = m; colsum[c] = red[0]; }
}

// row softmax of cos-sim -> bf16 hi/lo pairs
__global__ __launch_bounds__(256) void k_cs_softmax(
    const float* __restrict__ sc, const float* __restrict__ xnorm,
    const float* __restrict__ hnorm, const float* __restrict__ valid1,
    unsigned short* __restrict__ cshi, unsigned short* __restrict__ cslo) {
  __shared__ float red[256];
  int i = blockIdx.x, t = threadIdx.x;
  float xn = xnorm[i];
  float r0 = sc[(size_t)i * C + t], r1 = sc[(size_t)i * C + 256 + t];
  float d0 = xn * hnorm[t], d1 = xn * hnorm[256 + t];
  float c0 = r0 / (d0 == 0.f ? 1.f : d0);
  float c1 = r1 / (d1 == 0.f ? 1.f : d1);
  float s0 = (valid1[t] != 0.f) ? c0 : -3e38f;
  float s1 = (valid1[256 + t] != 0.f) ? c1 : -3e38f;
  red[t] = fmaxf(s0, s1); __syncthreads();
  for (int s = 128; s; s >>= 1) { if (t < s) red[t] = fmaxf(red[t], red[t + s]); __syncthreads(); }
  float m = red[0]; __syncthreads();
  float p0 = (s0 > -1e37f) ? __expf(s0 - m) : 0.f;
  float p1 = (s1 > -1e37f) ? __expf(s1 - m) : 0.f;
  red[t] = p0 + p1; __syncthreads();
  for (int s = 128; s; s >>= 1) { if (t < s) red[t] += red[t + s]; __syncthreads(); }
  float inv = 1.f / red[0];
  float a = p0 * inv, b = p1 * inv;
  unsigned short ha = f2bf(a), hb = f2bf(b);
  cshi[(size_t)i * C + t] = ha;
  cslo[(size_t)i * C + t] = f2bf(a - bf2f(ha));
  cshi[(size_t)i * C + 256 + t] = hb;
  cslo[(size_t)i * C + 256 + t] = f2bf(b - bf2f(hb));
}

// finalize hidden2 + h2hat pairs + valid2f
__global__ __launch_bounds__(64) void k_fin_hidden2(
    const float* __restrict__ h, const float* __restrict__ diagv,
    const float* __restrict__ colsum_m, float* __restrict__ hidden2,
    unsigned short* __restrict__ h2hi, unsigned short* __restrict__ h2lo,
    float* __restrict__ valid2f) {
  int j = blockIdx.x, t = threadIdx.x;
  float add = (colsum_m[j] != 0.f) ? diagv[j] : 0.f;
  float a = hidden2[(size_t)j * H + t] + add * h[(size_t)j * H + t];
  float b = hidden2[(size_t)j * H + 64 + t] + add * h[(size_t)j * H + 64 + t];
  float s = a + b, ss = a * a + b * b;
#pragma unroll
  for (int m = 32; m; m >>= 1) { s += __shfl_xor(s, m); ss += __shfl_xor(ss, m); }
  bool valid = (s != 0.f);
  a = valid ? a : 0.f; b = valid ? b : 0.f;
  hidden2[(size_t)j * H + t] = a;
  hidden2[(size_t)j * H + 64 + t] = b;
  float inv = (valid && ss > 0.f) ? (1.f / sqrtf(ss)) : 1.f;
  float va = a * inv, vb = b * inv;
  unsigned short ha = f2bf(va), hb = f2bf(vb);
  h2hi[(size_t)j * H + t] = ha;
  h2lo[(size_t)j * H + t] = f2bf(va - bf2f(ha));
  h2hi[(size_t)j * H + 64 + t] = hb;
  h2lo[(size_t)j * H + 64 + t] = f2bf(vb - bf2f(hb));
  if (t == 0) valid2f[j] = valid ? 1.f : 0.f;
}

// ---------------- bf16x3 MFMA NT GEMM: A[64,128] @ B[128,128]^T, fp32 out ----
// 64-row tiles so grid (C/128, N/64) = 256 blocks fills all CUs.
__global__ __launch_bounds__(256) void k_mfma_nt(
    const unsigned short* __restrict__ Ahi, const unsigned short* __restrict__ Alo,
    const unsigned short* __restrict__ Bhi, const unsigned short* __restrict__ Blo,
    float* __restrict__ out, int Nn) {
  __shared__ __align__(16) unsigned short sAh[64 * PAD];
  __shared__ __align__(16) unsigned short sAl[64 * PAD];
  __shared__ __align__(16) unsigned short sBh[128 * PAD];
  __shared__ __align__(16) unsigned short sBl[128 * PAD];
  int tid = threadIdx.x;
  int bm = blockIdx.y * 64, bn = blockIdx.x * 128;
  int lane = tid & 63, w = tid >> 6;
  int wm = (w & 1) * 32, wn = (w >> 1) * 64;
  int l15 = lane & 15, quad = lane >> 4;
  f32x4 zero = {0.f, 0.f, 0.f, 0.f};
  f32x4 acc[2][4];
#pragma unroll
  for (int mt = 0; mt < 2; mt++)
#pragma unroll
    for (int nt = 0; nt < 4; nt++) acc[mt][nt] = zero;

  for (int kt = 0; kt < 128; kt += 32) {
    {
      int row = tid >> 2, ch = tid & 3;  // A: 64 rows x 4 chunks
      size_t ga = (size_t)(bm + row) * 128 + kt + ch * 8;
      int ls = row * PAD + ch * 8;
      *(uint4*)&sAh[ls] = *(const uint4*)&Ahi[ga];
      *(uint4*)&sAl[ls] = *(const uint4*)&Alo[ga];
    }
#pragma unroll
    for (int q = 0; q < 2; q++) {     // B: 128 rows x 4 chunks
      int f = q * 256 + tid;
      int row = f >> 2, ch = f & 3;
      size_t gb = (size_t)(bn + row) * 128 + kt + ch * 8;
      int ls = row * PAD + ch * 8;
      *(uint4*)&sBh[ls] = *(const uint4*)&Bhi[gb];
      *(uint4*)&sBl[ls] = *(const uint4*)&Blo[gb];
    }
    __syncthreads();
    bf16x8 ah[2], al[2], bh[4], bl[4];
#pragma unroll
    for (int t = 0; t < 2; t++) {
      int ar = (wm + t * 16 + l15) * PAD + quad * 8;
      ah[t] = *(const bf16x8*)&sAh[ar];
      al[t] = *(const bf16x8*)&sAl[ar];
    }
#pragma unroll
    for (int t = 0; t < 4; t++) {
      int br = (wn + t * 16 + l15) * PAD + quad * 8;
      bh[t] = *(const bf16x8*)&sBh[br];
      bl[t] = *(const bf16x8*)&sBl[br];
    }
#pragma unroll
    for (int mt = 0; mt < 2; mt++)
#pragma unroll
      for (int nt = 0; nt < 4; nt++) {
        acc[mt][nt] = __builtin_amdgcn_mfma_f32_16x16x32_bf16(ah[mt], bh[nt], acc[mt][nt], 0, 0, 0);
        acc[mt][nt] = __builtin_amdgcn_mfma_f32_16x16x32_bf16(ah[mt], bl[nt], acc[mt][nt], 0, 0, 0);
        acc[mt][nt] = __builtin_amdgcn_mfma_f32_16x16x32_bf16(al[mt], bh[nt], acc[mt][nt], 0, 0, 0);
      }
    __syncthreads();
  }
#pragma unroll
  for (int mt = 0; mt < 2; mt++) {
#pragma unroll
    for (int nt = 0; nt < 4; nt++) {
      int col = bn + wn + nt * 16 + l15;
#pragma unroll
      for (int rg = 0; rg < 4; rg++) {
        int row = bm + wm + mt * 16 + quad * 4 + rg;
        out[(size_t)row * Nn + col] = acc[mt][nt][rg];
      }
    }
  }
}

// ---------------- S = hhat@hhat^T + fused quarter-row top-5 screen -----------
// 512 threads = 8 waves (4 row-bands x 2 col-halves). S-tile dumped to LDS
// fp16 (diag 0); each thread serially scans a 32-col quarter-row -> cand.
__global__ __launch_bounds__(512) void k_snt(
    const unsigned short* __restrict__ Ahi, const unsigned short* __restrict__ Alo,
    float2* __restrict__ cand) {
  __shared__ __align__(16) unsigned short sAh[128 * PAD];
  __shared__ __align__(16) unsigned short sAl[128 * PAD];
  __shared__ __align__(16) unsigned short sBh[128 * PAD];
  __shared__ __align__(16) unsigned short sBl[128 * PAD];
  __shared__ __align__(16) unsigned short sS[128 * SP];
  int tid = threadIdx.x;
  int bm = blockIdx.y * 128, bn = blockIdx.x * 128;
  int lane = tid & 63, w = tid >> 6;
  int wm = (w & 3) * 32, wn = (w >> 2) * 64;
  int l15 = lane & 15, quad = lane >> 4;
  f32x4 zero = {0.f, 0.f, 0.f, 0.f};
  f32x4 acc[2][4];
#pragma unroll
  for (int mt = 0; mt < 2; mt++)
#pragma unroll
    for (int nt = 0; nt < 4; nt++) acc[mt][nt] = zero;

  for (int kt = 0; kt < 128; kt += 32) {
    {
      int row = tid >> 2, ch = tid & 3;
      size_t ga = (size_t)(bm + row) * 128 + kt + ch * 8;
      size_t gb = (size_t)(bn + row) * 128 + kt + ch * 8;
      int ls = row * PAD + ch * 8;
      *(uint4*)&sAh[ls] = *(const uint4*)&Ahi[ga];
      *(uint4*)&sAl[ls] = *(const uint4*)&Alo[ga];
      *(uint4*)&sBh[ls] = *(const uint4*)&Ahi[gb];
      *(uint4*)&sBl[ls] = *(const uint4*)&Alo[gb];
    }
    __syncthreads();
    bf16x8 ah[2], al[2], bh[4], bl[4];
#pragma unroll
    for (int t = 0; t < 2; t++) {
      int ar = (wm + t * 16 + l15) * PAD + quad * 8;
      ah[t] = *(const bf16x8*)&sAh[ar];
      al[t] = *(const bf16x8*)&sAl[ar];
    }
#pragma unroll
    for (int t = 0; t < 4; t++) {
      int br = (wn + t * 16 + l15) * PAD + quad * 8;
      bh[t] = *(const bf16x8*)&sBh[br];
      bl[t] = *(const bf16x8*)&sBl[br];
    }
#pragma unroll
    for (int mt = 0; mt < 2; mt++)
#pragma unroll
      for (int nt = 0; nt < 4; nt++) {
        acc[mt][nt] = __builtin_amdgcn_mfma_f32_16x16x32_bf16(ah[mt], bh[nt], acc[mt][nt], 0, 0, 0);
        acc[mt][nt] = __builtin_amdgcn_mfma_f32_16x16x32_bf16(ah[mt], bl[nt], acc[mt][nt], 0, 0, 0);
        acc[mt][nt] = __builtin_amdgcn_mfma_f32_16x16x32_bf16(al[mt], bh[nt], acc[mt][nt], 0, 0, 0);
      }
    __syncthreads();
  }
  // dump S tile as fp16 (diag zeroed)
#pragma unroll
  for (int mt = 0; mt < 2; mt++)
#pragma unroll
    for (int nt = 0; nt < 4; nt++) {
      int coll = wn + nt * 16 + l15;
#pragma unroll
      for (int rg = 0; rg < 4; rg++) {
        int rowl = wm + mt * 16 + quad * 4 + rg;
        float v = (bm + rowl == bn + coll) ? 0.f : acc[mt][nt][rg];
        sS[rowl * SP + coll] = __half_as_ushort(__float2half(v));
      }
    }
  __syncthreads();
  // serial top-5 scan: thread handles quarter-row (r = tid>>2, qf = tid&3)
  int r = tid >> 2, qf = tid & 3;
  const unsigned short* rowp = &sS[r * SP + qf * 32];
  int cbase = bn + qf * 32;
  float v5[5] = {-3e38f, -3e38f, -3e38f, -3e38f, -3e38f};
  int j5[5] = {0x7fffffff, 0x7fffffff, 0x7fffffff, 0x7fffffff, 0x7fffffff};
#pragma unroll
  for (int q = 0; q < 4; q++) {
    uint4 p = *(const uint4*)&rowp[q * 8];
    unsigned pk[4] = {p.x, p.y, p.z, p.w};
#pragma unroll
    for (int c2 = 0; c2 < 4; c2++) {
      float e0 = __half2float(__ushort_as_half((unsigned short)(pk[c2] & 0xffffu)));
      float e1 = __half2float(__ushort_as_half((unsigned short)(pk[c2] >> 16)));
      ins5(e0, cbase + q * 8 + c2 * 2, v5, j5);
      ins5(e1, cbase + q * 8 + c2 * 2 + 1, v5, j5);
    }
  }
  int slot = (bn >> 5) + qf;
  float2* cp = &cand[((size_t)(bm + r) * 128 + slot) * 5];
#pragma unroll
  for (int c2 = 0; c2 < 5; c2++) cp[c2] = {v5[c2], __int_as_float(j5[c2])};
}

// ---------------- row top-k merge: candidates -> exact fp32 rescore ----------
__global__ __launch_bounds__(256) void k_rowtop2(
    const float2* __restrict__ cand, const float* __restrict__ hhat,
    float* __restrict__ mtv, int* __restrict__ mtj) {
  int i = blockIdx.x * 4 + (threadIdx.x >> 6);
  int lane = threadIdx.x & 63;
  const float2* cr = &cand[(size_t)i * 640];
  float v[5] = {-3e38f, -3e38f, -3e38f, -3e38f, -3e38f};
  int jx[5] = {0x7fffffff, 0x7fffffff, 0x7fffffff, 0x7fffffff, 0x7fffffff};
#pragma unroll
  for (int c = 0; c < 10; c++) {
    float2 p = cr[lane * 10 + c];
    ins5(p.x, __float_as_int(p.y), v, jx);
  }
#pragma unroll
  for (int d = 1; d < 64; d <<= 1) {
    float fv[5]; int fj[5];
#pragma unroll
    for (int c = 0; c < 5; c++) { fv[c] = __shfl_xor(v[c], d); fj[c] = __shfl_xor(jx[c], d); }
#pragma unroll
    for (int c = 0; c < 5; c++) ins5(fv[c], fj[c], v, jx);
  }
  const float* hi = &hhat[(size_t)i * H];
  float b0 = -3e38f, b1 = -3e38f, b2 = -3e38f;
  int q0 = 0, q1 = 0, q2 = 0;
#pragma unroll
  for (int c = 0; c < 5; c++) {
    int j = jx[c];
    float s;
    if (j == i) {
      s = 0.f;
    } else {
      const float* hj = &hhat[(size_t)j * H];
      float p = hi[lane] * hj[lane] + hi[lane + 64] * hj[lane + 64];
      s = wave_reduce_sum(p);
    }
    top3_ins(s, j, b0, q0, b1, q1, b2, q2);
  }
  if (lane == 0) {
    mtv[i * 3 + 0] = b0; mtv[i * 3 + 1] = b1; mtv[i * 3 + 2] = b2;
    mtj[i * 3 + 0] = q0; mtj[i * 3 + 1] = q1; mtj[i * 3 + 2] = q2;
  }
}

// ---------------- flash-fused hs_pre numerator: U[z] = E_z @ hidden2 ---------
// Q=hhat pairs [N,128]; K=h2hat pairs [N,128]; V=h2t pairs [128,N].
// 256 threads, bm-tile 64 (waves: wm=(w&1)*32, wn=(w>>1)*64). LDS ~71 KB ->
// 2 blocks/CU for cross-block barrier overlap. V read directly from global
// (L2-resident) so the PV loop has ZERO barriers. Per jb: QK (4x stage+2bar),
// exp epilogue -> sP + lsum (1 bar), PV (no bar; next jb's QK barriers protect
// sP reads since barriers require all waves to arrive).
__global__ __launch_bounds__(256) void k_flash(
    const unsigned short* __restrict__ Qhi, const unsigned short* __restrict__ Qlo,
    const unsigned short* __restrict__ Khi, const unsigned short* __restrict__ Klo,
    const unsigned short* __restrict__ Vthi, const unsigned short* __restrict__ Vtlo,
    const float* __restrict__ valid2f, float* __restrict__ partialU,
    float* __restrict__ plsum, int KVC) {
  __shared__ __align__(16) unsigned short sQh[64 * FWP];
  __shared__ __align__(16) unsigned short sQl[64 * FWP];
  __shared__ __align__(16) unsigned short sP[64 * FWP];
  __shared__ __align__(16) unsigned short sKh[128 * PAD];
  __shared__ __align__(16) unsigned short sKl[128 * PAD];
  __shared__ float lsum_s[64];
  int tid = threadIdx.x;
  int z = blockIdx.x;
  int bm = blockIdx.y * 64;
  int j0 = z * KVC;
  int lane = tid & 63, w = tid >> 6;
  int wm = (w & 1) * 32, wn = (w >> 1) * 64;
  int l15 = lane & 15, quad = lane >> 4;
  // stage Q tile (persistent) + zero lsum
#pragma unroll
  for (int q = 0; q < 4; q++) {
    int f = q * 256 + tid;
    int row = f >> 4, ch = f & 15;
    size_t ga = (size_t)(bm + row) * 128 + ch * 8;
    int ls = row * FWP + ch * 8;
    *(uint4*)&sQh[ls] = *(const uint4*)&Qhi[ga];
    *(uint4*)&sQl[ls] = *(const uint4*)&Qlo[ga];
  }
  if (tid < 64) lsum_s[tid] = 0.f;
  __syncthreads();
  f32x4 zero = {0.f, 0.f, 0.f, 0.f};
  f32x4 uacc[2][4];
#pragma unroll
  for (int mt = 0; mt < 2; mt++)
#pragma unroll
    for (int nt = 0; nt < 4; nt++) uacc[mt][nt] = zero;

  for (int jb = j0; jb < j0 + KVC; jb += 128) {
    float vm[4];
#pragma unroll
    for (int nt = 0; nt < 4; nt++) vm[nt] = valid2f[jb + wn + nt * 16 + l15];
    f32x4 qacc[2][4];
#pragma unroll
    for (int mt = 0; mt < 2; mt++)
#pragma unroll
      for (int nt = 0; nt < 4; nt++) qacc[mt][nt] = zero;
    // --- QK^T ---
    for (int kt = 0; kt < 128; kt += 32) {
#pragma unroll
      for (int q = 0; q < 2; q++) {
        int f = q * 256 + tid;
        int row = f >> 2, ch = f & 3;
        size_t gb = (size_t)(jb + row) * 128 + kt + ch * 8;
        int ls = row * PAD + ch * 8;
        *(uint4*)&sKh[ls] = *(const uint4*)&Khi[gb];
        *(uint4*)&sKl[ls] = *(const uint4*)&Klo[gb];
      }
      __syncthreads();
      bf16x8 ah[2], al[2], bh[4], bl[4];
#pragma unroll
      for (int t = 0; t < 2; t++) {
        int ar = (wm + t * 16 + l15) * FWP + kt + quad * 8;
        ah[t] = *(const bf16x8*)&sQh[ar];
        al[t] = *(const bf16x8*)&sQl[ar];
      }
#pragma unroll
      for (int t = 0; t < 4; t++) {
        int br = (wn + t * 16 + l15) * PAD + quad * 8;
        bh[t] = *(const bf16x8*)&sKh[br];
        bl[t] = *(const bf16x8*)&sKl[br];
      }
#pragma unroll
      for (int mt = 0; mt < 2; mt++)
#pragma unroll
        for (int nt = 0; nt < 4; nt++) {
          qacc[mt][nt] = __builtin_amdgcn_mfma_f32_16x16x32_bf16(ah[mt], bh[nt], qacc[mt][nt], 0, 0, 0);
          qacc[mt][nt] = __builtin_amdgcn_mfma_f32_16x16x32_bf16(ah[mt], bl[nt], qacc[mt][nt], 0, 0, 0);
          qacc[mt][nt] = __builtin_amdgcn_mfma_f32_16x16x32_bf16(al[mt], bh[nt], qacc[mt][nt], 0, 0, 0);
        }
      __syncthreads();
    }
    // --- exp epilogue: P to LDS + row sums ---
#pragma unroll
    for (int mt = 0; mt < 2; mt++) {
#pragma unroll
      for (int rg = 0; rg < 4; rg++) {
        int row = wm + mt * 16 + quad * 4 + rg;
        float rs = 0.f;
#pragma unroll
        for (int nt = 0; nt < 4; nt++) {
          float e = (vm[nt] != 0.f) ? __expf(qacc[mt][nt][rg] - 1.f) : 0.f;
          rs += e;
          sP[row * FWP + wn + nt * 16 + l15] = f2bf(e);
        }
#pragma unroll
        for (int d = 1; d < 16; d <<= 1) rs += __shfl_xor(rs, d);
        if (l15 == 0) atomicAdd(&lsum_s[row], rs);
      }
    }
    __syncthreads();
    // --- PV: P from LDS, V direct from global; no barriers ---
    for (int kt = 0; kt < 128; kt += 32) {
      bf16x8 pa[2], vh[4], vl[4];
#pragma unroll
      for (int t = 0; t < 2; t++) {
        int ar = (wm + t * 16 + l15) * FWP + kt + quad * 8;
        pa[t] = *(const bf16x8*)&sP[ar];
      }
#pragma unroll
      for (int t = 0; t < 4; t++) {
        size_t gv = (size_t)(wn + t * 16 + l15) * N + jb + kt + quad * 8;
        vh[t] = *(const bf16x8*)&Vthi[gv];
        vl[t] = *(const bf16x8*)&Vtlo[gv];
      }
#pragma unroll
      for (int mt = 0; mt < 2; mt++)
#pragma unroll
        for (int nt = 0; nt < 4; nt++) {
          uacc[mt][nt] = __builtin_amdgcn_mfma_f32_16x16x32_bf16(pa[mt], vh[nt], uacc[mt][nt], 0, 0, 0);
          uacc[mt][nt] = __builtin_amdgcn_mfma_f32_16x16x32_bf16(pa[mt], vl[nt], uacc[mt][nt], 0, 0, 0);
        }
    }
  }
  // --- write partials ---
  float* pU = partialU + (size_t)z * N * 128;
#pragma unroll
  for (int mt = 0; mt < 2; mt++)
#pragma unroll
    for (int nt = 0; nt < 4; nt++) {
      int col = wn + nt * 16 + l15;
#pragma unroll
      for (int rg = 0; rg < 4; rg++) {
        int row = bm + wm + mt * 16 + quad * 4 + rg;
        pU[(size_t)row * 128 + col] = uacc[mt][nt][rg];
      }
    }
  __syncthreads();
  if (tid < 64) plsum[(size_t)z * N + bm + tid] = lsum_s[tid];
}

// ---------------- bf16 MFMA KN GEMM (split-K): partial[z] = A @ B ------------
__global__ __launch_bounds__(256) void k_mfma_kn(
    const unsigned short* __restrict__ Ahi, const unsigned short* __restrict__ Alo,
    const unsigned short* __restrict__ Bthi, const unsigned short* __restrict__ Btlo,
    float* __restrict__ partial, int lda, int KC) {
  __shared__ __align__(16) unsigned short sAh[128 * PAD];
  __shared__ __align__(16) unsigned short sAl[128 * PAD];
  __shared__ __align__(16) unsigned short sBh[128 * PAD];
  __shared__ __align__(16) unsigned short sBl[128 * PAD];
  int tid = threadIdx.x;
  int bm = blockIdx.y * 128;
  int k0 = blockIdx.z * KC;
  int lane = tid & 63, w = tid >> 6;
  int wm = (w & 1) * 64, wn = (w >> 1) * 64;
  int l15 = lane & 15, quad = lane >> 4;
  f32x4 zero = {0.f, 0.f, 0.f, 0.f};
  f32x4 acc[4][4];
#pragma unroll
  for (int mt = 0; mt < 4; mt++)
#pragma unroll
    for (int nt = 0; nt < 4; nt++) acc[mt][nt] = zero;

  for (int kt = 0; kt < KC; kt += 32) {
#pragma unroll
    for (int q = 0; q < 2; q++) {
      int f = tid * 2 + q;
      int row = f >> 2, ch = f & 3;
      size_t ga = (size_t)(bm + row) * lda + k0 + kt + ch * 8;
      size_t gb = (size_t)row * lda + k0 + kt + ch * 8;
      int ls = row * PAD + ch * 8;
      *(uint4*)&sAh[ls] = *(const uint4*)&Ahi[ga];
      *(uint4*)&sAl[ls] = *(const uint4*)&Alo[ga];
      *(uint4*)&sBh[ls] = *(const uint4*)&Bthi[gb];
      *(uint4*)&sBl[ls] = *(const uint4*)&Btlo[gb];
    }
    __syncthreads();
    bf16x8 ah[4], al[4], bh[4], bl[4];
#pragma unroll
    for (int t = 0; t < 4; t++) {
      int ar = (wm + t * 16 + l15) * PAD + quad * 8;
      ah[t] = *(const bf16x8*)&sAh[ar];
      al[t] = *(const bf16x8*)&sAl[ar];
      int br = (wn + t * 16 + l15) * PAD + quad * 8;
      bh[t] = *(const bf16x8*)&sBh[br];
      bl[t] = *(const bf16x8*)&sBl[br];
    }
#pragma unroll
    for (int mt = 0; mt < 4; mt++)
#pragma unroll
      for (int nt = 0; nt < 4; nt++) {
        acc[mt][nt] = __builtin_amdgcn_mfma_f32_16x16x32_bf16(ah[mt], bh[nt], acc[mt][nt], 0, 0, 0);
        acc[mt][nt] = __builtin_amdgcn_mfma_f32_16x16x32_bf16(ah[mt], bl[nt], acc[mt][nt], 0, 0, 0);
        acc[mt][nt] = __builtin_amdgcn_mfma_f32_16x16x32_bf16(al[mt], bh[nt], acc[mt][nt], 0, 0, 0);
      }
    __syncthreads();
  }
  float* pp = partial + (size_t)blockIdx.z * N * 128;
#pragma unroll
  for (int mt = 0; mt < 4; mt++)
#pragma unroll
    for (int nt = 0; nt < 4; nt++) {
      int col = wn + nt * 16 + l15;
#pragma unroll
      for (int rg = 0; rg < 4; rg++) {
        int row = bm + wm + mt * 16 + quad * 4 + rg;
        pp[(size_t)row * 128 + col] = acc[mt][nt][rg];
      }
    }
}

// ---------------- bf16x3 MFMA genA GEMM (split-K) ----------------
template <int AMODE>
__global__ __launch_bounds__(256) void k_mfma_genA(
    const float* __restrict__ P, const float* __restrict__ mv,
    const float* __restrict__ col1, const float* __restrict__ col2,
    const unsigned short* __restrict__ Bthi, const unsigned short* __restrict__ Btlo,
    float* __restrict__ partial, int KC) {
  __shared__ __align__(16) unsigned short sAh[128 * PAD];
  __shared__ __align__(16) unsigned short sAl[128 * PAD];
  __shared__ __align__(16) unsigned short sBh[128 * PAD];
  __shared__ __align__(16) unsigned short sBl[128 * PAD];
  int tid = threadIdx.x;
  int bm = blockIdx.y * 128;
  int k0 = blockIdx.z * KC;
  int lane = tid & 63, w = tid >> 6;
  int wm = (w & 1) * 64, wn = (w >> 1) * 64;
  int l15 = lane & 15, quad = lane >> 4;
  f32x4 zero = {0.f, 0.f, 0.f, 0.f};
  f32x4 acc[4][4];
#pragma unroll
  for (int mt = 0; mt < 4; mt++)
#pragma unroll
    for (int nt = 0; nt < 4; nt++) acc[mt][nt] = zero;

  for (int kt = 0; kt < KC; kt += 32) {
    int kr = tid >> 3;
    int mc = (tid & 7) * 16;
    int k = k0 + kt + kr;
    float mvk = (AMODE == 1) ? mv[k] : 0.f;
#pragma unroll
    for (int q = 0; q < 4; q++) {
      int m0 = mc + q * 4;
      float4 pv = *(const float4*)&P[(size_t)k * C + bm + m0];
      float4 c1 = *(const float4*)&col1[bm + m0];
      float wv[4];
      if (AMODE == 1) {
        wv[0] = pv.x * mvk / (c1.x * pv.x + 1.f);
        wv[1] = pv.y * mvk / (c1.y * pv.y + 1.f);
        wv[2] = pv.z * mvk / (c1.z * pv.z + 1.f);
        wv[3] = pv.w * mvk / (c1.w * pv.w + 1.f);
      } else {
        float4 c2 = *(const float4*)&col2[bm + m0];
        wv[0] = __expf(pv.x - c1.x) / c2.x;
        wv[1] = __expf(pv.y - c1.y) / c2.y;
        wv[2] = __expf(pv.z - c1.z) / c2.z;
        wv[3] = __expf(pv.w - c1.w) / c2.w;
      }
#pragma unroll
      for (int j = 0; j < 4; j++) {
        unsigned short hh = f2bf(wv[j]);
        sAh[(m0 + j) * PAD + kr] = hh;
        sAl[(m0 + j) * PAD + kr] = f2bf(wv[j] - bf2f(hh));
      }
    }
#pragma unroll
    for (int q = 0; q < 2; q++) {
      int f = q * 256 + tid;
      int row = f >> 2, ch = f & 3;
      size_t gb = (size_t)row * N + k0 + kt + ch * 8;
      int ls = row * PAD + ch * 8;
      *(uint4*)&sBh[ls] = *(const uint4*)&Bthi[gb];
      *(uint4*)&sBl[ls] = *(const uint4*)&Btlo[gb];
    }
    __syncthreads();
    bf16x8 ah[4], al[4], bh[4], bl[4];
#pragma unroll
    for (int t = 0; t < 4; t++) {
      int ar = (wm + t * 16 + l15) * PAD + quad * 8;
      ah[t] = *(const bf16x8*)&sAh[ar];
      al[t] = *(const bf16x8*)&sAl[ar];
      int br = (wn + t * 16 + l15) * PAD + quad * 8;
      bh[t] = *(const bf16x8*)&sBh[br];
      bl[t] = *(const bf16x8*)&sBl[br];
    }
#pragma unroll
    for (int mt = 0; mt < 4; mt++)
#pragma unroll
      for (int nt = 0; nt < 4; nt++) {
        acc[mt][nt] = __builtin_amdgcn_mfma_f32_16x16x32_bf16(ah[mt], bh[nt], acc[mt][nt], 0, 0, 0);
        acc[mt][nt] = __builtin_amdgcn_mfma_f32_16x16x32_bf16(ah[mt], bl[nt], acc[mt][nt], 0, 0, 0);
        acc[mt][nt] = __builtin_amdgcn_mfma_f32_16x16x32_bf16(al[mt], bh[nt], acc[mt][nt], 0, 0, 0);
      }
    __syncthreads();
  }
  float* pp = partial + (size_t)blockIdx.z * C * 128;
#pragma unroll
  for (int mt = 0; mt < 4; mt++)
#pragma unroll
    for (int nt = 0; nt < 4; nt++) {
      int col = wn + nt * 16 + l15;
#pragma unroll
      for (int rg = 0; rg < 4; rg++) {
        int row = bm + wm + mt * 16 + quad * 4 + rg;
        pp[(size_t)row * 128 + col] = acc[mt][nt][rg];
      }
    }
}

__global__ __launch_bounds__(256) void k_scatter(
    const float* __restrict__ mtv, const int* __restrict__ mtj,
    const float* __restrict__ h, float* __restrict__ hidden2,
    float* __restrict__ colsum_m) {
  int i = blockIdx.x * 4 + (threadIdx.x >> 6);
  int lane = threadIdx.x & 63;
  float h0 = h[(size_t)i * H + lane], h1 = h[(size_t)i * H + 64 + lane];
#pragma unroll
  for (int s = 0; s < 3; s++) {
    float v = mtv[i * 3 + s];
    int j = mtj[i * 3 + s];
    atomicAdd(&hidden2[(size_t)j * H + lane], v * h0);
    atomicAdd(&hidden2[(size_t)j * H + 64 + lane], v * h1);
    if (lane == s) atomicAdd(&colsum_m[j], v);
  }
}

// reduce split-K partials; optional per-row scale (mul) or per-row divisor from
// summed per-z lsum partials; optional bf16 hi/lo pair emission; optional
// row-norm / row-valid emission
__global__ __launch_bounds__(256) void k_reduce(
    const float* __restrict__ partial, float* __restrict__ out, int cnt,
    size_t slot, size_t size4, const float* __restrict__ scalem,
    const float* __restrict__ plsum, unsigned short* __restrict__ hi,
    unsigned short* __restrict__ lo, float* __restrict__ nrmout,
    float* __restrict__ validout) {
  size_t idx = (size_t)blockIdx.x * 256 + threadIdx.x;
  if (idx >= size4) return;
  float4 s = {0, 0, 0, 0};
  for (int c = 0; c < cnt; c++) {
    float4 v = *(const float4*)&partial[c * slot + idx * 4];
    s.x += v.x; s.y += v.y; s.z += v.z; s.w += v.w;
  }
  if (scalem) {
    float sc = scalem[idx >> 5];
    s.x *= sc; s.y *= sc; s.z *= sc; s.w *= sc;
  }
  if (plsum) {
    int r = idx >> 5;
    float d = 0.f;
    for (int c = 0; c < cnt; c++) d += plsum[(size_t)c * N + r];
    float sc = 1.f / d;
    s.x *= sc; s.y *= sc; s.z *= sc; s.w *= sc;
  }
  *(float4*)&out[idx * 4] = s;
  if (hi) {
    float vv[4] = {s.x, s.y, s.z, s.w};
    unsigned short h[4], l[4];
#pragma unroll
    for (int c = 0; c < 4; c++) {
      h[c] = f2bf(vv[c]);
      l[c] = f2bf(vv[c] - bf2f(h[c]));
    }
    uint2 ph = {(unsigned)h[0] | ((unsigned)h[1] << 16),
                (unsigned)h[2] | ((unsigned)h[3] << 16)};
    uint2 pl = {(unsigned)l[0] | ((unsigned)l[1] << 16),
                (unsigned)l[2] | ((unsigned)l[3] << 16)};
    *(uint2*)&hi[idx * 4] = ph;
    *(uint2*)&lo[idx * 4] = pl;
  }
  if (nrmout || validout) {
    float rs = s.x + s.y + s.z + s.w;
    float rq = s.x * s.x + s.y * s.y + s.z * s.z + s.w * s.w;
#pragma unroll
    for (int m = 16; m; m >>= 1) { rs += __shfl_xor(rs, m); rq += __shfl_xor(rq, m); }
    if ((threadIdx.x & 31) == 0) {
      if (nrmout) nrmout[idx >> 5] = sqrtf(rq);
      if (validout) validout[idx >> 5] = (rs != 0.f) ? 1.f : 0.f;
    }
  }
}

// ---------------- fused branch-tail kernels ----------------
// Both: 32 output rows per block, full K=128 resident; weights cycled through LDS.

#define LOAD_W(Wt)                                                        \
  do {                                                                    \
    _Pragma("unroll") for (int q = 0; q < 16; q++) {                      \
      int f = q * 256 + tid;                                              \
      int wr = f >> 5, wc = (f & 31) * 4;                                 \
      float4 wv = *(const float4*)&(Wt)[(size_t)wr * 128 + wc];           \
      float ww[4] = {wv.x, wv.y, wv.z, wv.w};                             \
      _Pragma("unroll") for (int c = 0; c < 4; c++) {                     \
        unsigned short hh = f2bf(ww[c]);                                  \
        sWh[wr * WP + wc + c] = hh;                                       \
        sWl[wr * WP + wc + c] = f2bf(ww[c] - bf2f(hh));                   \
      }                                                                   \
    }                                                                     \
  } while (0)

#define GEMM32(accv)                                                              \
  do {                                                                            \
    _Pragma("unroll") for (int nt = 0; nt < 4; nt++) accv[nt] = zero;             \
    _Pragma("unroll") for (int kt = 0; kt < 128; kt += 32) {                      \
      bf16x8 ah = *(const bf16x8*)&sAh[(rt + l15) * WP + kt + quad * 8];          \
      bf16x8 al = *(const bf16x8*)&sAl[(rt + l15) * WP + kt + quad * 8];          \
      _Pragma("unroll") for (int nt = 0; nt < 4; nt++) {                          \
        int br = (ch2 + nt * 16 + l15) * WP + kt + quad * 8;                      \
        bf16x8 bh = *(const bf16x8*)&sWh[br];                                     \
        bf16x8 bl = *(const bf16x8*)&sWl[br];                                     \
        accv[nt] = __builtin_amdgcn_mfma_f32_16x16x32_bf16(ah, bh, accv[nt], 0, 0, 0); \
        accv[nt] = __builtin_amdgcn_mfma_f32_16x16x32_bf16(ah, bl, accv[nt], 0, 0, 0); \
        accv[nt] = __builtin_amdgcn_mfma_f32_16x16x32_bf16(al, bh, accv[nt], 0, 0, 0); \
      }                                                                           \
    }                                                                             \
  } while (0)

// ps tail: p_shared = lin(ps_pre,W_ps); h = x - lin(p_shared,W_psb);
// out_ps = lrelu(lin(p_shared,W_psf)) -> all_info; hhat/pairs/diagv from h.
__global__ __launch_bounds__(256) void k_ps_tail(
    const float* __restrict__ A, const float* __restrict__ x,
    const float* __restrict__ W_ps, const float* __restrict__ b_ps,
    const float* __restrict__ W_psb, const float* __restrict__ b_psb,
    const float* __restrict__ W_psf, const float* __restrict__ b_psf,
    float* __restrict__ hbuf, float* __restrict__ hhat,
    unsigned short* __restrict__ hhi, unsigned short* __restrict__ hlo,
    float* __restrict__ diagv, float* __restrict__ all_info) {
  __shared__ __align__(16) unsigned short sWh[128 * WP];
  __shared__ __align__(16) unsigned short sWl[128 * WP];
  __shared__ __align__(16) unsigned short sAh[32 * WP];
  __shared__ __align__(16) unsigned short sAl[32 * WP];
  __shared__ __align__(16) float sF[32][132];
  int tid = threadIdx.x;
  int bm = blockIdx.x * 32;
  int lane = tid & 63, w = tid >> 6;
  int rt = (w & 1) * 16, ch2 = (w >> 1) * 64;
  int l15 = lane & 15, quad = lane >> 4;
  f32x4 zero = {0.f, 0.f, 0.f, 0.f};
  f32x4 acc[4];

  // stage ps_pre tile -> pairs
  {
    int row = tid >> 3, c0 = (tid & 7) * 16;
    const float* src = &A[(size_t)(bm + row) * 128 + c0];
#pragma unroll
    for (int q = 0; q < 4; q++) {
      float4 v = *(const float4*)&src[q * 4];
      float vv[4] = {v.x, v.y, v.z, v.w};
#pragma unroll
      for (int c = 0; c < 4; c++) {
        unsigned short hh = f2bf(vv[c]);
        sAh[row * WP + c0 + q * 4 + c] = hh;
        sAl[row * WP + c0 + q * 4 + c] = f2bf(vv[c] - bf2f(hh));
      }
    }
  }
  LOAD_W(W_ps);
  __syncthreads();
  GEMM32(acc);  // p_shared (pre-bias)
  __syncthreads();
  // p_shared pairs -> sA
#pragma unroll
  for (int nt = 0; nt < 4; nt++) {
    int col = ch2 + nt * 16 + l15;
    float bv = b_ps[col];
#pragma unroll
    for (int rg = 0; rg < 4; rg++) {
      int row = rt + quad * 4 + rg;
      float v = acc[nt][rg] + bv;
      unsigned short hh = f2bf(v);
      sAh[row * WP + col] = hh;
      sAl[row * WP + col] = f2bf(v - bf2f(hh));
    }
  }
  LOAD_W(W_psb);
  __syncthreads();
  GEMM32(acc);  // p_back (pre-bias)
  // h = x - p_back
#pragma unroll
  for (int nt = 0; nt < 4; nt++) {
    int col = ch2 + nt * 16 + l15;
    float bv = b_psb[col];
#pragma unroll
    for (int rg = 0; rg < 4; rg++) {
      int row = rt + quad * 4 + rg;
      size_t off = (size_t)(bm + row) * 128 + col;
      float hv = x[off] - (acc[nt][rg] + bv);
      hbuf[off] = hv;
      sF[row][col] = hv;
    }
  }
  __syncthreads();
  // hhat substage (reads sF) + load W_psf (disjoint LDS)
  {
    int row = tid >> 3, c0 = (tid & 7) * 16;
    float hv16[16];
    float ssp = 0.f;
#pragma unroll
    for (int q = 0; q < 16; q++) {
      float v = sF[row][c0 + q];
      hv16[q] = v;
      ssp += v * v;
    }
    ssp += __shfl_xor(ssp, 1);
    ssp += __shfl_xor(ssp, 2);
    ssp += __shfl_xor(ssp, 4);
    float ss = ssp;
    float hn = sqrtf(ss);
    float den = hn * hn;
    float dg = (den == 0.f) ? 0.f : ss / den;
    float inv = (ss > 0.f) ? (1.f / hn) : 1.f;
    size_t base = (size_t)(bm + row) * H + c0;
    float va16[16];
    unsigned short hh16[16], ll16[16];
#pragma unroll
    for (int q = 0; q < 16; q++) {
      va16[q] = hv16[q] * inv;
      hh16[q] = f2bf(va16[q]);
      ll16[q] = f2bf(va16[q] - bf2f(hh16[q]));
    }
#pragma unroll
    for (int q4 = 0; q4 < 4; q4++) {
      float4 fv = {va16[q4 * 4], va16[q4 * 4 + 1], va16[q4 * 4 + 2], va16[q4 * 4 + 3]};
      *(float4*)&hhat[base + q4 * 4] = fv;
    }
    uint4 ph0 = {(unsigned)hh16[0] | ((unsigned)hh16[1] << 16), (unsigned)hh16[2] | ((unsigned)hh16[3] << 16),
                 (unsigned)hh16[4] | ((unsigned)hh16[5] << 16), (unsigned)hh16[6] | ((unsigned)hh16[7] << 16)};
    uint4 ph1 = {(unsigned)hh16[8] | ((unsigned)hh16[9] << 16), (unsigned)hh16[10] | ((unsigned)hh16[11] << 16),
                 (unsigned)hh16[12] | ((unsigned)hh16[13] << 16), (unsigned)hh16[14] | ((unsigned)hh16[15] << 16)};
    uint4 pl0 = {(unsigned)ll16[0] | ((unsigned)ll16[1] << 16), (unsigned)ll16[2] | ((unsigned)ll16[3] << 16),
                 (unsigned)ll16[4] | ((unsigned)ll16[5] << 16), (unsigned)ll16[6] | ((unsigned)ll16[7] << 16)};
    uint4 pl1 = {(unsigned)ll16[8] | ((unsigned)ll16[9] << 16), (unsigned)ll16[10] | ((unsigned)ll16[11] << 16),
                 (unsigned)ll16[12] | ((unsigned)ll16[13] << 16), (unsigned)ll16[14] | ((unsigned)ll16[15] << 16)};
    *(uint4*)&hhi[base] = ph0; *(uint4*)&hhi[base + 8] = ph1;
    *(uint4*)&hlo[base] = pl0; *(uint4*)&hlo[base + 8] = pl1;
    if ((tid & 7) == 0) diagv[bm + row] = dg;
  }
  LOAD_W(W_psf);
  __syncthreads();
  GEMM32(acc);  // out_ps (pre-bias)
#pragma unroll
  for (int nt = 0; nt < 4; nt++) {
    int col = ch2 + nt * 16 + l15;
    float bv = b_psf[col];
#pragma unroll
    for (int rg = 0; rg < 4; rg++) {
      int row = rt + quad * 4 + rg;
      size_t off = (size_t)(bm + row) * 128 + col;
      all_info[off] = lrelu(acc[nt][rg] + bv);
    }
  }
}

// hs tail: h_shared = lin(hs_pre,W_hs); all = all_info + lrelu(lin(h_shared,W_hsf));
// indiv = h - lin(h_shared,W_hsb); all += lrelu(lin(indiv,W_in)); out = all @ W_out + b.
__global__ __launch_bounds__(256) void k_hs_tail(
    const float* __restrict__ A, const float* __restrict__ hbuf,
    const float* __restrict__ all_info,
    const float* __restrict__ W_hs, const float* __restrict__ b_hs,
    const float* __restrict__ W_hsf, const float* __restrict__ b_hsf,
    const float* __restrict__ W_hsb, const float* __restrict__ b_hsb,
    const float* __restrict__ W_in, const float* __restrict__ b_in,
    const float* __restrict__ W_out, const float* __restrict__ b_out,
    float* __restrict__ out) {
  __shared__ __align__(16) unsigned short sWh[128 * WP];
  __shared__ __align__(16) unsigned short sWl[128 * WP];
  __shared__ __align__(16) unsigned short sAh[32 * WP];
  __shared__ __align__(16) unsigned short sAl[32 * WP];
  __shared__ __align__(16) float sF[32][132];
  int tid = threadIdx.x;
  int bm = blockIdx.x * 32;
  int lane = tid & 63, w = tid >> 6;
  int rt = (w & 1) * 16, ch2 = (w >> 1) * 64;
  int l15 = lane & 15, quad = lane >> 4;
  f32x4 zero = {0.f, 0.f, 0.f, 0.f};
  f32x4 acc[4];
  float allv[4][4];

  // stage hs_pre tile -> pairs
  {
    int row = tid >> 3, c0 = (tid & 7) * 16;
    const float* src = &A[(size_t)(bm + row) * 128 + c0];
#pragma unroll
    for (int q = 0; q < 4; q++) {
      float4 v = *(const float4*)&src[q * 4];
      float vv[4] = {v.x, v.y, v.z, v.w};
#pragma unroll
      for (int c = 0; c < 4; c++) {
        unsigned short hh = f2bf(vv[c]);
        sAh[row * WP + c0 + q * 4 + c] = hh;
        sAl[row * WP + c0 + q * 4 + c] = f2bf(vv[c] - bf2f(hh));
      }
    }
  }
  LOAD_W(W_hs);
  __syncthreads();
  GEMM32(acc);  // h_shared (pre-bias)
  __syncthreads();
  // h_shared pairs -> sA
#pragma unroll
  for (int nt = 0; nt < 4; nt++) {
    int col = ch2 + nt * 16 + l15;
    float bv = b_hs[col];
#pragma unroll
    for (int rg = 0; rg < 4; rg++) {
      int row = rt + quad * 4 + rg;
      float v = acc[nt][rg] + bv;
      unsigned short hh = f2bf(v);
      sAh[row * WP + col] = hh;
      sAl[row * WP + col] = f2bf(v - bf2f(hh));
    }
  }
  LOAD_W(W_hsf);
  __syncthreads();
  GEMM32(acc);  // out_hs (pre-bias)
#pragma unroll
  for (int nt = 0; nt < 4; nt++) {
    int col = ch2 + nt * 16 + l15;
    float bv = b_hsf[col];
#pragma unroll
    for (int rg = 0; rg < 4; rg++) {
      int row = rt + quad * 4 + rg;
      size_t off = (size_t)(bm + row) * 128 + col;
      allv[nt][rg] = all_info[off] + lrelu(acc[nt][rg] + bv);
    }
  }
  __syncthreads();  // all reads of sWh done
  LOAD_W(W_hsb);
  __syncthreads();
  GEMM32(acc);  // h_back (pre-bias)
  // indiv = h - h_back
  float iv[4][4];
#pragma unroll
  for (int nt = 0; nt < 4; nt++) {
    int col = ch2 + nt * 16 + l15;
    float bv = b_hsb[col];
#pragma unroll
    for (int rg = 0; rg < 4; rg++) {
      int row = rt + quad * 4 + rg;
      size_t off = (size_t)(bm + row) * 128 + col;
      iv[nt][rg] = hbuf[off] - (acc[nt][rg] + bv);
    }
  }
  __syncthreads();  // all reads of sA (h_shared) done
  // indiv pairs -> sA
#pragma unroll
  for (int nt = 0; nt < 4; nt++) {
    int col = ch2 + nt * 16 + l15;
#pragma unroll
    for (int rg = 0; rg < 4; rg++) {
      int row = rt + quad * 4 + rg;
      unsigned short hh = f2bf(iv[nt][rg]);
      sAh[row * WP + col] = hh;
      sAl[row * WP + col] = f2bf(iv[nt][rg] - bf2f(hh));
    }
  }
  LOAD_W(W_in);
  __syncthreads();
  GEMM32(acc);  // out_indi (pre-bias)
#pragma unroll
  for (int nt = 0; nt < 4; nt++) {
    int col = ch2 + nt * 16 + l15;
    float bv = b_in[col];
#pragma unroll
    for (int rg = 0; rg < 4; rg++) {
      int row = rt + quad * 4 + rg;
      allv[nt][rg] += lrelu(acc[nt][rg] + bv);
      sF[row][col] = allv[nt][rg];
    }
  }
  __syncthreads();
  // final: out[row] = dot(all_info_row, W_out) + b_out
  {
    int row = tid >> 3, c0 = (tid & 7) * 16;
    float s = 0.f;
#pragma unroll
    for (int q = 0; q < 16; q++) s += sF[row][c0 + q] * W_out[c0 + q];
    s += __shfl_xor(s, 1);
    s += __shfl_xor(s, 2);
    s += __shfl_xor(s, 4);
    if ((tid & 7) == 0) out[bm + row] = s + b_out[0];
  }
}

// ---------------- launch ----------------

extern "C" void kernel_launch(void* const* d_in, const int* in_sizes, int n_in,
                              void* d_out, int out_size, void* d_ws, size_t ws_size,
                              hipStream_t stream) {
  (void)in_sizes; (void)n_in; (void)out_size; (void)ws_size;
  const float* x   = (const float*)d_in[0];
  const float* cm  = (const float*)d_in[1];
  const float* mv  = (const float*)d_in[2];
  const float* W_ps = (const float*)d_in[3],  *b_ps = (const float*)d_in[4];
  const float* W_psf = (const float*)d_in[5], *b_psf = (const float*)d_in[6];
  const float* W_psb = (const float*)d_in[7], *b_psb = (const float*)d_in[8];
  const float* W_hs = (const float*)d_in[9],  *b_hs = (const float*)d_in[10];
  const float* W_hsf = (const float*)d_in[11], *b_hsf = (const float*)d_in[12];
  const float* W_hsb = (const float*)d_in[13], *b_hsb = (const float*)d_in[14];
  const float* W_in = (const float*)d_in[15], *b_in = (const float*)d_in[16];
  const float* W_out = (const float*)d_in[17], *b_out = (const float*)d_in[18];
  float* out = (float*)d_out;

  float* W = (float*)d_ws;
  size_t o = 0;
  auto alloc = [&](size_t n) { float* p = W + o; o += n; return p; };
  float* colsum_c = alloc(C);
  float* colmax   = alloc(C);
  float* colsumexp= alloc(C);
  float* valid1   = alloc(C);
  float* hnorm_ps = alloc(C);
  float* xnorm    = alloc(N);
  float* diagv    = alloc(N);
  float* colsum_m = alloc(N);
  float* valid2f  = alloc(N);
  float* plsum    = alloc((size_t)8 * N);
  float* mtv      = alloc(3 * N);
  int*   mtj      = (int*)alloc(3 * N);
  float* hidden1  = alloc((size_t)C * H);
  float* hidden_ps= alloc((size_t)C * H);
  float* scores   = alloc((size_t)N * C);
  float* ps_pre   = alloc((size_t)N * H);   // later hs_pre
  float* all_info = alloc((size_t)N * H);
  float* hbuf     = alloc((size_t)N * H);   // h
  float* hhat     = alloc((size_t)N * H);
  float* hidden2  = alloc((size_t)N * H);
  unsigned short* xhi    = (unsigned short*)alloc((size_t)N * H / 2);
  unsigned short* xlo    = (unsigned short*)alloc((size_t)N * H / 2);
  unsigned short* hhathi = (unsigned short*)alloc((size_t)N * H / 2);
  unsigned short* hhatlo = (unsigned short*)alloc((size_t)N * H / 2);
  unsigned short* h2hi   = (unsigned short*)alloc((size_t)N * H / 2);
  unsigned short* h2lo   = (unsigned short*)alloc((size_t)N * H / 2);
  unsigned short* h1hi   = (unsigned short*)alloc((size_t)C * H / 2);
  unsigned short* h1lo   = (unsigned short*)alloc((size_t)C * H / 2);
  unsigned short* hpshi  = (unsigned short*)alloc((size_t)C * H / 2);
  unsigned short* hpslo  = (unsigned short*)alloc((size_t)C * H / 2);
  unsigned short* cshi   = (unsigned short*)alloc((size_t)N * C / 2);
  unsigned short* cslo   = (unsigned short*)alloc((size_t)N * C / 2);
  unsigned short* hpst_hi= (unsigned short*)alloc((size_t)H * C / 2);
  unsigned short* hpst_lo= (unsigned short*)alloc((size_t)H * C / 2);
  unsigned short* h2t_hi = (unsigned short*)alloc((size_t)H * N / 2);
  unsigned short* h2t_lo = (unsigned short*)alloc((size_t)H * N / 2);
  unsigned short* xt_hi  = (unsigned short*)alloc((size_t)H * N / 2);
  unsigned short* xt_lo  = (unsigned short*)alloc((size_t)H * N / 2);
  float2* cand    = (float2*)alloc((size_t)N * 128 * 5 * 2);
  float* partial  = W + o;
  const int Z = 8;        // flash split-KV (8*N*128 fp32 = 16 MB)
  const int ZG = 64;      // genA split-K (64*C*128 fp32 = 16.8 MB); same region

  hipMemsetAsync(colsum_c, 0, C * sizeof(float), stream);
  hipMemsetAsync(colsum_m, 0, N * sizeof(float), stream);
  hipMemsetAsync(hidden2, 0, (size_t)N * H * sizeof(float), stream);

  dim3 blk(256);
  // --- ps branch ---
  k_split<<<dim3(N * H / 1024), blk, 0, stream>>>(x, xhi, xlo, xnorm);
  k_tsplit<<<dim3(N / 32), blk, 0, stream>>>(x, xt_hi, xt_lo, N);
  k_colsum_s2c<<<dim3(C / 64, 16), dim3(64), 0, stream>>>(cm, mv, colsum_c);
  k_mfma_genA<1><<<dim3(1, C / 128, ZG), blk, 0, stream>>>(
      cm, mv, colsum_c, nullptr, xt_hi, xt_lo, partial, N / ZG);
  k_reduce<<<dim3(C * H / 4 / 256), blk, 0, stream>>>(
      partial, hidden1, ZG, (size_t)C * H, (size_t)C * H / 4, nullptr, nullptr,
      h1hi, h1lo, nullptr, valid1);
  k_mfma_nt<<<dim3(C / 128, N / 64), blk, 0, stream>>>(
      xhi, xlo, h1hi, h1lo, scores, C);
  k_colstats<<<dim3(C), blk, 0, stream>>>(scores, colmax, colsumexp);
  k_mfma_genA<2><<<dim3(1, C / 128, ZG), blk, 0, stream>>>(
      scores, nullptr, colmax, colsumexp, xt_hi, xt_lo, partial, N / ZG);
  k_reduce<<<dim3(C * H / 4 / 256), blk, 0, stream>>>(
      partial, hidden_ps, ZG, (size_t)C * H, (size_t)C * H / 4, valid1, nullptr,
      hpshi, hpslo, hnorm_ps, nullptr);
  k_mfma_nt<<<dim3(C / 128, N / 64), blk, 0, stream>>>(
      xhi, xlo, hpshi, hpslo, scores, C);
  k_cs_softmax<<<dim3(N), blk, 0, stream>>>(scores, xnorm, hnorm_ps, valid1,
                                            cshi, cslo);
  k_tsplit<<<dim3(C / 32), blk, 0, stream>>>(hidden_ps, hpst_hi, hpst_lo, C);
  k_mfma_kn<<<dim3(1, N / 128, 4), blk, 0, stream>>>(
      cshi, cslo, hpst_hi, hpst_lo, partial, C, C / 4);
  k_reduce<<<dim3(N * H / 4 / 256), blk, 0, stream>>>(
      partial, ps_pre, 4, (size_t)N * H, (size_t)N * H / 4, nullptr, nullptr,
      nullptr, nullptr, nullptr, nullptr);
  k_ps_tail<<<dim3(N / 32), blk, 0, stream>>>(
      ps_pre, x, W_ps, b_ps, W_psb, b_psb, W_psf, b_psf,
      hbuf, hhat, hhathi, hhatlo, diagv, all_info);
  // --- hs branch ---
  k_snt<<<dim3(N / 128, N / 128), dim3(512), 0, stream>>>(
      hhathi, hhatlo, cand);
  k_rowtop2<<<dim3(N / 4), blk, 0, stream>>>(cand, hhat, mtv, mtj);
  k_scatter<<<dim3(N / 4), blk, 0, stream>>>(mtv, mtj, hbuf, hidden2, colsum_m);
  k_fin_hidden2<<<dim3(N), dim3(64), 0, stream>>>(hbuf, diagv, colsum_m, hidden2,
                                                  h2hi, h2lo, valid2f);
  k_tsplit<<<dim3(N / 32), blk, 0, stream>>>(hidden2, h2t_hi, h2t_lo, N);
  k_flash<<<dim3(Z, N / 64), blk, 0, stream>>>(
      hhathi, hhatlo, h2hi, h2lo, h2t_hi, h2t_lo, valid2f, partial, plsum,
      N / Z);
  k_reduce<<<dim3(N * H / 4 / 256), blk, 0, stream>>>(
      partial, ps_pre, Z, (size_t)N * H, (size_t)N * H / 4, nullptr, plsum,
      nullptr, nullptr, nullptr, nullptr);  // hs_pre = U / l
  k_hs_tail<<<dim3(N / 32), blk, 0, stream>>>(
      ps_pre, hbuf, all_info, W_hs, b_hs, W_hsf, b_hsf, W_hsb, b_hsb,
      W_in, b_in, W_out, b_out, out);
}

// Round 8
// 369.188 us; speedup vs baseline: 1.0429x; 1.0429x over previous
//
#include <hip/hip_runtime.h>
#include <hip/hip_fp16.h>
#include <math.h>

#define N 4096
#define C 512
#define H 128
#define PAD 40  // ushort row pitch for 32-col MFMA LDS staging tiles
#define WP 136  // ushort row pitch for full-K (128 col) LDS tiles
#define FWP 136 // ushort row pitch for flash Q/P tiles
#define SP 136  // ushort row pitch for S-tile scan buffer (272 B, 16B-aligned)

typedef __attribute__((ext_vector_type(8))) short bf16x8;
typedef __attribute__((ext_vector_type(4))) float f32x4;

// ---------------- helpers ----------------

__device__ inline float wave_reduce_sum(float v) {
#pragma unroll
  for (int m = 32; m; m >>= 1) v += __shfl_xor(v, m);
  return v;
}

__device__ inline float lrelu(float v) { return v > 0.f ? v : 0.01f * v; }

__device__ inline bool better(float v, int j, float w, int k) {
  return (v > w) || (v == w && j < k);
}

__device__ inline void top3_ins(float v, int j, float& v0, int& j0,
                                float& v1, int& j1, float& v2, int& j2) {
  if (better(v, j, v0, j0)) { v2 = v1; j2 = j1; v1 = v0; j1 = j0; v0 = v; j0 = j; }
  else if (better(v, j, v1, j1)) { v2 = v1; j2 = j1; v1 = v; j1 = j; }
  else if (better(v, j, v2, j2)) { v2 = v; j2 = j; }
}

__device__ inline void ins5(float s, int j, float v[5], int jx[5]) {
  if (!better(s, j, v[4], jx[4])) return;
  if (better(s, j, v[0], jx[0])) {
    v[4]=v[3]; jx[4]=jx[3]; v[3]=v[2]; jx[3]=jx[2]; v[2]=v[1]; jx[2]=jx[1];
    v[1]=v[0]; jx[1]=jx[0]; v[0]=s; jx[0]=j;
  } else if (better(s, j, v[1], jx[1])) {
    v[4]=v[3]; jx[4]=jx[3]; v[3]=v[2]; jx[3]=jx[2]; v[2]=v[1]; jx[2]=jx[1];
    v[1]=s; jx[1]=j;
  } else if (better(s, j, v[2], jx[2])) {
    v[4]=v[3]; jx[4]=jx[3]; v[3]=v[2]; jx[3]=jx[2]; v[2]=s; jx[2]=j;
  } else if (better(s, j, v[3], jx[3])) {
    v[4]=v[3]; jx[4]=jx[3]; v[3]=s; jx[3]=j;
  } else {
    v[4]=s; jx[4]=j;
  }
}

__device__ inline unsigned short f2bf(float f) {
  unsigned u = __float_as_uint(f);
  unsigned r = u + 0x7fffu + ((u >> 16) & 1u);
  return (unsigned short)(r >> 16);
}
__device__ inline float bf2f(unsigned short h) {
  return __uint_as_float(((unsigned)h) << 16);
}

// ---------------- split fp32 -> bf16 hi/lo (+ row norms of x) ----------------
__global__ __launch_bounds__(256) void k_split(const float* __restrict__ in,
                                               unsigned short* __restrict__ hi,
                                               unsigned short* __restrict__ lo,
                                               float* __restrict__ nrm) {
  int t = threadIdx.x;
  int idx = (blockIdx.x * 256 + t) * 4;
  float4 v = *(const float4*)&in[idx];
  float vv[4] = {v.x, v.y, v.z, v.w};
  unsigned short h[4], l[4];
  float ss = 0.f;
#pragma unroll
  for (int c = 0; c < 4; c++) {
    ss += vv[c] * vv[c];
    h[c] = f2bf(vv[c]);
    l[c] = f2bf(vv[c] - bf2f(h[c]));
  }
  uint2 ph = {(unsigned)h[0] | ((unsigned)h[1] << 16),
              (unsigned)h[2] | ((unsigned)h[3] << 16)};
  uint2 pl = {(unsigned)l[0] | ((unsigned)l[1] << 16),
              (unsigned)l[2] | ((unsigned)l[3] << 16)};
  *(uint2*)&hi[idx] = ph;
  *(uint2*)&lo[idx] = pl;
  if (nrm) {
#pragma unroll
    for (int m = 16; m; m >>= 1) ss += __shfl_xor(ss, m);  // 32-lane row group
    if ((t & 31) == 0) nrm[idx >> 7] = sqrtf(ss);
  }
}

// transpose + split: in [R,128] fp32 -> thi/tlo [128,R] ushort
__global__ __launch_bounds__(256) void k_tsplit(const float* __restrict__ in,
                                                unsigned short* __restrict__ thi,
                                                unsigned short* __restrict__ tlo,
                                                int R) {
  __shared__ float tile[32][132];
  int r0 = blockIdx.x * 32, tid = threadIdx.x;
#pragma unroll
  for (int q = 0; q < 4; q++) {
    int f = q * 256 + tid;
    int row = f >> 5, ch = f & 31;
    *(float4*)&tile[row][ch * 4] = *(const float4*)&in[(size_t)(r0 + row) * 128 + ch * 4];
  }
  __syncthreads();
  int c = tid & 127, half = tid >> 7;
  unsigned short hh[16], ll[16];
#pragma unroll
  for (int rr = 0; rr < 16; rr++) {
    float v = tile[half * 16 + rr][c];
    hh[rr] = f2bf(v);
    ll[rr] = f2bf(v - bf2f(hh[rr]));
  }
  size_t off = (size_t)c * R + r0 + half * 16;
  uint4 ph0 = {(unsigned)hh[0] | ((unsigned)hh[1] << 16), (unsigned)hh[2] | ((unsigned)hh[3] << 16),
               (unsigned)hh[4] | ((unsigned)hh[5] << 16), (unsigned)hh[6] | ((unsigned)hh[7] << 16)};
  uint4 ph1 = {(unsigned)hh[8] | ((unsigned)hh[9] << 16), (unsigned)hh[10] | ((unsigned)hh[11] << 16),
               (unsigned)hh[12] | ((unsigned)hh[13] << 16), (unsigned)hh[14] | ((unsigned)hh[15] << 16)};
  uint4 pl0 = {(unsigned)ll[0] | ((unsigned)ll[1] << 16), (unsigned)ll[2] | ((unsigned)ll[3] << 16),
               (unsigned)ll[4] | ((unsigned)ll[5] << 16), (unsigned)ll[6] | ((unsigned)ll[7] << 16)};
  uint4 pl1 = {(unsigned)ll[8] | ((unsigned)ll[9] << 16), (unsigned)ll[10] | ((unsigned)ll[11] << 16),
               (unsigned)ll[12] | ((unsigned)ll[13] << 16), (unsigned)ll[14] | ((unsigned)ll[15] << 16)};
  *(uint4*)&thi[off] = ph0; *(uint4*)&thi[off + 8] = ph1;
  *(uint4*)&tlo[off] = pl0; *(uint4*)&tlo[off + 8] = pl1;
}

// ---------------- small kernels ----------------

__global__ __launch_bounds__(64) void k_colsum_s2c(
    const float* __restrict__ cm, const float* __restrict__ mv,
    float* __restrict__ colsum_c) {
  int c = blockIdx.x * 64 + threadIdx.x;
  int i0 = blockIdx.y * 256;
  float acc = 0.f;
  for (int i = i0; i < i0 + 256; i++) acc += cm[(size_t)i * C + c] * mv[i];
  atomicAdd(&colsum_c[c], acc);
}

__global__ __launch_bounds__(256) void k_colstats(const float* __restrict__ sc,
                                                  float* __restrict__ colmax,
                                                  float* __restrict__ colsum) {
  __shared__ float red[256];
  int c = blockIdx.x, t = threadIdx.x;
  float v[16];
  float m = -3e38f;
#pragma unroll
  for (int q = 0; q < 16; q++) {
    v[q] = sc[(size_t)(q * 256 + t) * C + c];
    m = fmaxf(m, v[q]);
  }
  red[t] = m; __syncthreads();
  for (int s = 128; s; s >>= 1) { if (t < s) red[t] = fmaxf(red[t], red[t + s]); __syncthreads(); }
  m = red[0]; __syncthreads();
  float sum = 0.f;
#pragma unroll
  for (int q = 0; q < 16; q++) sum += __expf(v[q] - m);
  red[t] = sum; __syncthreads();
  for (int s = 128; s; s >>= 1) { if (t < s) red[t] += red[t + s]; __syncthreads(); }
  if (t == 0) { colmax[c] = m; colsum[c] = red[0]; }
}

// row softmax of cos-sim -> bf16 hi/lo pairs
__global__ __launch_bounds__(256) void k_cs_softmax(
    const float* __restrict__ sc, const float* __restrict__ xnorm,
    const float* __restrict__ hnorm, const float* __restrict__ valid1,
    unsigned short* __restrict__ cshi, unsigned short* __restrict__ cslo) {
  __shared__ float red[256];
  int i = blockIdx.x, t = threadIdx.x;
  float xn = xnorm[i];
  float r0 = sc[(size_t)i * C + t], r1 = sc[(size_t)i * C + 256 + t];
  float d0 = xn * hnorm[t], d1 = xn * hnorm[256 + t];
  float c0 = r0 / (d0 == 0.f ? 1.f : d0);
  float c1 = r1 / (d1 == 0.f ? 1.f : d1);
  float s0 = (valid1[t] != 0.f) ? c0 : -3e38f;
  float s1 = (valid1[256 + t] != 0.f) ? c1 : -3e38f;
  red[t] = fmaxf(s0, s1); __syncthreads();
  for (int s = 128; s; s >>= 1) { if (t < s) red[t] = fmaxf(red[t], red[t + s]); __syncthreads(); }
  float m = red[0]; __syncthreads();
  float p0 = (s0 > -1e37f) ? __expf(s0 - m) : 0.f;
  float p1 = (s1 > -1e37f) ? __expf(s1 - m) : 0.f;
  red[t] = p0 + p1; __syncthreads();
  for (int s = 128; s; s >>= 1) { if (t < s) red[t] += red[t + s]; __syncthreads(); }
  float inv = 1.f / red[0];
  float a = p0 * inv, b = p1 * inv;
  unsigned short ha = f2bf(a), hb = f2bf(b);
  cshi[(size_t)i * C + t] = ha;
  cslo[(size_t)i * C + t] = f2bf(a - bf2f(ha));
  cshi[(size_t)i * C + 256 + t] = hb;
  cslo[(size_t)i * C + 256 + t] = f2bf(b - bf2f(hb));
}

// finalize hidden2 + h2hat pairs + valid2f
__global__ __launch_bounds__(64) void k_fin_hidden2(
    const float* __restrict__ h, const float* __restrict__ diagv,
    const float* __restrict__ colsum_m, float* __restrict__ hidden2,
    unsigned short* __restrict__ h2hi, unsigned short* __restrict__ h2lo,
    float* __restrict__ valid2f) {
  int j = blockIdx.x, t = threadIdx.x;
  float add = (colsum_m[j] != 0.f) ? diagv[j] : 0.f;
  float a = hidden2[(size_t)j * H + t] + add * h[(size_t)j * H + t];
  float b = hidden2[(size_t)j * H + 64 + t] + add * h[(size_t)j * H + 64 + t];
  float s = a + b, ss = a * a + b * b;
#pragma unroll
  for (int m = 32; m; m >>= 1) { s += __shfl_xor(s, m); ss += __shfl_xor(ss, m); }
  bool valid = (s != 0.f);
  a = valid ? a : 0.f; b = valid ? b : 0.f;
  hidden2[(size_t)j * H + t] = a;
  hidden2[(size_t)j * H + 64 + t] = b;
  float inv = (valid && ss > 0.f) ? (1.f / sqrtf(ss)) : 1.f;
  float va = a * inv, vb = b * inv;
  unsigned short ha = f2bf(va), hb = f2bf(vb);
  h2hi[(size_t)j * H + t] = ha;
  h2lo[(size_t)j * H + t] = f2bf(va - bf2f(ha));
  h2hi[(size_t)j * H + 64 + t] = hb;
  h2lo[(size_t)j * H + 64 + t] = f2bf(vb - bf2f(hb));
  if (t == 0) valid2f[j] = valid ? 1.f : 0.f;
}

// ---------------- bf16x3 MFMA NT GEMM: A[64,128] @ B[128,128]^T, fp32 out ----
// 64-row tiles so grid (C/128, N/64) = 256 blocks fills all CUs.
__global__ __launch_bounds__(256) void k_mfma_nt(
    const unsigned short* __restrict__ Ahi, const unsigned short* __restrict__ Alo,
    const unsigned short* __restrict__ Bhi, const unsigned short* __restrict__ Blo,
    float* __restrict__ out, int Nn) {
  __shared__ __align__(16) unsigned short sAh[64 * PAD];
  __shared__ __align__(16) unsigned short sAl[64 * PAD];
  __shared__ __align__(16) unsigned short sBh[128 * PAD];
  __shared__ __align__(16) unsigned short sBl[128 * PAD];
  int tid = threadIdx.x;
  int bm = blockIdx.y * 64, bn = blockIdx.x * 128;
  int lane = tid & 63, w = tid >> 6;
  int wm = (w & 1) * 32, wn = (w >> 1) * 64;
  int l15 = lane & 15, quad = lane >> 4;
  f32x4 zero = {0.f, 0.f, 0.f, 0.f};
  f32x4 acc[2][4];
#pragma unroll
  for (int mt = 0; mt < 2; mt++)
#pragma unroll
    for (int nt = 0; nt < 4; nt++) acc[mt][nt] = zero;

  for (int kt = 0; kt < 128; kt += 32) {
    {
      int row = tid >> 2, ch = tid & 3;  // A: 64 rows x 4 chunks
      size_t ga = (size_t)(bm + row) * 128 + kt + ch * 8;
      int ls = row * PAD + ch * 8;
      *(uint4*)&sAh[ls] = *(const uint4*)&Ahi[ga];
      *(uint4*)&sAl[ls] = *(const uint4*)&Alo[ga];
    }
#pragma unroll
    for (int q = 0; q < 2; q++) {     // B: 128 rows x 4 chunks
      int f = q * 256 + tid;
      int row = f >> 2, ch = f & 3;
      size_t gb = (size_t)(bn + row) * 128 + kt + ch * 8;
      int ls = row * PAD + ch * 8;
      *(uint4*)&sBh[ls] = *(const uint4*)&Bhi[gb];
      *(uint4*)&sBl[ls] = *(const uint4*)&Blo[gb];
    }
    __syncthreads();
    bf16x8 ah[2], al[2], bh[4], bl[4];
#pragma unroll
    for (int t = 0; t < 2; t++) {
      int ar = (wm + t * 16 + l15) * PAD + quad * 8;
      ah[t] = *(const bf16x8*)&sAh[ar];
      al[t] = *(const bf16x8*)&sAl[ar];
    }
#pragma unroll
    for (int t = 0; t < 4; t++) {
      int br = (wn + t * 16 + l15) * PAD + quad * 8;
      bh[t] = *(const bf16x8*)&sBh[br];
      bl[t] = *(const bf16x8*)&sBl[br];
    }
#pragma unroll
    for (int mt = 0; mt < 2; mt++)
#pragma unroll
      for (int nt = 0; nt < 4; nt++) {
        acc[mt][nt] = __builtin_amdgcn_mfma_f32_16x16x32_bf16(ah[mt], bh[nt], acc[mt][nt], 0, 0, 0);
        acc[mt][nt] = __builtin_amdgcn_mfma_f32_16x16x32_bf16(ah[mt], bl[nt], acc[mt][nt], 0, 0, 0);
        acc[mt][nt] = __builtin_amdgcn_mfma_f32_16x16x32_bf16(al[mt], bh[nt], acc[mt][nt], 0, 0, 0);
      }
    __syncthreads();
  }
#pragma unroll
  for (int mt = 0; mt < 2; mt++) {
#pragma unroll
    for (int nt = 0; nt < 4; nt++) {
      int col = bn + wn + nt * 16 + l15;
#pragma unroll
      for (int rg = 0; rg < 4; rg++) {
        int row = bm + wm + mt * 16 + quad * 4 + rg;
        out[(size_t)row * Nn + col] = acc[mt][nt][rg];
      }
    }
  }
}

// ---------------- S = hhat@hhat^T + fused quarter-row top-5 screen -----------
// 512 threads = 8 waves (4 row-bands x 2 col-halves). S-tile dumped to LDS
// fp16 (diag 0); each thread serially scans a 32-col quarter-row -> cand.
__global__ __launch_bounds__(512) void k_snt(
    const unsigned short* __restrict__ Ahi, const unsigned short* __restrict__ Alo,
    float2* __restrict__ cand) {
  __shared__ __align__(16) unsigned short sAh[128 * PAD];
  __shared__ __align__(16) unsigned short sAl[128 * PAD];
  __shared__ __align__(16) unsigned short sBh[128 * PAD];
  __shared__ __align__(16) unsigned short sBl[128 * PAD];
  __shared__ __align__(16) unsigned short sS[128 * SP];
  int tid = threadIdx.x;
  int bm = blockIdx.y * 128, bn = blockIdx.x * 128;
  int lane = tid & 63, w = tid >> 6;
  int wm = (w & 3) * 32, wn = (w >> 2) * 64;
  int l15 = lane & 15, quad = lane >> 4;
  f32x4 zero = {0.f, 0.f, 0.f, 0.f};
  f32x4 acc[2][4];
#pragma unroll
  for (int mt = 0; mt < 2; mt++)
#pragma unroll
    for (int nt = 0; nt < 4; nt++) acc[mt][nt] = zero;

  for (int kt = 0; kt < 128; kt += 32) {
    {
      int row = tid >> 2, ch = tid & 3;
      size_t ga = (size_t)(bm + row) * 128 + kt + ch * 8;
      size_t gb = (size_t)(bn + row) * 128 + kt + ch * 8;
      int ls = row * PAD + ch * 8;
      *(uint4*)&sAh[ls] = *(const uint4*)&Ahi[ga];
      *(uint4*)&sAl[ls] = *(const uint4*)&Alo[ga];
      *(uint4*)&sBh[ls] = *(const uint4*)&Ahi[gb];
      *(uint4*)&sBl[ls] = *(const uint4*)&Alo[gb];
    }
    __syncthreads();
    bf16x8 ah[2], al[2], bh[4], bl[4];
#pragma unroll
    for (int t = 0; t < 2; t++) {
      int ar = (wm + t * 16 + l15) * PAD + quad * 8;
      ah[t] = *(const bf16x8*)&sAh[ar];
      al[t] = *(const bf16x8*)&sAl[ar];
    }
#pragma unroll
    for (int t = 0; t < 4; t++) {
      int br = (wn + t * 16 + l15) * PAD + quad * 8;
      bh[t] = *(const bf16x8*)&sBh[br];
      bl[t] = *(const bf16x8*)&sBl[br];
    }
#pragma unroll
    for (int mt = 0; mt < 2; mt++)
#pragma unroll
      for (int nt = 0; nt < 4; nt++) {
        acc[mt][nt] = __builtin_amdgcn_mfma_f32_16x16x32_bf16(ah[mt], bh[nt], acc[mt][nt], 0, 0, 0);
        acc[mt][nt] = __builtin_amdgcn_mfma_f32_16x16x32_bf16(ah[mt], bl[nt], acc[mt][nt], 0, 0, 0);
        acc[mt][nt] = __builtin_amdgcn_mfma_f32_16x16x32_bf16(al[mt], bh[nt], acc[mt][nt], 0, 0, 0);
      }
    __syncthreads();
  }
  // dump S tile as fp16 (diag zeroed)
#pragma unroll
  for (int mt = 0; mt < 2; mt++)
#pragma unroll
    for (int nt = 0; nt < 4; nt++) {
      int coll = wn + nt * 16 + l15;
#pragma unroll
      for (int rg = 0; rg < 4; rg++) {
        int rowl = wm + mt * 16 + quad * 4 + rg;
        float v = (bm + rowl == bn + coll) ? 0.f : acc[mt][nt][rg];
        sS[rowl * SP + coll] = __half_as_ushort(__float2half(v));
      }
    }
  __syncthreads();
  // serial top-5 scan: thread handles quarter-row (r = tid>>2, qf = tid&3)
  int r = tid >> 2, qf = tid & 3;
  const unsigned short* rowp = &sS[r * SP + qf * 32];
  int cbase = bn + qf * 32;
  float v5[5] = {-3e38f, -3e38f, -3e38f, -3e38f, -3e38f};
  int j5[5] = {0x7fffffff, 0x7fffffff, 0x7fffffff, 0x7fffffff, 0x7fffffff};
#pragma unroll
  for (int q = 0; q < 4; q++) {
    uint4 p = *(const uint4*)&rowp[q * 8];
    unsigned pk[4] = {p.x, p.y, p.z, p.w};
#pragma unroll
    for (int c2 = 0; c2 < 4; c2++) {
      float e0 = __half2float(__ushort_as_half((unsigned short)(pk[c2] & 0xffffu)));
      float e1 = __half2float(__ushort_as_half((unsigned short)(pk[c2] >> 16)));
      ins5(e0, cbase + q * 8 + c2 * 2, v5, j5);
      ins5(e1, cbase + q * 8 + c2 * 2 + 1, v5, j5);
    }
  }
  int slot = (bn >> 5) + qf;
  float2* cp = &cand[((size_t)(bm + r) * 128 + slot) * 5];
#pragma unroll
  for (int c2 = 0; c2 < 5; c2++) cp[c2] = {v5[c2], __int_as_float(j5[c2])};
}

// ---------------- row top-k merge: candidates -> exact fp32 rescore ----------
__global__ __launch_bounds__(256) void k_rowtop2(
    const float2* __restrict__ cand, const float* __restrict__ hhat,
    float* __restrict__ mtv, int* __restrict__ mtj) {
  int i = blockIdx.x * 4 + (threadIdx.x >> 6);
  int lane = threadIdx.x & 63;
  const float2* cr = &cand[(size_t)i * 640];
  float v[5] = {-3e38f, -3e38f, -3e38f, -3e38f, -3e38f};
  int jx[5] = {0x7fffffff, 0x7fffffff, 0x7fffffff, 0x7fffffff, 0x7fffffff};
#pragma unroll
  for (int c = 0; c < 10; c++) {
    float2 p = cr[lane * 10 + c];
    ins5(p.x, __float_as_int(p.y), v, jx);
  }
#pragma unroll
  for (int d = 1; d < 64; d <<= 1) {
    float fv[5]; int fj[5];
#pragma unroll
    for (int c = 0; c < 5; c++) { fv[c] = __shfl_xor(v[c], d); fj[c] = __shfl_xor(jx[c], d); }
#pragma unroll
    for (int c = 0; c < 5; c++) ins5(fv[c], fj[c], v, jx);
  }
  const float* hi = &hhat[(size_t)i * H];
  float b0 = -3e38f, b1 = -3e38f, b2 = -3e38f;
  int q0 = 0, q1 = 0, q2 = 0;
#pragma unroll
  for (int c = 0; c < 5; c++) {
    int j = jx[c];
    float s;
    if (j == i) {
      s = 0.f;
    } else {
      const float* hj = &hhat[(size_t)j * H];
      float p = hi[lane] * hj[lane] + hi[lane + 64] * hj[lane + 64];
      s = wave_reduce_sum(p);
    }
    top3_ins(s, j, b0, q0, b1, q1, b2, q2);
  }
  if (lane == 0) {
    mtv[i * 3 + 0] = b0; mtv[i * 3 + 1] = b1; mtv[i * 3 + 2] = b2;
    mtj[i * 3 + 0] = q0; mtj[i * 3 + 1] = q1; mtj[i * 3 + 2] = q2;
  }
}

// ---------------- flash-fused hs_pre numerator: U[z] = E_z @ hidden2 ---------
// Q=hhat pairs [N,128]; K=h2hat pairs [N,128]; V=h2t pairs [128,N].
// 512 threads = 8 waves (4 row-bands x 2 col-halves). K/V kt-chunks cycle
// through a 2-slot LDS ring: each phase issues next-chunk global loads into
// registers BEFORE its MFMAs, ds_writes to the other slot after, then ONE
// barrier. 9 barriers/jb (was ~17) and load latency hides under MFMA.
__global__ __launch_bounds__(512) void k_flash(
    const unsigned short* __restrict__ Qhi, const unsigned short* __restrict__ Qlo,
    const unsigned short* __restrict__ Khi, const unsigned short* __restrict__ Klo,
    const unsigned short* __restrict__ Vthi, const unsigned short* __restrict__ Vtlo,
    const float* __restrict__ valid2f, float* __restrict__ partialU,
    float* __restrict__ plsum, int KVC) {
  __shared__ __align__(16) unsigned short sQh[128 * FWP];
  __shared__ __align__(16) unsigned short sQl[128 * FWP];
  __shared__ __align__(16) unsigned short sP[128 * FWP];
  __shared__ __align__(16) unsigned short sBh[2][128 * PAD];
  __shared__ __align__(16) unsigned short sBl[2][128 * PAD];
  __shared__ float lsum_s[128];
  int tid = threadIdx.x;
  int z = blockIdx.x;
  int bm = blockIdx.y * 128;
  int j0 = z * KVC;
  int lane = tid & 63, w = tid >> 6;
  int wm = (w & 3) * 32, wn = (w >> 2) * 64;
  int l15 = lane & 15, quad = lane >> 4;
  int srow = tid >> 2, sch = tid & 3;
  int sls = srow * PAD + sch * 8;
  // stage Q tile (persistent) + zero lsum
#pragma unroll
  for (int q = 0; q < 4; q++) {
    int f = q * 512 + tid;
    int row = f >> 4, ch = f & 15;
    size_t ga = (size_t)(bm + row) * 128 + ch * 8;
    int ls = row * FWP + ch * 8;
    *(uint4*)&sQh[ls] = *(const uint4*)&Qhi[ga];
    *(uint4*)&sQl[ls] = *(const uint4*)&Qlo[ga];
  }
  if (tid < 128) lsum_s[tid] = 0.f;
  // prologue: K chunk 0 of first jb -> slot 0
  {
    size_t a = (size_t)(j0 + srow) * 128 + sch * 8;
    uint4 rh = *(const uint4*)&Khi[a];
    uint4 rl = *(const uint4*)&Klo[a];
    __syncthreads();
    *(uint4*)&sBh[0][sls] = rh;
    *(uint4*)&sBl[0][sls] = rl;
  }
  __syncthreads();
  int cur = 0;
  f32x4 zero = {0.f, 0.f, 0.f, 0.f};
  f32x4 uacc[2][4];
#pragma unroll
  for (int mt = 0; mt < 2; mt++)
#pragma unroll
    for (int nt = 0; nt < 4; nt++) uacc[mt][nt] = zero;

  for (int jb = j0; jb < j0 + KVC; jb += 128) {
    float vm[4];
#pragma unroll
    for (int nt = 0; nt < 4; nt++) vm[nt] = valid2f[jb + wn + nt * 16 + l15];
    f32x4 qacc[2][4];
#pragma unroll
    for (int mt = 0; mt < 2; mt++)
#pragma unroll
      for (int nt = 0; nt < 4; nt++) qacc[mt][nt] = zero;
    // --- QK^T over 4 kt-chunks (ring) ---
#pragma unroll
    for (int t = 0; t < 4; t++) {
      uint4 nrh, nrl;
      if (t < 3) {  // next K chunk
        size_t a = (size_t)(jb + srow) * 128 + (t + 1) * 32 + sch * 8;
        nrh = *(const uint4*)&Khi[a];
        nrl = *(const uint4*)&Klo[a];
      } else {      // first V chunk
        size_t a = (size_t)srow * N + jb + sch * 8;
        nrh = *(const uint4*)&Vthi[a];
        nrl = *(const uint4*)&Vtlo[a];
      }
      int kt = t * 32;
      bf16x8 ah[2], al[2], bh[4], bl[4];
#pragma unroll
      for (int tt = 0; tt < 2; tt++) {
        int ar = (wm + tt * 16 + l15) * FWP + kt + quad * 8;
        ah[tt] = *(const bf16x8*)&sQh[ar];
        al[tt] = *(const bf16x8*)&sQl[ar];
      }
#pragma unroll
      for (int tt = 0; tt < 4; tt++) {
        int br = (wn + tt * 16 + l15) * PAD + quad * 8;
        bh[tt] = *(const bf16x8*)&sBh[cur][br];
        bl[tt] = *(const bf16x8*)&sBl[cur][br];
      }
#pragma unroll
      for (int mt = 0; mt < 2; mt++)
#pragma unroll
        for (int nt = 0; nt < 4; nt++) {
          qacc[mt][nt] = __builtin_amdgcn_mfma_f32_16x16x32_bf16(ah[mt], bh[nt], qacc[mt][nt], 0, 0, 0);
          qacc[mt][nt] = __builtin_amdgcn_mfma_f32_16x16x32_bf16(ah[mt], bl[nt], qacc[mt][nt], 0, 0, 0);
          qacc[mt][nt] = __builtin_amdgcn_mfma_f32_16x16x32_bf16(al[mt], bh[nt], qacc[mt][nt], 0, 0, 0);
        }
      *(uint4*)&sBh[cur ^ 1][sls] = nrh;
      *(uint4*)&sBl[cur ^ 1][sls] = nrl;
      __syncthreads();
      cur ^= 1;
    }
    // --- exp epilogue: P to LDS + row sums ---
#pragma unroll
    for (int mt = 0; mt < 2; mt++) {
#pragma unroll
      for (int rg = 0; rg < 4; rg++) {
        int row = wm + mt * 16 + quad * 4 + rg;
        float rs = 0.f;
#pragma unroll
        for (int nt = 0; nt < 4; nt++) {
          float e = (vm[nt] != 0.f) ? __expf(qacc[mt][nt][rg] - 1.f) : 0.f;
          rs += e;
          sP[row * FWP + wn + nt * 16 + l15] = f2bf(e);
        }
#pragma unroll
        for (int d = 1; d < 16; d <<= 1) rs += __shfl_xor(rs, d);
        if (l15 == 0) atomicAdd(&lsum_s[row], rs);
      }
    }
    __syncthreads();
    // --- PV over 4 kt-chunks (ring) ---
#pragma unroll
    for (int t = 0; t < 4; t++) {
      uint4 nrh = {0, 0, 0, 0}, nrl = {0, 0, 0, 0};
      bool have;
      if (t < 3) {  // next V chunk
        have = true;
        size_t a = (size_t)srow * N + jb + (t + 1) * 32 + sch * 8;
        nrh = *(const uint4*)&Vthi[a];
        nrl = *(const uint4*)&Vtlo[a];
      } else {      // first K chunk of next jb
        have = (jb + 128 < j0 + KVC);
        if (have) {
          size_t a = (size_t)(jb + 128 + srow) * 128 + sch * 8;
          nrh = *(const uint4*)&Khi[a];
          nrl = *(const uint4*)&Klo[a];
        }
      }
      int kt = t * 32;
      bf16x8 pa[2], vh[4], vl[4];
#pragma unroll
      for (int tt = 0; tt < 2; tt++) {
        int ar = (wm + tt * 16 + l15) * FWP + kt + quad * 8;
        pa[tt] = *(const bf16x8*)&sP[ar];
      }
#pragma unroll
      for (int tt = 0; tt < 4; tt++) {
        int br = (wn + tt * 16 + l15) * PAD + quad * 8;
        vh[tt] = *(const bf16x8*)&sBh[cur][br];
        vl[tt] = *(const bf16x8*)&sBl[cur][br];
      }
#pragma unroll
      for (int mt = 0; mt < 2; mt++)
#pragma unroll
        for (int nt = 0; nt < 4; nt++) {
          uacc[mt][nt] = __builtin_amdgcn_mfma_f32_16x16x32_bf16(pa[mt], vh[nt], uacc[mt][nt], 0, 0, 0);
          uacc[mt][nt] = __builtin_amdgcn_mfma_f32_16x16x32_bf16(pa[mt], vl[nt], uacc[mt][nt], 0, 0, 0);
        }
      if (have) {
        *(uint4*)&sBh[cur ^ 1][sls] = nrh;
        *(uint4*)&sBl[cur ^ 1][sls] = nrl;
      }
      __syncthreads();
      cur ^= 1;
    }
  }
  // --- write partials ---
  float* pU = partialU + (size_t)z * N * 128;
#pragma unroll
  for (int mt = 0; mt < 2; mt++)
#pragma unroll
    for (int nt = 0; nt < 4; nt++) {
      int col = wn + nt * 16 + l15;
#pragma unroll
      for (int rg = 0; rg < 4; rg++) {
        int row = bm + wm + mt * 16 + quad * 4 + rg;
        pU[(size_t)row * 128 + col] = uacc[mt][nt][rg];
      }
    }
  if (tid < 128) plsum[(size_t)z * N + bm + tid] = lsum_s[tid];
}

// ---------------- bf16 MFMA KN GEMM (split-K): partial[z] = A @ B ------------
__global__ __launch_bounds__(256) void k_mfma_kn(
    const unsigned short* __restrict__ Ahi, const unsigned short* __restrict__ Alo,
    const unsigned short* __restrict__ Bthi, const unsigned short* __restrict__ Btlo,
    float* __restrict__ partial, int lda, int KC) {
  __shared__ __align__(16) unsigned short sAh[128 * PAD];
  __shared__ __align__(16) unsigned short sAl[128 * PAD];
  __shared__ __align__(16) unsigned short sBh[128 * PAD];
  __shared__ __align__(16) unsigned short sBl[128 * PAD];
  int tid = threadIdx.x;
  int bm = blockIdx.y * 128;
  int k0 = blockIdx.z * KC;
  int lane = tid & 63, w = tid >> 6;
  int wm = (w & 1) * 64, wn = (w >> 1) * 64;
  int l15 = lane & 15, quad = lane >> 4;
  f32x4 zero = {0.f, 0.f, 0.f, 0.f};
  f32x4 acc[4][4];
#pragma unroll
  for (int mt = 0; mt < 4; mt++)
#pragma unroll
    for (int nt = 0; nt < 4; nt++) acc[mt][nt] = zero;

  for (int kt = 0; kt < KC; kt += 32) {
#pragma unroll
    for (int q = 0; q < 2; q++) {
      int f = tid * 2 + q;
      int row = f >> 2, ch = f & 3;
      size_t ga = (size_t)(bm + row) * lda + k0 + kt + ch * 8;
      size_t gb = (size_t)row * lda + k0 + kt + ch * 8;
      int ls = row * PAD + ch * 8;
      *(uint4*)&sAh[ls] = *(const uint4*)&Ahi[ga];
      *(uint4*)&sAl[ls] = *(const uint4*)&Alo[ga];
      *(uint4*)&sBh[ls] = *(const uint4*)&Bthi[gb];
      *(uint4*)&sBl[ls] = *(const uint4*)&Btlo[gb];
    }
    __syncthreads();
    bf16x8 ah[4], al[4], bh[4], bl[4];
#pragma unroll
    for (int t = 0; t < 4; t++) {
      int ar = (wm + t * 16 + l15) * PAD + quad * 8;
      ah[t] = *(const bf16x8*)&sAh[ar];
      al[t] = *(const bf16x8*)&sAl[ar];
      int br = (wn + t * 16 + l15) * PAD + quad * 8;
      bh[t] = *(const bf16x8*)&sBh[br];
      bl[t] = *(const bf16x8*)&sBl[br];
    }
#pragma unroll
    for (int mt = 0; mt < 4; mt++)
#pragma unroll
      for (int nt = 0; nt < 4; nt++) {
        acc[mt][nt] = __builtin_amdgcn_mfma_f32_16x16x32_bf16(ah[mt], bh[nt], acc[mt][nt], 0, 0, 0);
        acc[mt][nt] = __builtin_amdgcn_mfma_f32_16x16x32_bf16(ah[mt], bl[nt], acc[mt][nt], 0, 0, 0);
        acc[mt][nt] = __builtin_amdgcn_mfma_f32_16x16x32_bf16(al[mt], bh[nt], acc[mt][nt], 0, 0, 0);
      }
    __syncthreads();
  }
  float* pp = partial + (size_t)blockIdx.z * N * 128;
#pragma unroll
  for (int mt = 0; mt < 4; mt++)
#pragma unroll
    for (int nt = 0; nt < 4; nt++) {
      int col = wn + nt * 16 + l15;
#pragma unroll
      for (int rg = 0; rg < 4; rg++) {
        int row = bm + wm + mt * 16 + quad * 4 + rg;
        pp[(size_t)row * 128 + col] = acc[mt][nt][rg];
      }
    }
}

// ---------------- bf16x3 MFMA genA GEMM (split-K) ----------------
template <int AMODE>
__global__ __launch_bounds__(256) void k_mfma_genA(
    const float* __restrict__ P, const float* __restrict__ mv,
    const float* __restrict__ col1, const float* __restrict__ col2,
    const unsigned short* __restrict__ Bthi, const unsigned short* __restrict__ Btlo,
    float* __restrict__ partial, int KC) {
  __shared__ __align__(16) unsigned short sAh[128 * PAD];
  __shared__ __align__(16) unsigned short sAl[128 * PAD];
  __shared__ __align__(16) unsigned short sBh[128 * PAD];
  __shared__ __align__(16) unsigned short sBl[128 * PAD];
  int tid = threadIdx.x;
  int bm = blockIdx.y * 128;
  int k0 = blockIdx.z * KC;
  int lane = tid & 63, w = tid >> 6;
  int wm = (w & 1) * 64, wn = (w >> 1) * 64;
  int l15 = lane & 15, quad = lane >> 4;
  f32x4 zero = {0.f, 0.f, 0.f, 0.f};
  f32x4 acc[4][4];
#pragma unroll
  for (int mt = 0; mt < 4; mt++)
#pragma unroll
    for (int nt = 0; nt < 4; nt++) acc[mt][nt] = zero;

  for (int kt = 0; kt < KC; kt += 32) {
    int kr = tid >> 3;
    int mc = (tid & 7) * 16;
    int k = k0 + kt + kr;
    float mvk = (AMODE == 1) ? mv[k] : 0.f;
#pragma unroll
    for (int q = 0; q < 4; q++) {
      int m0 = mc + q * 4;
      float4 pv = *(const float4*)&P[(size_t)k * C + bm + m0];
      float4 c1 = *(const float4*)&col1[bm + m0];
      float wv[4];
      if (AMODE == 1) {
        wv[0] = pv.x * mvk / (c1.x * pv.x + 1.f);
        wv[1] = pv.y * mvk / (c1.y * pv.y + 1.f);
        wv[2] = pv.z * mvk / (c1.z * pv.z + 1.f);
        wv[3] = pv.w * mvk / (c1.w * pv.w + 1.f);
      } else {
        float4 c2 = *(const float4*)&col2[bm + m0];
        wv[0] = __expf(pv.x - c1.x) / c2.x;
        wv[1] = __expf(pv.y - c1.y) / c2.y;
        wv[2] = __expf(pv.z - c1.z) / c2.z;
        wv[3] = __expf(pv.w - c1.w) / c2.w;
      }
#pragma unroll
      for (int j = 0; j < 4; j++) {
        unsigned short hh = f2bf(wv[j]);
        sAh[(m0 + j) * PAD + kr] = hh;
        sAl[(m0 + j) * PAD + kr] = f2bf(wv[j] - bf2f(hh));
      }
    }
#pragma unroll
    for (int q = 0; q < 2; q++) {
      int f = q * 256 + tid;
      int row = f >> 2, ch = f & 3;
      size_t gb = (size_t)row * N + k0 + kt + ch * 8;
      int ls = row * PAD + ch * 8;
      *(uint4*)&sBh[ls] = *(const uint4*)&Bthi[gb];
      *(uint4*)&sBl[ls] = *(const uint4*)&Btlo[gb];
    }
    __syncthreads();
    bf16x8 ah[4], al[4], bh[4], bl[4];
#pragma unroll
    for (int t = 0; t < 4; t++) {
      int ar = (wm + t * 16 + l15) * PAD + quad * 8;
      ah[t] = *(const bf16x8*)&sAh[ar];
      al[t] = *(const bf16x8*)&sAl[ar];
      int br = (wn + t * 16 + l15) * PAD + quad * 8;
      bh[t] = *(const bf16x8*)&sBh[br];
      bl[t] = *(const bf16x8*)&sBl[br];
    }
#pragma unroll
    for (int mt = 0; mt < 4; mt++)
#pragma unroll
      for (int nt = 0; nt < 4; nt++) {
        acc[mt][nt] = __builtin_amdgcn_mfma_f32_16x16x32_bf16(ah[mt], bh[nt], acc[mt][nt], 0, 0, 0);
        acc[mt][nt] = __builtin_amdgcn_mfma_f32_16x16x32_bf16(ah[mt], bl[nt], acc[mt][nt], 0, 0, 0);
        acc[mt][nt] = __builtin_amdgcn_mfma_f32_16x16x32_bf16(al[mt], bh[nt], acc[mt][nt], 0, 0, 0);
      }
    __syncthreads();
  }
  float* pp = partial + (size_t)blockIdx.z * C * 128;
#pragma unroll
  for (int mt = 0; mt < 4; mt++)
#pragma unroll
    for (int nt = 0; nt < 4; nt++) {
      int col = wn + nt * 16 + l15;
#pragma unroll
      for (int rg = 0; rg < 4; rg++) {
        int row = bm + wm + mt * 16 + quad * 4 + rg;
        pp[(size_t)row * 128 + col] = acc[mt][nt][rg];
      }
    }
}

__global__ __launch_bounds__(256) void k_scatter(
    const float* __restrict__ mtv, const int* __restrict__ mtj,
    const float* __restrict__ h, float* __restrict__ hidden2,
    float* __restrict__ colsum_m) {
  int i = blockIdx.x * 4 + (threadIdx.x >> 6);
  int lane = threadIdx.x & 63;
  float h0 = h[(size_t)i * H + lane], h1 = h[(size_t)i * H + 64 + lane];
#pragma unroll
  for (int s = 0; s < 3; s++) {
    float v = mtv[i * 3 + s];
    int j = mtj[i * 3 + s];
    atomicAdd(&hidden2[(size_t)j * H + lane], v * h0);
    atomicAdd(&hidden2[(size_t)j * H + 64 + lane], v * h1);
    if (lane == s) atomicAdd(&colsum_m[j], v);
  }
}

// reduce split-K partials; optional per-row scale (mul) or per-row divisor from
// summed per-z lsum partials; optional bf16 hi/lo pair emission; optional
// row-norm / row-valid emission
__global__ __launch_bounds__(256) void k_reduce(
    const float* __restrict__ partial, float* __restrict__ out, int cnt,
    size_t slot, size_t size4, const float* __restrict__ scalem,
    const float* __restrict__ plsum, unsigned short* __restrict__ hi,
    unsigned short* __restrict__ lo, float* __restrict__ nrmout,
    float* __restrict__ validout) {
  size_t idx = (size_t)blockIdx.x * 256 + threadIdx.x;
  if (idx >= size4) return;
  float4 s = {0, 0, 0, 0};
  for (int c = 0; c < cnt; c++) {
    float4 v = *(const float4*)&partial[c * slot + idx * 4];
    s.x += v.x; s.y += v.y; s.z += v.z; s.w += v.w;
  }
  if (scalem) {
    float sc = scalem[idx >> 5];
    s.x *= sc; s.y *= sc; s.z *= sc; s.w *= sc;
  }
  if (plsum) {
    int r = idx >> 5;
    float d = 0.f;
    for (int c = 0; c < cnt; c++) d += plsum[(size_t)c * N + r];
    float sc = 1.f / d;
    s.x *= sc; s.y *= sc; s.z *= sc; s.w *= sc;
  }
  *(float4*)&out[idx * 4] = s;
  if (hi) {
    float vv[4] = {s.x, s.y, s.z, s.w};
    unsigned short h[4], l[4];
#pragma unroll
    for (int c = 0; c < 4; c++) {
      h[c] = f2bf(vv[c]);
      l[c] = f2bf(vv[c] - bf2f(h[c]));
    }
    uint2 ph = {(unsigned)h[0] | ((unsigned)h[1] << 16),
                (unsigned)h[2] | ((unsigned)h[3] << 16)};
    uint2 pl = {(unsigned)l[0] | ((unsigned)l[1] << 16),
                (unsigned)l[2] | ((unsigned)l[3] << 16)};
    *(uint2*)&hi[idx * 4] = ph;
    *(uint2*)&lo[idx * 4] = pl;
  }
  if (nrmout || validout) {
    float rs = s.x + s.y + s.z + s.w;
    float rq = s.x * s.x + s.y * s.y + s.z * s.z + s.w * s.w;
#pragma unroll
    for (int m = 16; m; m >>= 1) { rs += __shfl_xor(rs, m); rq += __shfl_xor(rq, m); }
    if ((threadIdx.x & 31) == 0) {
      if (nrmout) nrmout[idx >> 5] = sqrtf(rq);
      if (validout) validout[idx >> 5] = (rs != 0.f) ? 1.f : 0.f;
    }
  }
}

// ---------------- fused branch-tail kernels ----------------
// Both: 32 output rows per block, full K=128 resident; weights cycled through LDS.

#define LOAD_W(Wt)                                                        \
  do {                                                                    \
    _Pragma("unroll") for (int q = 0; q < 16; q++) {                      \
      int f = q * 256 + tid;                                              \
      int wr = f >> 5, wc = (f & 31) * 4;                                 \
      float4 wv = *(const float4*)&(Wt)[(size_t)wr * 128 + wc];           \
      float ww[4] = {wv.x, wv.y, wv.z, wv.w};                             \
      _Pragma("unroll") for (int c = 0; c < 4; c++) {                     \
        unsigned short hh = f2bf(ww[c]);                                  \
        sWh[wr * WP + wc + c] = hh;                                       \
        sWl[wr * WP + wc + c] = f2bf(ww[c] - bf2f(hh));                   \
      }                                                                   \
    }                                                                     \
  } while (0)

#define GEMM32(accv)                                                              \
  do {                                                                            \
    _Pragma("unroll") for (int nt = 0; nt < 4; nt++) accv[nt] = zero;             \
    _Pragma("unroll") for (int kt = 0; kt < 128; kt += 32) {                      \
      bf16x8 ah = *(const bf16x8*)&sAh[(rt + l15) * WP + kt + quad * 8];          \
      bf16x8 al = *(const bf16x8*)&sAl[(rt + l15) * WP + kt + quad * 8];          \
      _Pragma("unroll") for (int nt = 0; nt < 4; nt++) {                          \
        int br = (ch2 + nt * 16 + l15) * WP + kt + quad * 8;                      \
        bf16x8 bh = *(const bf16x8*)&sWh[br];                                     \
        bf16x8 bl = *(const bf16x8*)&sWl[br];                                     \
        accv[nt] = __builtin_amdgcn_mfma_f32_16x16x32_bf16(ah, bh, accv[nt], 0, 0, 0); \
        accv[nt] = __builtin_amdgcn_mfma_f32_16x16x32_bf16(ah, bl, accv[nt], 0, 0, 0); \
        accv[nt] = __builtin_amdgcn_mfma_f32_16x16x32_bf16(al, bh, accv[nt], 0, 0, 0); \
      }                                                                           \
    }                                                                             \
  } while (0)

// ps tail: p_shared = lin(ps_pre,W_ps); h = x - lin(p_shared,W_psb);
// out_ps = lrelu(lin(p_shared,W_psf)) -> all_info; hhat/pairs/diagv from h.
__global__ __launch_bounds__(256) void k_ps_tail(
    const float* __restrict__ A, const float* __restrict__ x,
    const float* __restrict__ W_ps, const float* __restrict__ b_ps,
    const float* __restrict__ W_psb, const float* __restrict__ b_psb,
    const float* __restrict__ W_psf, const float* __restrict__ b_psf,
    float* __restrict__ hbuf, float* __restrict__ hhat,
    unsigned short* __restrict__ hhi, unsigned short* __restrict__ hlo,
    float* __restrict__ diagv, float* __restrict__ all_info) {
  __shared__ __align__(16) unsigned short sWh[128 * WP];
  __shared__ __align__(16) unsigned short sWl[128 * WP];
  __shared__ __align__(16) unsigned short sAh[32 * WP];
  __shared__ __align__(16) unsigned short sAl[32 * WP];
  __shared__ __align__(16) float sF[32][132];
  int tid = threadIdx.x;
  int bm = blockIdx.x * 32;
  int lane = tid & 63, w = tid >> 6;
  int rt = (w & 1) * 16, ch2 = (w >> 1) * 64;
  int l15 = lane & 15, quad = lane >> 4;
  f32x4 zero = {0.f, 0.f, 0.f, 0.f};
  f32x4 acc[4];

  // stage ps_pre tile -> pairs
  {
    int row = tid >> 3, c0 = (tid & 7) * 16;
    const float* src = &A[(size_t)(bm + row) * 128 + c0];
#pragma unroll
    for (int q = 0; q < 4; q++) {
      float4 v = *(const float4*)&src[q * 4];
      float vv[4] = {v.x, v.y, v.z, v.w};
#pragma unroll
      for (int c = 0; c < 4; c++) {
        unsigned short hh = f2bf(vv[c]);
        sAh[row * WP + c0 + q * 4 + c] = hh;
        sAl[row * WP + c0 + q * 4 + c] = f2bf(vv[c] - bf2f(hh));
      }
    }
  }
  LOAD_W(W_ps);
  __syncthreads();
  GEMM32(acc);  // p_shared (pre-bias)
  __syncthreads();
  // p_shared pairs -> sA
#pragma unroll
  for (int nt = 0; nt < 4; nt++) {
    int col = ch2 + nt * 16 + l15;
    float bv = b_ps[col];
#pragma unroll
    for (int rg = 0; rg < 4; rg++) {
      int row = rt + quad * 4 + rg;
      float v = acc[nt][rg] + bv;
      unsigned short hh = f2bf(v);
      sAh[row * WP + col] = hh;
      sAl[row * WP + col] = f2bf(v - bf2f(hh));
    }
  }
  LOAD_W(W_psb);
  __syncthreads();
  GEMM32(acc);  // p_back (pre-bias)
  // h = x - p_back
#pragma unroll
  for (int nt = 0; nt < 4; nt++) {
    int col = ch2 + nt * 16 + l15;
    float bv = b_psb[col];
#pragma unroll
    for (int rg = 0; rg < 4; rg++) {
      int row = rt + quad * 4 + rg;
      size_t off = (size_t)(bm + row) * 128 + col;
      float hv = x[off] - (acc[nt][rg] + bv);
      hbuf[off] = hv;
      sF[row][col] = hv;
    }
  }
  __syncthreads();
  // hhat substage (reads sF) + load W_psf (disjoint LDS)
  {
    int row = tid >> 3, c0 = (tid & 7) * 16;
    float hv16[16];
    float ssp = 0.f;
#pragma unroll
    for (int q = 0; q < 16; q++) {
      float v = sF[row][c0 + q];
      hv16[q] = v;
      ssp += v * v;
    }
    ssp += __shfl_xor(ssp, 1);
    ssp += __shfl_xor(ssp, 2);
    ssp += __shfl_xor(ssp, 4);
    float ss = ssp;
    float hn = sqrtf(ss);
    float den = hn * hn;
    float dg = (den == 0.f) ? 0.f : ss / den;
    float inv = (ss > 0.f) ? (1.f / hn) : 1.f;
    size_t base = (size_t)(bm + row) * H + c0;
    float va16[16];
    unsigned short hh16[16], ll16[16];
#pragma unroll
    for (int q = 0; q < 16; q++) {
      va16[q] = hv16[q] * inv;
      hh16[q] = f2bf(va16[q]);
      ll16[q] = f2bf(va16[q] - bf2f(hh16[q]));
    }
#pragma unroll
    for (int q4 = 0; q4 < 4; q4++) {
      float4 fv = {va16[q4 * 4], va16[q4 * 4 + 1], va16[q4 * 4 + 2], va16[q4 * 4 + 3]};
      *(float4*)&hhat[base + q4 * 4] = fv;
    }
    uint4 ph0 = {(unsigned)hh16[0] | ((unsigned)hh16[1] << 16), (unsigned)hh16[2] | ((unsigned)hh16[3] << 16),
                 (unsigned)hh16[4] | ((unsigned)hh16[5] << 16), (unsigned)hh16[6] | ((unsigned)hh16[7] << 16)};
    uint4 ph1 = {(unsigned)hh16[8] | ((unsigned)hh16[9] << 16), (unsigned)hh16[10] | ((unsigned)hh16[11] << 16),
                 (unsigned)hh16[12] | ((unsigned)hh16[13] << 16), (unsigned)hh16[14] | ((unsigned)hh16[15] << 16)};
    uint4 pl0 = {(unsigned)ll16[0] | ((unsigned)ll16[1] << 16), (unsigned)ll16[2] | ((unsigned)ll16[3] << 16),
                 (unsigned)ll16[4] | ((unsigned)ll16[5] << 16), (unsigned)ll16[6] | ((unsigned)ll16[7] << 16)};
    uint4 pl1 = {(unsigned)ll16[8] | ((unsigned)ll16[9] << 16), (unsigned)ll16[10] | ((unsigned)ll16[11] << 16),
                 (unsigned)ll16[12] | ((unsigned)ll16[13] << 16), (unsigned)ll16[14] | ((unsigned)ll16[15] << 16)};
    *(uint4*)&hhi[base] = ph0; *(uint4*)&hhi[base + 8] = ph1;
    *(uint4*)&hlo[base] = pl0; *(uint4*)&hlo[base + 8] = pl1;
    if ((tid & 7) == 0) diagv[bm + row] = dg;
  }
  LOAD_W(W_psf);
  __syncthreads();
  GEMM32(acc);  // out_ps (pre-bias)
#pragma unroll
  for (int nt = 0; nt < 4; nt++) {
    int col = ch2 + nt * 16 + l15;
    float bv = b_psf[col];
#pragma unroll
    for (int rg = 0; rg < 4; rg++) {
      int row = rt + quad * 4 + rg;
      size_t off = (size_t)(bm + row) * 128 + col;
      all_info[off] = lrelu(acc[nt][rg] + bv);
    }
  }
}

// hs tail: h_shared = lin(hs_pre,W_hs); all = all_info + lrelu(lin(h_shared,W_hsf));
// indiv = h - lin(h_shared,W_hsb); all += lrelu(lin(indiv,W_in)); out = all @ W_out + b.
__global__ __launch_bounds__(256) void k_hs_tail(
    const float* __restrict__ A, const float* __restrict__ hbuf,
    const float* __restrict__ all_info,
    const float* __restrict__ W_hs, const float* __restrict__ b_hs,
    const float* __restrict__ W_hsf, const float* __restrict__ b_hsf,
    const float* __restrict__ W_hsb, const float* __restrict__ b_hsb,
    const float* __restrict__ W_in, const float* __restrict__ b_in,
    const float* __restrict__ W_out, const float* __restrict__ b_out,
    float* __restrict__ out) {
  __shared__ __align__(16) unsigned short sWh[128 * WP];
  __shared__ __align__(16) unsigned short sWl[128 * WP];
  __shared__ __align__(16) unsigned short sAh[32 * WP];
  __shared__ __align__(16) unsigned short sAl[32 * WP];
  __shared__ __align__(16) float sF[32][132];
  int tid = threadIdx.x;
  int bm = blockIdx.x * 32;
  int lane = tid & 63, w = tid >> 6;
  int rt = (w & 1) * 16, ch2 = (w >> 1) * 64;
  int l15 = lane & 15, quad = lane >> 4;
  f32x4 zero = {0.f, 0.f, 0.f, 0.f};
  f32x4 acc[4];
  float allv[4][4];

  // stage hs_pre tile -> pairs
  {
    int row = tid >> 3, c0 = (tid & 7) * 16;
    const float* src = &A[(size_t)(bm + row) * 128 + c0];
#pragma unroll
    for (int q = 0; q < 4; q++) {
      float4 v = *(const float4*)&src[q * 4];
      float vv[4] = {v.x, v.y, v.z, v.w};
#pragma unroll
      for (int c = 0; c < 4; c++) {
        unsigned short hh = f2bf(vv[c]);
        sAh[row * WP + c0 + q * 4 + c] = hh;
        sAl[row * WP + c0 + q * 4 + c] = f2bf(vv[c] - bf2f(hh));
      }
    }
  }
  LOAD_W(W_hs);
  __syncthreads();
  GEMM32(acc);  // h_shared (pre-bias)
  __syncthreads();
  // h_shared pairs -> sA
#pragma unroll
  for (int nt = 0; nt < 4; nt++) {
    int col = ch2 + nt * 16 + l15;
    float bv = b_hs[col];
#pragma unroll
    for (int rg = 0; rg < 4; rg++) {
      int row = rt + quad * 4 + rg;
      float v = acc[nt][rg] + bv;
      unsigned short hh = f2bf(v);
      sAh[row * WP + col] = hh;
      sAl[row * WP + col] = f2bf(v - bf2f(hh));
    }
  }
  LOAD_W(W_hsf);
  __syncthreads();
  GEMM32(acc);  // out_hs (pre-bias)
#pragma unroll
  for (int nt = 0; nt < 4; nt++) {
    int col = ch2 + nt * 16 + l15;
    float bv = b_hsf[col];
#pragma unroll
    for (int rg = 0; rg < 4; rg++) {
      int row = rt + quad * 4 + rg;
      size_t off = (size_t)(bm + row) * 128 + col;
      allv[nt][rg] = all_info[off] + lrelu(acc[nt][rg] + bv);
    }
  }
  __syncthreads();  // all reads of sWh done
  LOAD_W(W_hsb);
  __syncthreads();
  GEMM32(acc);  // h_back (pre-bias)
  // indiv = h - h_back
  float iv[4][4];
#pragma unroll
  for (int nt = 0; nt < 4; nt++) {
    int col = ch2 + nt * 16 + l15;
    float bv = b_hsb[col];
#pragma unroll
    for (int rg = 0; rg < 4; rg++) {
      int row = rt + quad * 4 + rg;
      size_t off = (size_t)(bm + row) * 128 + col;
      iv[nt][rg] = hbuf[off] - (acc[nt][rg] + bv);
    }
  }
  __syncthreads();  // all reads of sA (h_shared) done
  // indiv pairs -> sA
#pragma unroll
  for (int nt = 0; nt < 4; nt++) {
    int col = ch2 + nt * 16 + l15;
#pragma unroll
    for (int rg = 0; rg < 4; rg++) {
      int row = rt + quad * 4 + rg;
      unsigned short hh = f2bf(iv[nt][rg]);
      sAh[row * WP + col] = hh;
      sAl[row * WP + col] = f2bf(iv[nt][rg] - bf2f(hh));
    }
  }
  LOAD_W(W_in);
  __syncthreads();
  GEMM32(acc);  // out_indi (pre-bias)
#pragma unroll
  for (int nt = 0; nt < 4; nt++) {
    int col = ch2 + nt * 16 + l15;
    float bv = b_in[col];
#pragma unroll
    for (int rg = 0; rg < 4; rg++) {
      int row = rt + quad * 4 + rg;
      allv[nt][rg] += lrelu(acc[nt][rg] + bv);
      sF[row][col] = allv[nt][rg];
    }
  }
  __syncthreads();
  // final: out[row] = dot(all_info_row, W_out) + b_out
  {
    int row = tid >> 3, c0 = (tid & 7) * 16;
    float s = 0.f;
#pragma unroll
    for (int q = 0; q < 16; q++) s += sF[row][c0 + q] * W_out[c0 + q];
    s += __shfl_xor(s, 1);
    s += __shfl_xor(s, 2);
    s += __shfl_xor(s, 4);
    if ((tid & 7) == 0) out[bm + row] = s + b_out[0];
  }
}

// ---------------- launch ----------------

extern "C" void kernel_launch(void* const* d_in, const int* in_sizes, int n_in,
                              void* d_out, int out_size, void* d_ws, size_t ws_size,
                              hipStream_t stream) {
  (void)in_sizes; (void)n_in; (void)out_size; (void)ws_size;
  const float* x   = (const float*)d_in[0];
  const float* cm  = (const float*)d_in[1];
  const float* mv  = (const float*)d_in[2];
  const float* W_ps = (const float*)d_in[3],  *b_ps = (const float*)d_in[4];
  const float* W_psf = (const float*)d_in[5], *b_psf = (const float*)d_in[6];
  const float* W_psb = (const float*)d_in[7], *b_psb = (const float*)d_in[8];
  const float* W_hs = (const float*)d_in[9],  *b_hs = (const float*)d_in[10];
  const float* W_hsf = (const float*)d_in[11], *b_hsf = (const float*)d_in[12];
  const float* W_hsb = (const float*)d_in[13], *b_hsb = (const float*)d_in[14];
  const float* W_in = (const float*)d_in[15], *b_in = (const float*)d_in[16];
  const float* W_out = (const float*)d_in[17], *b_out = (const float*)d_in[18];
  float* out = (float*)d_out;

  float* W = (float*)d_ws;
  size_t o = 0;
  auto alloc = [&](size_t n) { float* p = W + o; o += n; return p; };
  float* colsum_c = alloc(C);
  float* colmax   = alloc(C);
  float* colsumexp= alloc(C);
  float* valid1   = alloc(C);
  float* hnorm_ps = alloc(C);
  float* xnorm    = alloc(N);
  float* diagv    = alloc(N);
  float* colsum_m = alloc(N);
  float* valid2f  = alloc(N);
  float* plsum    = alloc((size_t)8 * N);
  float* mtv      = alloc(3 * N);
  int*   mtj      = (int*)alloc(3 * N);
  float* hidden1  = alloc((size_t)C * H);
  float* hidden_ps= alloc((size_t)C * H);
  float* scores   = alloc((size_t)N * C);
  float* ps_pre   = alloc((size_t)N * H);   // later hs_pre
  float* all_info = alloc((size_t)N * H);
  float* hbuf     = alloc((size_t)N * H);   // h
  float* hhat     = alloc((size_t)N * H);
  float* hidden2  = alloc((size_t)N * H);
  unsigned short* xhi    = (unsigned short*)alloc((size_t)N * H / 2);
  unsigned short* xlo    = (unsigned short*)alloc((size_t)N * H / 2);
  unsigned short* hhathi = (unsigned short*)alloc((size_t)N * H / 2);
  unsigned short* hhatlo = (unsigned short*)alloc((size_t)N * H / 2);
  unsigned short* h2hi   = (unsigned short*)alloc((size_t)N * H / 2);
  unsigned short* h2lo   = (unsigned short*)alloc((size_t)N * H / 2);
  unsigned short* h1hi   = (unsigned short*)alloc((size_t)C * H / 2);
  unsigned short* h1lo   = (unsigned short*)alloc((size_t)C * H / 2);
  unsigned short* hpshi  = (unsigned short*)alloc((size_t)C * H / 2);
  unsigned short* hpslo  = (unsigned short*)alloc((size_t)C * H / 2);
  unsigned short* cshi   = (unsigned short*)alloc((size_t)N * C / 2);
  unsigned short* cslo   = (unsigned short*)alloc((size_t)N * C / 2);
  unsigned short* hpst_hi= (unsigned short*)alloc((size_t)H * C / 2);
  unsigned short* hpst_lo= (unsigned short*)alloc((size_t)H * C / 2);
  unsigned short* h2t_hi = (unsigned short*)alloc((size_t)H * N / 2);
  unsigned short* h2t_lo = (unsigned short*)alloc((size_t)H * N / 2);
  unsigned short* xt_hi  = (unsigned short*)alloc((size_t)H * N / 2);
  unsigned short* xt_lo  = (unsigned short*)alloc((size_t)H * N / 2);
  float2* cand    = (float2*)alloc((size_t)N * 128 * 5 * 2);
  float* partial  = W + o;
  const int Z = 8;        // flash split-KV (8*N*128 fp32 = 16.8 MB)
  const int ZG = 64;      // genA split-K (64*C*128 fp32 = 16.8 MB); same region
  const int ZK = 8;       // cs-GEMM split-K (8*N*128 fp32 = 16.8 MB); same region

  hipMemsetAsync(colsum_c, 0, C * sizeof(float), stream);
  hipMemsetAsync(colsum_m, 0, N * sizeof(float), stream);
  hipMemsetAsync(hidden2, 0, (size_t)N * H * sizeof(float), stream);

  dim3 blk(256);
  // --- ps branch ---
  k_split<<<dim3(N * H / 1024), blk, 0, stream>>>(x, xhi, xlo, xnorm);
  k_tsplit<<<dim3(N / 32), blk, 0, stream>>>(x, xt_hi, xt_lo, N);
  k_colsum_s2c<<<dim3(C / 64, 16), dim3(64), 0, stream>>>(cm, mv, colsum_c);
  k_mfma_genA<1><<<dim3(1, C / 128, ZG), blk, 0, stream>>>(
      cm, mv, colsum_c, nullptr, xt_hi, xt_lo, partial, N / ZG);
  k_reduce<<<dim3(C * H / 4 / 256), blk, 0, stream>>>(
      partial, hidden1, ZG, (size_t)C * H, (size_t)C * H / 4, nullptr, nullptr,
      h1hi, h1lo, nullptr, valid1);
  k_mfma_nt<<<dim3(C / 128, N / 64), blk, 0, stream>>>(
      xhi, xlo, h1hi, h1lo, scores, C);
  k_colstats<<<dim3(C), blk, 0, stream>>>(scores, colmax, colsumexp);
  k_mfma_genA<2><<<dim3(1, C / 128, ZG), blk, 0, stream>>>(
      scores, nullptr, colmax, colsumexp, xt_hi, xt_lo, partial, N / ZG);
  k_reduce<<<dim3(C * H / 4 / 256), blk, 0, stream>>>(
      partial, hidden_ps, ZG, (size_t)C * H, (size_t)C * H / 4, valid1, nullptr,
      hpshi, hpslo, hnorm_ps, nullptr);
  k_mfma_nt<<<dim3(C / 128, N / 64), blk, 0, stream>>>(
      xhi, xlo, hpshi, hpslo, scores, C);
  k_cs_softmax<<<dim3(N), blk, 0, stream>>>(scores, xnorm, hnorm_ps, valid1,
                                            cshi, cslo);
  k_tsplit<<<dim3(C / 32), blk, 0, stream>>>(hidden_ps, hpst_hi, hpst_lo, C);
  k_mfma_kn<<<dim3(1, N / 128, ZK), blk, 0, stream>>>(
      cshi, cslo, hpst_hi, hpst_lo, partial, C, C / ZK);
  k_reduce<<<dim3(N * H / 4 / 256), blk, 0, stream>>>(
      partial, ps_pre, ZK, (size_t)N * H, (size_t)N * H / 4, nullptr, nullptr,
      nullptr, nullptr, nullptr, nullptr);
  k_ps_tail<<<dim3(N / 32), blk, 0, stream>>>(
      ps_pre, x, W_ps, b_ps, W_psb, b_psb, W_psf, b_psf,
      hbuf, hhat, hhathi, hhatlo, diagv, all_info);
  // --- hs branch ---
  k_snt<<<dim3(N / 128, N / 128), dim3(512), 0, stream>>>(
      hhathi, hhatlo, cand);
  k_rowtop2<<<dim3(N / 4), blk, 0, stream>>>(cand, hhat, mtv, mtj);
  k_scatter<<<dim3(N / 4), blk, 0, stream>>>(mtv, mtj, hbuf, hidden2, colsum_m);
  k_fin_hidden2<<<dim3(N), dim3(64), 0, stream>>>(hbuf, diagv, colsum_m, hidden2,
                                                  h2hi, h2lo, valid2f);
  k_tsplit<<<dim3(N / 32), blk, 0, stream>>>(hidden2, h2t_hi, h2t_lo, N);
  k_flash<<<dim3(Z, N / 128), dim3(512), 0, stream>>>(
      hhathi, hhatlo, h2hi, h2lo, h2t_hi, h2t_lo, valid2f, partial, plsum,
      N / Z);
  k_reduce<<<dim3(N * H / 4 / 256), blk, 0, stream>>>(
      partial, ps_pre, Z, (size_t)N * H, (size_t)N * H / 4, nullptr, plsum,
      nullptr, nullptr, nullptr, nullptr);  // hs_pre = U / l
  k_hs_tail<<<dim3(N / 32), blk, 0, stream>>>(
      ps_pre, hbuf, all_info, W_hs, b_hs, W_hsf, b_hsf, W_hsb, b_hsb,
      W_in, b_in, W_out, b_out, out);
}

// Round 9
// 356.858 us; speedup vs baseline: 1.0789x; 1.0346x over previous
//
#include <hip/hip_runtime.h>
#include <hip/hip_fp16.h>
#include <math.h>

#define N 4096
#define C 512
#define H 128
#define PAD 40  // ushort row pitch for 32-col MFMA LDS staging tiles
#define WP 136  // ushort row pitch for full-K (128 col) LDS tiles
#define FWP 136 // ushort row pitch for flash Q/P tiles
#define SP 136  // ushort row pitch for S-tile scan buffer

typedef __attribute__((ext_vector_type(8))) short bf16x8;
typedef __attribute__((ext_vector_type(4))) float f32x4;

// ---------------- helpers ----------------

__device__ inline float wave_reduce_sum(float v) {
#pragma unroll
  for (int m = 32; m; m >>= 1) v += __shfl_xor(v, m);
  return v;
}

__device__ inline float lrelu(float v) { return v > 0.f ? v : 0.01f * v; }

__device__ inline bool better(float v, int j, float w, int k) {
  return (v > w) || (v == w && j < k);
}

__device__ inline void top3_ins(float v, int j, float& v0, int& j0,
                                float& v1, int& j1, float& v2, int& j2) {
  if (better(v, j, v0, j0)) { v2 = v1; j2 = j1; v1 = v0; j1 = j0; v0 = v; j0 = j; }
  else if (better(v, j, v1, j1)) { v2 = v1; j2 = j1; v1 = v; j1 = j; }
  else if (better(v, j, v2, j2)) { v2 = v; j2 = j; }
}

__device__ inline void ins5(float s, int j, float v[5], int jx[5]) {
  if (!better(s, j, v[4], jx[4])) return;
  if (better(s, j, v[0], jx[0])) {
    v[4]=v[3]; jx[4]=jx[3]; v[3]=v[2]; jx[3]=jx[2]; v[2]=v[1]; jx[2]=jx[1];
    v[1]=v[0]; jx[1]=jx[0]; v[0]=s; jx[0]=j;
  } else if (better(s, j, v[1], jx[1])) {
    v[4]=v[3]; jx[4]=jx[3]; v[3]=v[2]; jx[3]=jx[2]; v[2]=v[1]; jx[2]=jx[1];
    v[1]=s; jx[1]=j;
  } else if (better(s, j, v[2], jx[2])) {
    v[4]=v[3]; jx[4]=jx[3]; v[3]=v[2]; jx[3]=jx[2]; v[2]=s; jx[2]=j;
  } else if (better(s, j, v[3], jx[3])) {
    v[4]=v[3]; jx[4]=jx[3]; v[3]=s; jx[3]=j;
  } else {
    v[4]=s; jx[4]=j;
  }
}

__device__ inline unsigned short f2bf(float f) {
  unsigned u = __float_as_uint(f);
  unsigned r = u + 0x7fffu + ((u >> 16) & 1u);
  return (unsigned short)(r >> 16);
}
__device__ inline float bf2f(unsigned short h) {
  return __uint_as_float(((unsigned)h) << 16);
}

// ---- x prep: linear pairs + xnorm + transposed pairs + workspace zeroing ----
__global__ __launch_bounds__(256) void k_xprep(
    const float* __restrict__ in, unsigned short* __restrict__ hi,
    unsigned short* __restrict__ lo, float* __restrict__ nrm,
    unsigned short* __restrict__ thi, unsigned short* __restrict__ tlo,
    float* __restrict__ hidden2, float* __restrict__ colsum_c,
    float* __restrict__ colsum_m) {
  __shared__ float tile[32][132];
  int r0 = blockIdx.x * 32, tid = threadIdx.x;
  float4 zf = {0.f, 0.f, 0.f, 0.f};
#pragma unroll
  for (int q = 0; q < 4; q++) {
    size_t zi = ((size_t)blockIdx.x * 1024 + q * 256 + tid) * 4;
    *(float4*)&hidden2[zi] = zf;
  }
  if (blockIdx.x == 0 && tid < 128) *(float4*)&colsum_c[tid * 4] = zf;
  if (blockIdx.x == 1) {
#pragma unroll
    for (int q = 0; q < 4; q++) *(float4*)&colsum_m[(q * 256 + tid) * 4] = zf;
  }
#pragma unroll
  for (int q = 0; q < 4; q++) {
    int f = q * 256 + tid;
    int row = f >> 5, ch = f & 31;
    size_t gi = (size_t)(r0 + row) * 128 + ch * 4;
    float4 v = *(const float4*)&in[gi];
    *(float4*)&tile[row][ch * 4] = v;
    float vv[4] = {v.x, v.y, v.z, v.w};
    unsigned short hq[4], lq[4];
    float ss = 0.f;
#pragma unroll
    for (int c = 0; c < 4; c++) {
      ss += vv[c] * vv[c];
      hq[c] = f2bf(vv[c]);
      lq[c] = f2bf(vv[c] - bf2f(hq[c]));
    }
    uint2 ph = {(unsigned)hq[0] | ((unsigned)hq[1] << 16),
                (unsigned)hq[2] | ((unsigned)hq[3] << 16)};
    uint2 pl = {(unsigned)lq[0] | ((unsigned)lq[1] << 16),
                (unsigned)lq[2] | ((unsigned)lq[3] << 16)};
    *(uint2*)&hi[gi] = ph;
    *(uint2*)&lo[gi] = pl;
#pragma unroll
    for (int m = 16; m; m >>= 1) ss += __shfl_xor(ss, m);
    if ((tid & 31) == 0) nrm[r0 + row] = sqrtf(ss);
  }
  __syncthreads();
  int c = tid & 127, half = tid >> 7;
  unsigned short hh[16], ll[16];
#pragma unroll
  for (int rr = 0; rr < 16; rr++) {
    float v = tile[half * 16 + rr][c];
    hh[rr] = f2bf(v);
    ll[rr] = f2bf(v - bf2f(hh[rr]));
  }
  size_t off = (size_t)c * N + r0 + half * 16;
  uint4 ph0 = {(unsigned)hh[0] | ((unsigned)hh[1] << 16), (unsigned)hh[2] | ((unsigned)hh[3] << 16),
               (unsigned)hh[4] | ((unsigned)hh[5] << 16), (unsigned)hh[6] | ((unsigned)hh[7] << 16)};
  uint4 ph1 = {(unsigned)hh[8] | ((unsigned)hh[9] << 16), (unsigned)hh[10] | ((unsigned)hh[11] << 16),
               (unsigned)hh[12] | ((unsigned)hh[13] << 16), (unsigned)hh[14] | ((unsigned)hh[15] << 16)};
  uint4 pl0 = {(unsigned)ll[0] | ((unsigned)ll[1] << 16), (unsigned)ll[2] | ((unsigned)ll[3] << 16),
               (unsigned)ll[4] | ((unsigned)ll[5] << 16), (unsigned)ll[6] | ((unsigned)ll[7] << 16)};
  uint4 pl1 = {(unsigned)ll[8] | ((unsigned)ll[9] << 16), (unsigned)ll[10] | ((unsigned)ll[11] << 16),
               (unsigned)ll[12] | ((unsigned)ll[13] << 16), (unsigned)ll[14] | ((unsigned)ll[15] << 16)};
  *(uint4*)&thi[off] = ph0; *(uint4*)&thi[off + 8] = ph1;
  *(uint4*)&tlo[off] = pl0; *(uint4*)&tlo[off + 8] = pl1;
}

// transpose + split: in [R,128] fp32 -> thi/tlo [128,R] ushort
__global__ __launch_bounds__(256) void k_tsplit(const float* __restrict__ in,
                                                unsigned short* __restrict__ thi,
                                                unsigned short* __restrict__ tlo,
                                                int R) {
  __shared__ float tile[32][132];
  int r0 = blockIdx.x * 32, tid = threadIdx.x;
#pragma unroll
  for (int q = 0; q < 4; q++) {
    int f = q * 256 + tid;
    int row = f >> 5, ch = f & 31;
    *(float4*)&tile[row][ch * 4] = *(const float4*)&in[(size_t)(r0 + row) * 128 + ch * 4];
  }
  __syncthreads();
  int c = tid & 127, half = tid >> 7;
  unsigned short hh[16], ll[16];
#pragma unroll
  for (int rr = 0; rr < 16; rr++) {
    float v = tile[half * 16 + rr][c];
    hh[rr] = f2bf(v);
    ll[rr] = f2bf(v - bf2f(hh[rr]));
  }
  size_t off = (size_t)c * R + r0 + half * 16;
  uint4 ph0 = {(unsigned)hh[0] | ((unsigned)hh[1] << 16), (unsigned)hh[2] | ((unsigned)hh[3] << 16),
               (unsigned)hh[4] | ((unsigned)hh[5] << 16), (unsigned)hh[6] | ((unsigned)hh[7] << 16)};
  uint4 ph1 = {(unsigned)hh[8] | ((unsigned)hh[9] << 16), (unsigned)hh[10] | ((unsigned)hh[11] << 16),
               (unsigned)hh[12] | ((unsigned)hh[13] << 16), (unsigned)hh[14] | ((unsigned)hh[15] << 16)};
  uint4 pl0 = {(unsigned)ll[0] | ((unsigned)ll[1] << 16), (unsigned)ll[2] | ((unsigned)ll[3] << 16),
               (unsigned)ll[4] | ((unsigned)ll[5] << 16), (unsigned)ll[6] | ((unsigned)ll[7] << 16)};
  uint4 pl1 = {(unsigned)ll[8] | ((unsigned)ll[9] << 16), (unsigned)ll[10] | ((unsigned)ll[11] << 16),
               (unsigned)ll[12] | ((unsigned)ll[13] << 16), (unsigned)ll[14] | ((unsigned)ll[15] << 16)};
  *(uint4*)&thi[off] = ph0; *(uint4*)&thi[off + 8] = ph1;
  *(uint4*)&tlo[off] = pl0; *(uint4*)&tlo[off + 8] = pl1;
}

// ---------------- small kernels ----------------

__global__ __launch_bounds__(64) void k_colsum_s2c(
    const float* __restrict__ cm, const float* __restrict__ mv,
    float* __restrict__ colsum_c) {
  int c = blockIdx.x * 64 + threadIdx.x;
  int i0 = blockIdx.y * 256;
  float acc = 0.f;
  for (int i = i0; i < i0 + 256; i++) acc += cm[(size_t)i * C + c] * mv[i];
  atomicAdd(&colsum_c[c], acc);
}

__global__ __launch_bounds__(256) void k_colstats(const float* __restrict__ sc,
                                                  float* __restrict__ colmax,
                                                  float* __restrict__ colsum) {
  __shared__ float red[256];
  int c = blockIdx.x, t = threadIdx.x;
  float v[16];
  float m = -3e38f;
#pragma unroll
  for (int q = 0; q < 16; q++) {
    v[q] = sc[(size_t)(q * 256 + t) * C + c];
    m = fmaxf(m, v[q]);
  }
  red[t] = m; __syncthreads();
  for (int s = 128; s; s >>= 1) { if (t < s) red[t] = fmaxf(red[t], red[t + s]); __syncthreads(); }
  m = red[0]; __syncthreads();
  float sum = 0.f;
#pragma unroll
  for (int q = 0; q < 16; q++) sum += __expf(v[q] - m);
  red[t] = sum; __syncthreads();
  for (int s = 128; s; s >>= 1) { if (t < s) red[t] += red[t + s]; __syncthreads(); }
  if (t == 0) { colmax[c] = m; colsum[c] = red[0]; }
}

// row softmax of cos-sim -> bf16 hi/lo pairs
__global__ __launch_bounds__(256) void k_cs_softmax(
    const float* __restrict__ sc, const float* __restrict__ xnorm,
    const float* __restrict__ hnorm, const float* __restrict__ valid1,
    unsigned short* __restrict__ cshi, unsigned short* __restrict__ cslo) {
  __shared__ float red[256];
  int i = blockIdx.x, t = threadIdx.x;
  float xn = xnorm[i];
  float r0 = sc[(size_t)i * C + t], r1 = sc[(size_t)i * C + 256 + t];
  float d0 = xn * hnorm[t], d1 = xn * hnorm[256 + t];
  float c0 = r0 / (d0 == 0.f ? 1.f : d0);
  float c1 = r1 / (d1 == 0.f ? 1.f : d1);
  float s0 = (valid1[t] != 0.f) ? c0 : -3e38f;
  float s1 = (valid1[256 + t] != 0.f) ? c1 : -3e38f;
  red[t] = fmaxf(s0, s1); __syncthreads();
  for (int s = 128; s; s >>= 1) { if (t < s) red[t] = fmaxf(red[t], red[t + s]); __syncthreads(); }
  float m = red[0]; __syncthreads();
  float p0 = (s0 > -1e37f) ? __expf(s0 - m) : 0.f;
  float p1 = (s1 > -1e37f) ? __expf(s1 - m) : 0.f;
  red[t] = p0 + p1; __syncthreads();
  for (int s = 128; s; s >>= 1) { if (t < s) red[t] += red[t + s]; __syncthreads(); }
  float inv = 1.f / red[0];
  float a = p0 * inv, b = p1 * inv;
  unsigned short ha = f2bf(a), hb = f2bf(b);
  cshi[(size_t)i * C + t] = ha;
  cslo[(size_t)i * C + t] = f2bf(a - bf2f(ha));
  cshi[(size_t)i * C + 256 + t] = hb;
  cslo[(size_t)i * C + 256 + t] = f2bf(b - bf2f(hb));
}

// finalize hidden2 (32 rows/block) + h2hat pairs + valid2f + transposed pairs
__global__ __launch_bounds__(256) void k_fin2t(
    const float* __restrict__ h, const float* __restrict__ diagv,
    const float* __restrict__ colsum_m, float* __restrict__ hidden2,
    unsigned short* __restrict__ h2hi, unsigned short* __restrict__ h2lo,
    float* __restrict__ valid2f, unsigned short* __restrict__ thi,
    unsigned short* __restrict__ tlo) {
  __shared__ float tile[32][132];
  int j0 = blockIdx.x * 32, tid = threadIdx.x;
  int row = tid >> 3, c0 = (tid & 7) * 16;
  int j = j0 + row;
  float add = (colsum_m[j] != 0.f) ? diagv[j] : 0.f;
  float a16[16];
  float s = 0.f, ss = 0.f;
#pragma unroll
  for (int q = 0; q < 16; q++) {
    float a = hidden2[(size_t)j * H + c0 + q] + add * h[(size_t)j * H + c0 + q];
    a16[q] = a;
    s += a; ss += a * a;
  }
#pragma unroll
  for (int m = 4; m; m >>= 1) { s += __shfl_xor(s, m); ss += __shfl_xor(ss, m); }
  bool valid = (s != 0.f);
  float inv = (valid && ss > 0.f) ? (1.f / sqrtf(ss)) : 1.f;
  size_t base = (size_t)j * H + c0;
  unsigned short hh16[16], ll16[16];
#pragma unroll
  for (int q = 0; q < 16; q++) {
    a16[q] = valid ? a16[q] : 0.f;
    float va = a16[q] * inv;
    hh16[q] = f2bf(va);
    ll16[q] = f2bf(va - bf2f(hh16[q]));
    tile[row][c0 + q] = a16[q];
  }
#pragma unroll
  for (int q4 = 0; q4 < 4; q4++) {
    float4 fv = {a16[q4 * 4], a16[q4 * 4 + 1], a16[q4 * 4 + 2], a16[q4 * 4 + 3]};
    *(float4*)&hidden2[base + q4 * 4] = fv;
  }
  uint4 ph0 = {(unsigned)hh16[0] | ((unsigned)hh16[1] << 16), (unsigned)hh16[2] | ((unsigned)hh16[3] << 16),
               (unsigned)hh16[4] | ((unsigned)hh16[5] << 16), (unsigned)hh16[6] | ((unsigned)hh16[7] << 16)};
  uint4 ph1 = {(unsigned)hh16[8] | ((unsigned)hh16[9] << 16), (unsigned)hh16[10] | ((unsigned)hh16[11] << 16),
               (unsigned)hh16[12] | ((unsigned)hh16[13] << 16), (unsigned)hh16[14] | ((unsigned)hh16[15] << 16)};
  uint4 pl0 = {(unsigned)ll16[0] | ((unsigned)ll16[1] << 16), (unsigned)ll16[2] | ((unsigned)ll16[3] << 16),
               (unsigned)ll16[4] | ((unsigned)ll16[5] << 16), (unsigned)ll16[6] | ((unsigned)ll16[7] << 16)};
  uint4 pl1 = {(unsigned)ll16[8] | ((unsigned)ll16[9] << 16), (unsigned)ll16[10] | ((unsigned)ll16[11] << 16),
               (unsigned)ll16[12] | ((unsigned)ll16[13] << 16), (unsigned)ll16[14] | ((unsigned)ll16[15] << 16)};
  *(uint4*)&h2hi[base] = ph0; *(uint4*)&h2hi[base + 8] = ph1;
  *(uint4*)&h2lo[base] = pl0; *(uint4*)&h2lo[base + 8] = pl1;
  if ((tid & 7) == 0) valid2f[j] = valid ? 1.f : 0.f;
  __syncthreads();
  int c = tid & 127, half = tid >> 7;
  unsigned short th[16], tl[16];
#pragma unroll
  for (int rr = 0; rr < 16; rr++) {
    float v = tile[half * 16 + rr][c];
    th[rr] = f2bf(v);
    tl[rr] = f2bf(v - bf2f(th[rr]));
  }
  size_t off = (size_t)c * N + j0 + half * 16;
  uint4 tp0 = {(unsigned)th[0] | ((unsigned)th[1] << 16), (unsigned)th[2] | ((unsigned)th[3] << 16),
               (unsigned)th[4] | ((unsigned)th[5] << 16), (unsigned)th[6] | ((unsigned)th[7] << 16)};
  uint4 tp1 = {(unsigned)th[8] | ((unsigned)th[9] << 16), (unsigned)th[10] | ((unsigned)th[11] << 16),
               (unsigned)th[12] | ((unsigned)th[13] << 16), (unsigned)th[14] | ((unsigned)th[15] << 16)};
  uint4 tq0 = {(unsigned)tl[0] | ((unsigned)tl[1] << 16), (unsigned)tl[2] | ((unsigned)tl[3] << 16),
               (unsigned)tl[4] | ((unsigned)tl[5] << 16), (unsigned)tl[6] | ((unsigned)tl[7] << 16)};
  uint4 tq1 = {(unsigned)tl[8] | ((unsigned)tl[9] << 16), (unsigned)tl[10] | ((unsigned)tl[11] << 16),
               (unsigned)tl[12] | ((unsigned)tl[13] << 16), (unsigned)tl[14] | ((unsigned)tl[15] << 16)};
  *(uint4*)&thi[off] = tp0; *(uint4*)&thi[off + 8] = tp1;
  *(uint4*)&tlo[off] = tq0; *(uint4*)&tlo[off + 8] = tq1;
}

// ---------------- bf16x3 MFMA NT GEMM: A[64,128] @ B[128,128]^T, fp32 out ----
__global__ __launch_bounds__(256) void k_mfma_nt(
    const unsigned short* __restrict__ Ahi, const unsigned short* __restrict__ Alo,
    const unsigned short* __restrict__ Bhi, const unsigned short* __restrict__ Blo,
    float* __restrict__ out, int Nn) {
  __shared__ __align__(16) unsigned short sAh[64 * PAD];
  __shared__ __align__(16) unsigned short sAl[64 * PAD];
  __shared__ __align__(16) unsigned short sBh[128 * PAD];
  __shared__ __align__(16) unsigned short sBl[128 * PAD];
  int tid = threadIdx.x;
  int bm = blockIdx.y * 64, bn = blockIdx.x * 128;
  int lane = tid & 63, w = tid >> 6;
  int wm = (w & 1) * 32, wn = (w >> 1) * 64;
  int l15 = lane & 15, quad = lane >> 4;
  f32x4 zero = {0.f, 0.f, 0.f, 0.f};
  f32x4 acc[2][4];
#pragma unroll
  for (int mt = 0; mt < 2; mt++)
#pragma unroll
    for (int nt = 0; nt < 4; nt++) acc[mt][nt] = zero;

  for (int kt = 0; kt < 128; kt += 32) {
    {
      int row = tid >> 2, ch = tid & 3;
      size_t ga = (size_t)(bm + row) * 128 + kt + ch * 8;
      int ls = row * PAD + ch * 8;
      *(uint4*)&sAh[ls] = *(const uint4*)&Ahi[ga];
      *(uint4*)&sAl[ls] = *(const uint4*)&Alo[ga];
    }
#pragma unroll
    for (int q = 0; q < 2; q++) {
      int f = q * 256 + tid;
      int row = f >> 2, ch = f & 3;
      size_t gb = (size_t)(bn + row) * 128 + kt + ch * 8;
      int ls = row * PAD + ch * 8;
      *(uint4*)&sBh[ls] = *(const uint4*)&Bhi[gb];
      *(uint4*)&sBl[ls] = *(const uint4*)&Blo[gb];
    }
    __syncthreads();
    bf16x8 ah[2], al[2], bh[4], bl[4];
#pragma unroll
    for (int t = 0; t < 2; t++) {
      int ar = (wm + t * 16 + l15) * PAD + quad * 8;
      ah[t] = *(const bf16x8*)&sAh[ar];
      al[t] = *(const bf16x8*)&sAl[ar];
    }
#pragma unroll
    for (int t = 0; t < 4; t++) {
      int br = (wn + t * 16 + l15) * PAD + quad * 8;
      bh[t] = *(const bf16x8*)&sBh[br];
      bl[t] = *(const bf16x8*)&sBl[br];
    }
#pragma unroll
    for (int mt = 0; mt < 2; mt++)
#pragma unroll
      for (int nt = 0; nt < 4; nt++) {
        acc[mt][nt] = __builtin_amdgcn_mfma_f32_16x16x32_bf16(ah[mt], bh[nt], acc[mt][nt], 0, 0, 0);
        acc[mt][nt] = __builtin_amdgcn_mfma_f32_16x16x32_bf16(ah[mt], bl[nt], acc[mt][nt], 0, 0, 0);
        acc[mt][nt] = __builtin_amdgcn_mfma_f32_16x16x32_bf16(al[mt], bh[nt], acc[mt][nt], 0, 0, 0);
      }
    __syncthreads();
  }
#pragma unroll
  for (int mt = 0; mt < 2; mt++) {
#pragma unroll
    for (int nt = 0; nt < 4; nt++) {
      int col = bn + wn + nt * 16 + l15;
#pragma unroll
      for (int rg = 0; rg < 4; rg++) {
        int row = bm + wm + mt * 16 + quad * 4 + rg;
        out[(size_t)row * Nn + col] = acc[mt][nt][rg];
      }
    }
  }
}

// ---------------- S = hhat@hhat^T + fused quarter-row top-5 screen -----------
__global__ __launch_bounds__(512) void k_snt(
    const unsigned short* __restrict__ Ahi, const unsigned short* __restrict__ Alo,
    float2* __restrict__ cand) {
  __shared__ __align__(16) unsigned short sAh[128 * PAD];
  __shared__ __align__(16) unsigned short sAl[128 * PAD];
  __shared__ __align__(16) unsigned short sBh[128 * PAD];
  __shared__ __align__(16) unsigned short sBl[128 * PAD];
  __shared__ __align__(16) unsigned short sS[128 * SP];
  int tid = threadIdx.x;
  int bm = blockIdx.y * 128, bn = blockIdx.x * 128;
  int lane = tid & 63, w = tid >> 6;
  int wm = (w & 3) * 32, wn = (w >> 2) * 64;
  int l15 = lane & 15, quad = lane >> 4;
  f32x4 zero = {0.f, 0.f, 0.f, 0.f};
  f32x4 acc[2][4];
#pragma unroll
  for (int mt = 0; mt < 2; mt++)
#pragma unroll
    for (int nt = 0; nt < 4; nt++) acc[mt][nt] = zero;

  for (int kt = 0; kt < 128; kt += 32) {
    {
      int row = tid >> 2, ch = tid & 3;
      size_t ga = (size_t)(bm + row) * 128 + kt + ch * 8;
      size_t gb = (size_t)(bn + row) * 128 + kt + ch * 8;
      int ls = row * PAD + ch * 8;
      *(uint4*)&sAh[ls] = *(const uint4*)&Ahi[ga];
      *(uint4*)&sAl[ls] = *(const uint4*)&Alo[ga];
      *(uint4*)&sBh[ls] = *(const uint4*)&Ahi[gb];
      *(uint4*)&sBl[ls] = *(const uint4*)&Alo[gb];
    }
    __syncthreads();
    bf16x8 ah[2], al[2], bh[4], bl[4];
#pragma unroll
    for (int t = 0; t < 2; t++) {
      int ar = (wm + t * 16 + l15) * PAD + quad * 8;
      ah[t] = *(const bf16x8*)&sAh[ar];
      al[t] = *(const bf16x8*)&sAl[ar];
    }
#pragma unroll
    for (int t = 0; t < 4; t++) {
      int br = (wn + t * 16 + l15) * PAD + quad * 8;
      bh[t] = *(const bf16x8*)&sBh[br];
      bl[t] = *(const bf16x8*)&sBl[br];
    }
#pragma unroll
    for (int mt = 0; mt < 2; mt++)
#pragma unroll
      for (int nt = 0; nt < 4; nt++) {
        acc[mt][nt] = __builtin_amdgcn_mfma_f32_16x16x32_bf16(ah[mt], bh[nt], acc[mt][nt], 0, 0, 0);
        acc[mt][nt] = __builtin_amdgcn_mfma_f32_16x16x32_bf16(ah[mt], bl[nt], acc[mt][nt], 0, 0, 0);
        acc[mt][nt] = __builtin_amdgcn_mfma_f32_16x16x32_bf16(al[mt], bh[nt], acc[mt][nt], 0, 0, 0);
      }
    __syncthreads();
  }
#pragma unroll
  for (int mt = 0; mt < 2; mt++)
#pragma unroll
    for (int nt = 0; nt < 4; nt++) {
      int coll = wn + nt * 16 + l15;
#pragma unroll
      for (int rg = 0; rg < 4; rg++) {
        int rowl = wm + mt * 16 + quad * 4 + rg;
        float v = (bm + rowl == bn + coll) ? 0.f : acc[mt][nt][rg];
        sS[rowl * SP + coll] = __half_as_ushort(__float2half(v));
      }
    }
  __syncthreads();
  int r = tid >> 2, qf = tid & 3;
  const unsigned short* rowp = &sS[r * SP + qf * 32];
  int cbase = bn + qf * 32;
  float v5[5] = {-3e38f, -3e38f, -3e38f, -3e38f, -3e38f};
  int j5[5] = {0x7fffffff, 0x7fffffff, 0x7fffffff, 0x7fffffff, 0x7fffffff};
#pragma unroll
  for (int q = 0; q < 4; q++) {
    uint4 p = *(const uint4*)&rowp[q * 8];
    unsigned pk[4] = {p.x, p.y, p.z, p.w};
#pragma unroll
    for (int c2 = 0; c2 < 4; c2++) {
      float e0 = __half2float(__ushort_as_half((unsigned short)(pk[c2] & 0xffffu)));
      float e1 = __half2float(__ushort_as_half((unsigned short)(pk[c2] >> 16)));
      ins5(e0, cbase + q * 8 + c2 * 2, v5, j5);
      ins5(e1, cbase + q * 8 + c2 * 2 + 1, v5, j5);
    }
  }
  int slot = (bn >> 5) + qf;
  float2* cp = &cand[((size_t)(bm + r) * 128 + slot) * 5];
#pragma unroll
  for (int c2 = 0; c2 < 5; c2++) cp[c2] = {v5[c2], __int_as_float(j5[c2])};
}

// -------- row top-k merge + exact fp32 rescore + fused scatter --------
__global__ __launch_bounds__(256) void k_rowtop2s(
    const float2* __restrict__ cand, const float* __restrict__ hhat,
    const float* __restrict__ h, float* __restrict__ hidden2,
    float* __restrict__ colsum_m) {
  int i = blockIdx.x * 4 + (threadIdx.x >> 6);
  int lane = threadIdx.x & 63;
  const float2* cr = &cand[(size_t)i * 640];
  float v[5] = {-3e38f, -3e38f, -3e38f, -3e38f, -3e38f};
  int jx[5] = {0x7fffffff, 0x7fffffff, 0x7fffffff, 0x7fffffff, 0x7fffffff};
#pragma unroll
  for (int c = 0; c < 10; c++) {
    float2 p = cr[lane * 10 + c];
    ins5(p.x, __float_as_int(p.y), v, jx);
  }
#pragma unroll
  for (int d = 1; d < 64; d <<= 1) {
    float fv[5]; int fj[5];
#pragma unroll
    for (int c = 0; c < 5; c++) { fv[c] = __shfl_xor(v[c], d); fj[c] = __shfl_xor(jx[c], d); }
#pragma unroll
    for (int c = 0; c < 5; c++) ins5(fv[c], fj[c], v, jx);
  }
  const float* hi = &hhat[(size_t)i * H];
  float b0 = -3e38f, b1 = -3e38f, b2 = -3e38f;
  int q0 = 0, q1 = 0, q2 = 0;
#pragma unroll
  for (int c = 0; c < 5; c++) {
    int j = jx[c];
    float s;
    if (j == i) {
      s = 0.f;
    } else {
      const float* hj = &hhat[(size_t)j * H];
      float p = hi[lane] * hj[lane] + hi[lane + 64] * hj[lane + 64];
      s = wave_reduce_sum(p);
    }
    top3_ins(s, j, b0, q0, b1, q1, b2, q2);
  }
  // fused scatter (all 64 lanes hold identical b/q)
  float h0 = h[(size_t)i * H + lane], h1 = h[(size_t)i * H + 64 + lane];
  float bv[3] = {b0, b1, b2};
  int qv[3] = {q0, q1, q2};
#pragma unroll
  for (int s = 0; s < 3; s++) {
    float vv = bv[s];
    int j = qv[s];
    atomicAdd(&hidden2[(size_t)j * H + lane], vv * h0);
    atomicAdd(&hidden2[(size_t)j * H + 64 + lane], vv * h1);
    if (lane == s) atomicAdd(&colsum_m[j], vv);
  }
}

// ---------------- flash-fused hs_pre numerator (ring double-buffer) ----------
__global__ __launch_bounds__(512) void k_flash(
    const unsigned short* __restrict__ Qhi, const unsigned short* __restrict__ Qlo,
    const unsigned short* __restrict__ Khi, const unsigned short* __restrict__ Klo,
    const unsigned short* __restrict__ Vthi, const unsigned short* __restrict__ Vtlo,
    const float* __restrict__ valid2f, float* __restrict__ partialU,
    float* __restrict__ plsum, int KVC) {
  __shared__ __align__(16) unsigned short sQh[128 * FWP];
  __shared__ __align__(16) unsigned short sQl[128 * FWP];
  __shared__ __align__(16) unsigned short sP[128 * FWP];
  __shared__ __align__(16) unsigned short sBh[2][128 * PAD];
  __shared__ __align__(16) unsigned short sBl[2][128 * PAD];
  __shared__ float lsum_s[128];
  int tid = threadIdx.x;
  int z = blockIdx.x;
  int bm = blockIdx.y * 128;
  int j0 = z * KVC;
  int lane = tid & 63, w = tid >> 6;
  int wm = (w & 3) * 32, wn = (w >> 2) * 64;
  int l15 = lane & 15, quad = lane >> 4;
  int srow = tid >> 2, sch = tid & 3;
  int sls = srow * PAD + sch * 8;
#pragma unroll
  for (int q = 0; q < 4; q++) {
    int f = q * 512 + tid;
    int row = f >> 4, ch = f & 15;
    size_t ga = (size_t)(bm + row) * 128 + ch * 8;
    int ls = row * FWP + ch * 8;
    *(uint4*)&sQh[ls] = *(const uint4*)&Qhi[ga];
    *(uint4*)&sQl[ls] = *(const uint4*)&Qlo[ga];
  }
  if (tid < 128) lsum_s[tid] = 0.f;
  {
    size_t a = (size_t)(j0 + srow) * 128 + sch * 8;
    uint4 rh = *(const uint4*)&Khi[a];
    uint4 rl = *(const uint4*)&Klo[a];
    __syncthreads();
    *(uint4*)&sBh[0][sls] = rh;
    *(uint4*)&sBl[0][sls] = rl;
  }
  __syncthreads();
  int cur = 0;
  f32x4 zero = {0.f, 0.f, 0.f, 0.f};
  f32x4 uacc[2][4];
#pragma unroll
  for (int mt = 0; mt < 2; mt++)
#pragma unroll
    for (int nt = 0; nt < 4; nt++) uacc[mt][nt] = zero;

  for (int jb = j0; jb < j0 + KVC; jb += 128) {
    float vm[4];
#pragma unroll
    for (int nt = 0; nt < 4; nt++) vm[nt] = valid2f[jb + wn + nt * 16 + l15];
    f32x4 qacc[2][4];
#pragma unroll
    for (int mt = 0; mt < 2; mt++)
#pragma unroll
      for (int nt = 0; nt < 4; nt++) qacc[mt][nt] = zero;
#pragma unroll
    for (int t = 0; t < 4; t++) {
      uint4 nrh, nrl;
      if (t < 3) {
        size_t a = (size_t)(jb + srow) * 128 + (t + 1) * 32 + sch * 8;
        nrh = *(const uint4*)&Khi[a];
        nrl = *(const uint4*)&Klo[a];
      } else {
        size_t a = (size_t)srow * N + jb + sch * 8;
        nrh = *(const uint4*)&Vthi[a];
        nrl = *(const uint4*)&Vtlo[a];
      }
      int kt = t * 32;
      bf16x8 ah[2], al[2], bh[4], bl[4];
#pragma unroll
      for (int tt = 0; tt < 2; tt++) {
        int ar = (wm + tt * 16 + l15) * FWP + kt + quad * 8;
        ah[tt] = *(const bf16x8*)&sQh[ar];
        al[tt] = *(const bf16x8*)&sQl[ar];
      }
#pragma unroll
      for (int tt = 0; tt < 4; tt++) {
        int br = (wn + tt * 16 + l15) * PAD + quad * 8;
        bh[tt] = *(const bf16x8*)&sBh[cur][br];
        bl[tt] = *(const bf16x8*)&sBl[cur][br];
      }
#pragma unroll
      for (int mt = 0; mt < 2; mt++)
#pragma unroll
        for (int nt = 0; nt < 4; nt++) {
          qacc[mt][nt] = __builtin_amdgcn_mfma_f32_16x16x32_bf16(ah[mt], bh[nt], qacc[mt][nt], 0, 0, 0);
          qacc[mt][nt] = __builtin_amdgcn_mfma_f32_16x16x32_bf16(ah[mt], bl[nt], qacc[mt][nt], 0, 0, 0);
          qacc[mt][nt] = __builtin_amdgcn_mfma_f32_16x16x32_bf16(al[mt], bh[nt], qacc[mt][nt], 0, 0, 0);
        }
      *(uint4*)&sBh[cur ^ 1][sls] = nrh;
      *(uint4*)&sBl[cur ^ 1][sls] = nrl;
      __syncthreads();
      cur ^= 1;
    }
#pragma unroll
    for (int mt = 0; mt < 2; mt++) {
#pragma unroll
      for (int rg = 0; rg < 4; rg++) {
        int row = wm + mt * 16 + quad * 4 + rg;
        float rs = 0.f;
#pragma unroll
        for (int nt = 0; nt < 4; nt++) {
          float e = (vm[nt] != 0.f) ? __expf(qacc[mt][nt][rg] - 1.f) : 0.f;
          rs += e;
          sP[row * FWP + wn + nt * 16 + l15] = f2bf(e);
        }
#pragma unroll
        for (int d = 1; d < 16; d <<= 1) rs += __shfl_xor(rs, d);
        if (l15 == 0) atomicAdd(&lsum_s[row], rs);
      }
    }
    __syncthreads();
#pragma unroll
    for (int t = 0; t < 4; t++) {
      uint4 nrh = {0, 0, 0, 0}, nrl = {0, 0, 0, 0};
      bool have;
      if (t < 3) {
        have = true;
        size_t a = (size_t)srow * N + jb + (t + 1) * 32 + sch * 8;
        nrh = *(const uint4*)&Vthi[a];
        nrl = *(const uint4*)&Vtlo[a];
      } else {
        have = (jb + 128 < j0 + KVC);
        if (have) {
          size_t a = (size_t)(jb + 128 + srow) * 128 + sch * 8;
          nrh = *(const uint4*)&Khi[a];
          nrl = *(const uint4*)&Klo[a];
        }
      }
      int kt = t * 32;
      bf16x8 pa[2], vh[4], vl[4];
#pragma unroll
      for (int tt = 0; tt < 2; tt++) {
        int ar = (wm + tt * 16 + l15) * FWP + kt + quad * 8;
        pa[tt] = *(const bf16x8*)&sP[ar];
      }
#pragma unroll
      for (int tt = 0; tt < 4; tt++) {
        int br = (wn + tt * 16 + l15) * PAD + quad * 8;
        vh[tt] = *(const bf16x8*)&sBh[cur][br];
        vl[tt] = *(const bf16x8*)&sBl[cur][br];
      }
#pragma unroll
      for (int mt = 0; mt < 2; mt++)
#pragma unroll
        for (int nt = 0; nt < 4; nt++) {
          uacc[mt][nt] = __builtin_amdgcn_mfma_f32_16x16x32_bf16(pa[mt], vh[nt], uacc[mt][nt], 0, 0, 0);
          uacc[mt][nt] = __builtin_amdgcn_mfma_f32_16x16x32_bf16(pa[mt], vl[nt], uacc[mt][nt], 0, 0, 0);
        }
      if (have) {
        *(uint4*)&sBh[cur ^ 1][sls] = nrh;
        *(uint4*)&sBl[cur ^ 1][sls] = nrl;
      }
      __syncthreads();
      cur ^= 1;
    }
  }
  float* pU = partialU + (size_t)z * N * 128;
#pragma unroll
  for (int mt = 0; mt < 2; mt++)
#pragma unroll
    for (int nt = 0; nt < 4; nt++) {
      int col = wn + nt * 16 + l15;
#pragma unroll
      for (int rg = 0; rg < 4; rg++) {
        int row = bm + wm + mt * 16 + quad * 4 + rg;
        pU[(size_t)row * 128 + col] = uacc[mt][nt][rg];
      }
    }
  if (tid < 128) plsum[(size_t)z * N + bm + tid] = lsum_s[tid];
}

// ---------------- bf16 MFMA KN GEMM (split-K): partial[z] = A @ B ------------
__global__ __launch_bounds__(256) void k_mfma_kn(
    const unsigned short* __restrict__ Ahi, const unsigned short* __restrict__ Alo,
    const unsigned short* __restrict__ Bthi, const unsigned short* __restrict__ Btlo,
    float* __restrict__ partial, int lda, int KC) {
  __shared__ __align__(16) unsigned short sAh[128 * PAD];
  __shared__ __align__(16) unsigned short sAl[128 * PAD];
  __shared__ __align__(16) unsigned short sBh[128 * PAD];
  __shared__ __align__(16) unsigned short sBl[128 * PAD];
  int tid = threadIdx.x;
  int bm = blockIdx.y * 128;
  int k0 = blockIdx.z * KC;
  int lane = tid & 63, w = tid >> 6;
  int wm = (w & 1) * 64, wn = (w >> 1) * 64;
  int l15 = lane & 15, quad = lane >> 4;
  f32x4 zero = {0.f, 0.f, 0.f, 0.f};
  f32x4 acc[4][4];
#pragma unroll
  for (int mt = 0; mt < 4; mt++)
#pragma unroll
    for (int nt = 0; nt < 4; nt++) acc[mt][nt] = zero;

  for (int kt = 0; kt < KC; kt += 32) {
#pragma unroll
    for (int q = 0; q < 2; q++) {
      int f = tid * 2 + q;
      int row = f >> 2, ch = f & 3;
      size_t ga = (size_t)(bm + row) * lda + k0 + kt + ch * 8;
      size_t gb = (size_t)row * lda + k0 + kt + ch * 8;
      int ls = row * PAD + ch * 8;
      *(uint4*)&sAh[ls] = *(const uint4*)&Ahi[ga];
      *(uint4*)&sAl[ls] = *(const uint4*)&Alo[ga];
      *(uint4*)&sBh[ls] = *(const uint4*)&Bthi[gb];
      *(uint4*)&sBl[ls] = *(const uint4*)&Btlo[gb];
    }
    __syncthreads();
    bf16x8 ah[4], al[4], bh[4], bl[4];
#pragma unroll
    for (int t = 0; t < 4; t++) {
      int ar = (wm + t * 16 + l15) * PAD + quad * 8;
      ah[t] = *(const bf16x8*)&sAh[ar];
      al[t] = *(const bf16x8*)&sAl[ar];
      int br = (wn + t * 16 + l15) * PAD + quad * 8;
      bh[t] = *(const bf16x8*)&sBh[br];
      bl[t] = *(const bf16x8*)&sBl[br];
    }
#pragma unroll
    for (int mt = 0; mt < 4; mt++)
#pragma unroll
      for (int nt = 0; nt < 4; nt++) {
        acc[mt][nt] = __builtin_amdgcn_mfma_f32_16x16x32_bf16(ah[mt], bh[nt], acc[mt][nt], 0, 0, 0);
        acc[mt][nt] = __builtin_amdgcn_mfma_f32_16x16x32_bf16(ah[mt], bl[nt], acc[mt][nt], 0, 0, 0);
        acc[mt][nt] = __builtin_amdgcn_mfma_f32_16x16x32_bf16(al[mt], bh[nt], acc[mt][nt], 0, 0, 0);
      }
    __syncthreads();
  }
  float* pp = partial + (size_t)blockIdx.z * N * 128;
#pragma unroll
  for (int mt = 0; mt < 4; mt++)
#pragma unroll
    for (int nt = 0; nt < 4; nt++) {
      int col = wn + nt * 16 + l15;
#pragma unroll
      for (int rg = 0; rg < 4; rg++) {
        int row = bm + wm + mt * 16 + quad * 4 + rg;
        pp[(size_t)row * 128 + col] = acc[mt][nt][rg];
      }
    }
}

// ---------------- bf16x3 MFMA genA GEMM (split-K) ----------------
template <int AMODE>
__global__ __launch_bounds__(256) void k_mfma_genA(
    const float* __restrict__ P, const float* __restrict__ mv,
    const float* __restrict__ col1, const float* __restrict__ col2,
    const unsigned short* __restrict__ Bthi, const unsigned short* __restrict__ Btlo,
    float* __restrict__ partial, int KC) {
  __shared__ __align__(16) unsigned short sAh[128 * PAD];
  __shared__ __align__(16) unsigned short sAl[128 * PAD];
  __shared__ __align__(16) unsigned short sBh[128 * PAD];
  __shared__ __align__(16) unsigned short sBl[128 * PAD];
  int tid = threadIdx.x;
  int bm = blockIdx.y * 128;
  int k0 = blockIdx.z * KC;
  int lane = tid & 63, w = tid >> 6;
  int wm = (w & 1) * 64, wn = (w >> 1) * 64;
  int l15 = lane & 15, quad = lane >> 4;
  f32x4 zero = {0.f, 0.f, 0.f, 0.f};
  f32x4 acc[4][4];
#pragma unroll
  for (int mt = 0; mt < 4; mt++)
#pragma unroll
    for (int nt = 0; nt < 4; nt++) acc[mt][nt] = zero;

  for (int kt = 0; kt < KC; kt += 32) {
    int kr = tid >> 3;
    int mc = (tid & 7) * 16;
    int k = k0 + kt + kr;
    float mvk = (AMODE == 1) ? mv[k] : 0.f;
#pragma unroll
    for (int q = 0; q < 4; q++) {
      int m0 = mc + q * 4;
      float4 pv = *(const float4*)&P[(size_t)k * C + bm + m0];
      float4 c1 = *(const float4*)&col1[bm + m0];
      float wv[4];
      if (AMODE == 1) {
        wv[0] = pv.x * mvk / (c1.x * pv.x + 1.f);
        wv[1] = pv.y * mvk / (c1.y * pv.y + 1.f);
        wv[2] = pv.z * mvk / (c1.z * pv.z + 1.f);
        wv[3] = pv.w * mvk / (c1.w * pv.w + 1.f);
      } else {
        float4 c2 = *(const float4*)&col2[bm + m0];
        wv[0] = __expf(pv.x - c1.x) / c2.x;
        wv[1] = __expf(pv.y - c1.y) / c2.y;
        wv[2] = __expf(pv.z - c1.z) / c2.z;
        wv[3] = __expf(pv.w - c1.w) / c2.w;
      }
#pragma unroll
      for (int j = 0; j < 4; j++) {
        unsigned short hh = f2bf(wv[j]);
        sAh[(m0 + j) * PAD + kr] = hh;
        sAl[(m0 + j) * PAD + kr] = f2bf(wv[j] - bf2f(hh));
      }
    }
#pragma unroll
    for (int q = 0; q < 2; q++) {
      int f = q * 256 + tid;
      int row = f >> 2, ch = f & 3;
      size_t gb = (size_t)row * N + k0 + kt + ch * 8;
      int ls = row * PAD + ch * 8;
      *(uint4*)&sBh[ls] = *(const uint4*)&Bthi[gb];
      *(uint4*)&sBl[ls] = *(const uint4*)&Btlo[gb];
    }
    __syncthreads();
    bf16x8 ah[4], al[4], bh[4], bl[4];
#pragma unroll
    for (int t = 0; t < 4; t++) {
      int ar = (wm + t * 16 + l15) * PAD + quad * 8;
      ah[t] = *(const bf16x8*)&sAh[ar];
      al[t] = *(const bf16x8*)&sAl[ar];
      int br = (wn + t * 16 + l15) * PAD + quad * 8;
      bh[t] = *(const bf16x8*)&sBh[br];
      bl[t] = *(const bf16x8*)&sBl[br];
    }
#pragma unroll
    for (int mt = 0; mt < 4; mt++)
#pragma unroll
      for (int nt = 0; nt < 4; nt++) {
        acc[mt][nt] = __builtin_amdgcn_mfma_f32_16x16x32_bf16(ah[mt], bh[nt], acc[mt][nt], 0, 0, 0);
        acc[mt][nt] = __builtin_amdgcn_mfma_f32_16x16x32_bf16(ah[mt], bl[nt], acc[mt][nt], 0, 0, 0);
        acc[mt][nt] = __builtin_amdgcn_mfma_f32_16x16x32_bf16(al[mt], bh[nt], acc[mt][nt], 0, 0, 0);
      }
    __syncthreads();
  }
  float* pp = partial + (size_t)blockIdx.z * C * 128;
#pragma unroll
  for (int mt = 0; mt < 4; mt++)
#pragma unroll
    for (int nt = 0; nt < 4; nt++) {
      int col = wn + nt * 16 + l15;
#pragma unroll
      for (int rg = 0; rg < 4; rg++) {
        int row = bm + wm + mt * 16 + quad * 4 + rg;
        pp[(size_t)row * 128 + col] = acc[mt][nt][rg];
      }
    }
}

// reduce split-K partials (C*H shapes); optional per-row scale; pair emission;
// row-norm / row-valid emission
__global__ __launch_bounds__(256) void k_reduce(
    const float* __restrict__ partial, float* __restrict__ out, int cnt,
    size_t slot, size_t size4, const float* __restrict__ scalem,
    unsigned short* __restrict__ hi, unsigned short* __restrict__ lo,
    float* __restrict__ nrmout, float* __restrict__ validout) {
  size_t idx = (size_t)blockIdx.x * 256 + threadIdx.x;
  if (idx >= size4) return;
  float4 s = {0, 0, 0, 0};
  for (int c = 0; c < cnt; c++) {
    float4 v = *(const float4*)&partial[c * slot + idx * 4];
    s.x += v.x; s.y += v.y; s.z += v.z; s.w += v.w;
  }
  if (scalem) {
    float sc = scalem[idx >> 5];
    s.x *= sc; s.y *= sc; s.z *= sc; s.w *= sc;
  }
  *(float4*)&out[idx * 4] = s;
  if (hi) {
    float vv[4] = {s.x, s.y, s.z, s.w};
    unsigned short h[4], l[4];
#pragma unroll
    for (int c = 0; c < 4; c++) {
      h[c] = f2bf(vv[c]);
      l[c] = f2bf(vv[c] - bf2f(h[c]));
    }
    uint2 ph = {(unsigned)h[0] | ((unsigned)h[1] << 16),
                (unsigned)h[2] | ((unsigned)h[3] << 16)};
    uint2 pl = {(unsigned)l[0] | ((unsigned)l[1] << 16),
                (unsigned)l[2] | ((unsigned)l[3] << 16)};
    *(uint2*)&hi[idx * 4] = ph;
    *(uint2*)&lo[idx * 4] = pl;
  }
  if (nrmout || validout) {
    float rs = s.x + s.y + s.z + s.w;
    float rq = s.x * s.x + s.y * s.y + s.z * s.z + s.w * s.w;
#pragma unroll
    for (int m = 16; m; m >>= 1) { rs += __shfl_xor(rs, m); rq += __shfl_xor(rq, m); }
    if ((threadIdx.x & 31) == 0) {
      if (nrmout) nrmout[idx >> 5] = sqrtf(rq);
      if (validout) validout[idx >> 5] = (rs != 0.f) ? 1.f : 0.f;
    }
  }
}

// ---------------- fused branch-tail kernels ----------------

#define LOAD_W(Wt)                                                        \
  do {                                                                    \
    _Pragma("unroll") for (int q = 0; q < 16; q++) {                      \
      int f = q * 256 + tid;                                              \
      int wr = f >> 5, wc = (f & 31) * 4;                                 \
      float4 wv = *(const float4*)&(Wt)[(size_t)wr * 128 + wc];           \
      float ww[4] = {wv.x, wv.y, wv.z, wv.w};                             \
      _Pragma("unroll") for (int c = 0; c < 4; c++) {                     \
        unsigned short hh = f2bf(ww[c]);                                  \
        sWh[wr * WP + wc + c] = hh;                                       \
        sWl[wr * WP + wc + c] = f2bf(ww[c] - bf2f(hh));                   \
      }                                                                   \
    }                                                                     \
  } while (0)

#define GEMM32(accv)                                                              \
  do {                                                                            \
    _Pragma("unroll") for (int nt = 0; nt < 4; nt++) accv[nt] = zero;             \
    _Pragma("unroll") for (int kt = 0; kt < 128; kt += 32) {                      \
      bf16x8 ah = *(const bf16x8*)&sAh[(rt + l15) * WP + kt + quad * 8];          \
      bf16x8 al = *(const bf16x8*)&sAl[(rt + l15) * WP + kt + quad * 8];          \
      _Pragma("unroll") for (int nt = 0; nt < 4; nt++) {                          \
        int br = (ch2 + nt * 16 + l15) * WP + kt + quad * 8;                      \
        bf16x8 bh = *(const bf16x8*)&sWh[br];                                     \
        bf16x8 bl = *(const bf16x8*)&sWl[br];                                     \
        accv[nt] = __builtin_amdgcn_mfma_f32_16x16x32_bf16(ah, bh, accv[nt], 0, 0, 0); \
        accv[nt] = __builtin_amdgcn_mfma_f32_16x16x32_bf16(ah, bl, accv[nt], 0, 0, 0); \
        accv[nt] = __builtin_amdgcn_mfma_f32_16x16x32_bf16(al, bh, accv[nt], 0, 0, 0); \
      }                                                                           \
    }                                                                             \
  } while (0)

// ps tail: ps_pre = sum_z partial; p_shared = lin(ps_pre,W_ps);
// h = x - lin(p_shared,W_psb); out_ps -> all_info; hhat/pairs/diagv from h.
__global__ __launch_bounds__(256) void k_ps_tail(
    const float* __restrict__ partial, int zcnt, const float* __restrict__ x,
    const float* __restrict__ W_ps, const float* __restrict__ b_ps,
    const float* __restrict__ W_psb, const float* __restrict__ b_psb,
    const float* __restrict__ W_psf, const float* __restrict__ b_psf,
    float* __restrict__ hbuf, float* __restrict__ hhat,
    unsigned short* __restrict__ hhi, unsigned short* __restrict__ hlo,
    float* __restrict__ diagv, float* __restrict__ all_info) {
  __shared__ __align__(16) unsigned short sWh[128 * WP];
  __shared__ __align__(16) unsigned short sWl[128 * WP];
  __shared__ __align__(16) unsigned short sAh[32 * WP];
  __shared__ __align__(16) unsigned short sAl[32 * WP];
  __shared__ __align__(16) float sF[32][132];
  int tid = threadIdx.x;
  int bm = blockIdx.x * 32;
  int lane = tid & 63, w = tid >> 6;
  int rt = (w & 1) * 16, ch2 = (w >> 1) * 64;
  int l15 = lane & 15, quad = lane >> 4;
  f32x4 zero = {0.f, 0.f, 0.f, 0.f};
  f32x4 acc[4];

  // stage ps_pre tile (sum of split-K partials) -> pairs
  {
    int row = tid >> 3, c0 = (tid & 7) * 16;
    size_t off0 = (size_t)(bm + row) * 128 + c0;
#pragma unroll
    for (int q = 0; q < 4; q++) {
      float vv[4] = {0.f, 0.f, 0.f, 0.f};
      for (int z = 0; z < zcnt; z++) {
        float4 v = *(const float4*)&partial[(size_t)z * N * H + off0 + q * 4];
        vv[0] += v.x; vv[1] += v.y; vv[2] += v.z; vv[3] += v.w;
      }
#pragma unroll
      for (int c = 0; c < 4; c++) {
        unsigned short hh = f2bf(vv[c]);
        sAh[row * WP + c0 + q * 4 + c] = hh;
        sAl[row * WP + c0 + q * 4 + c] = f2bf(vv[c] - bf2f(hh));
      }
    }
  }
  LOAD_W(W_ps);
  __syncthreads();
  GEMM32(acc);  // p_shared (pre-bias)
  __syncthreads();
#pragma unroll
  for (int nt = 0; nt < 4; nt++) {
    int col = ch2 + nt * 16 + l15;
    float bv = b_ps[col];
#pragma unroll
    for (int rg = 0; rg < 4; rg++) {
      int row = rt + quad * 4 + rg;
      float v = acc[nt][rg] + bv;
      unsigned short hh = f2bf(v);
      sAh[row * WP + col] = hh;
      sAl[row * WP + col] = f2bf(v - bf2f(hh));
    }
  }
  LOAD_W(W_psb);
  __syncthreads();
  GEMM32(acc);  // p_back (pre-bias)
#pragma unroll
  for (int nt = 0; nt < 4; nt++) {
    int col = ch2 + nt * 16 + l15;
    float bv = b_psb[col];
#pragma unroll
    for (int rg = 0; rg < 4; rg++) {
      int row = rt + quad * 4 + rg;
      size_t off = (size_t)(bm + row) * 128 + col;
      float hv = x[off] - (acc[nt][rg] + bv);
      hbuf[off] = hv;
      sF[row][col] = hv;
    }
  }
  __syncthreads();
  {
    int row = tid >> 3, c0 = (tid & 7) * 16;
    float hv16[16];
    float ssp = 0.f;
#pragma unroll
    for (int q = 0; q < 16; q++) {
      float v = sF[row][c0 + q];
      hv16[q] = v;
      ssp += v * v;
    }
    ssp += __shfl_xor(ssp, 1);
    ssp += __shfl_xor(ssp, 2);
    ssp += __shfl_xor(ssp, 4);
    float ss = ssp;
    float hn = sqrtf(ss);
    float den = hn * hn;
    float dg = (den == 0.f) ? 0.f : ss / den;
    float inv = (ss > 0.f) ? (1.f / hn) : 1.f;
    size_t base = (size_t)(bm + row) * H + c0;
    float va16[16];
    unsigned short hh16[16], ll16[16];
#pragma unroll
    for (int q = 0; q < 16; q++) {
      va16[q] = hv16[q] * inv;
      hh16[q] = f2bf(va16[q]);
      ll16[q] = f2bf(va16[q] - bf2f(hh16[q]));
    }
#pragma unroll
    for (int q4 = 0; q4 < 4; q4++) {
      float4 fv = {va16[q4 * 4], va16[q4 * 4 + 1], va16[q4 * 4 + 2], va16[q4 * 4 + 3]};
      *(float4*)&hhat[base + q4 * 4] = fv;
    }
    uint4 ph0 = {(unsigned)hh16[0] | ((unsigned)hh16[1] << 16), (unsigned)hh16[2] | ((unsigned)hh16[3] << 16),
                 (unsigned)hh16[4] | ((unsigned)hh16[5] << 16), (unsigned)hh16[6] | ((unsigned)hh16[7] << 16)};
    uint4 ph1 = {(unsigned)hh16[8] | ((unsigned)hh16[9] << 16), (unsigned)hh16[10] | ((unsigned)hh16[11] << 16),
                 (unsigned)hh16[12] | ((unsigned)hh16[13] << 16), (unsigned)hh16[14] | ((unsigned)hh16[15] << 16)};
    uint4 pl0 = {(unsigned)ll16[0] | ((unsigned)ll16[1] << 16), (unsigned)ll16[2] | ((unsigned)ll16[3] << 16),
                 (unsigned)ll16[4] | ((unsigned)ll16[5] << 16), (unsigned)ll16[6] | ((unsigned)ll16[7] << 16)};
    uint4 pl1 = {(unsigned)ll16[8] | ((unsigned)ll16[9] << 16), (unsigned)ll16[10] | ((unsigned)ll16[11] << 16),
                 (unsigned)ll16[12] | ((unsigned)ll16[13] << 16), (unsigned)ll16[14] | ((unsigned)ll16[15] << 16)};
    *(uint4*)&hhi[base] = ph0; *(uint4*)&hhi[base + 8] = ph1;
    *(uint4*)&hlo[base] = pl0; *(uint4*)&hlo[base + 8] = pl1;
    if ((tid & 7) == 0) diagv[bm + row] = dg;
  }
  LOAD_W(W_psf);
  __syncthreads();
  GEMM32(acc);  // out_ps (pre-bias)
#pragma unroll
  for (int nt = 0; nt < 4; nt++) {
    int col = ch2 + nt * 16 + l15;
    float bv = b_psf[col];
#pragma unroll
    for (int rg = 0; rg < 4; rg++) {
      int row = rt + quad * 4 + rg;
      size_t off = (size_t)(bm + row) * 128 + col;
      all_info[off] = lrelu(acc[nt][rg] + bv);
    }
  }
}

// hs tail: hs_pre = (sum_z partialU)/lsum; h_shared = lin(hs_pre,W_hs);
// all = all_info + lrelu(lin(h_shared,W_hsf)); indiv = h - lin(h_shared,W_hsb);
// all += lrelu(lin(indiv,W_in)); out = all @ W_out + b.
__global__ __launch_bounds__(256) void k_hs_tail(
    const float* __restrict__ partial, const float* __restrict__ plsum, int zcnt,
    const float* __restrict__ hbuf, const float* __restrict__ all_info,
    const float* __restrict__ W_hs, const float* __restrict__ b_hs,
    const float* __restrict__ W_hsf, const float* __restrict__ b_hsf,
    const float* __restrict__ W_hsb, const float* __restrict__ b_hsb,
    const float* __restrict__ W_in, const float* __restrict__ b_in,
    const float* __restrict__ W_out, const float* __restrict__ b_out,
    float* __restrict__ out) {
  __shared__ __align__(16) unsigned short sWh[128 * WP];
  __shared__ __align__(16) unsigned short sWl[128 * WP];
  __shared__ __align__(16) unsigned short sAh[32 * WP];
  __shared__ __align__(16) unsigned short sAl[32 * WP];
  __shared__ __align__(16) float sF[32][132];
  int tid = threadIdx.x;
  int bm = blockIdx.x * 32;
  int lane = tid & 63, w = tid >> 6;
  int rt = (w & 1) * 16, ch2 = (w >> 1) * 64;
  int l15 = lane & 15, quad = lane >> 4;
  f32x4 zero = {0.f, 0.f, 0.f, 0.f};
  f32x4 acc[4];
  float allv[4][4];

  // stage hs_pre tile: sum of split-KV partials / total lsum
  {
    int row = tid >> 3, c0 = (tid & 7) * 16;
    float d = 0.f;
    for (int z = 0; z < zcnt; z++) d += plsum[(size_t)z * N + bm + row];
    float sc = 1.f / d;
    size_t off0 = (size_t)(bm + row) * 128 + c0;
#pragma unroll
    for (int q = 0; q < 4; q++) {
      float vv[4] = {0.f, 0.f, 0.f, 0.f};
      for (int z = 0; z < zcnt; z++) {
        float4 v = *(const float4*)&partial[(size_t)z * N * H + off0 + q * 4];
        vv[0] += v.x; vv[1] += v.y; vv[2] += v.z; vv[3] += v.w;
      }
#pragma unroll
      for (int c = 0; c < 4; c++) {
        float val = vv[c] * sc;
        unsigned short hh = f2bf(val);
        sAh[row * WP + c0 + q * 4 + c] = hh;
        sAl[row * WP + c0 + q * 4 + c] = f2bf(val - bf2f(hh));
      }
    }
  }
  LOAD_W(W_hs);
  __syncthreads();
  GEMM32(acc);  // h_shared (pre-bias)
  __syncthreads();
#pragma unroll
  for (int nt = 0; nt < 4; nt++) {
    int col = ch2 + nt * 16 + l15;
    float bv = b_hs[col];
#pragma unroll
    for (int rg = 0; rg < 4; rg++) {
      int row = rt + quad * 4 + rg;
      float v = acc[nt][rg] + bv;
      unsigned short hh = f2bf(v);
      sAh[row * WP + col] = hh;
      sAl[row * WP + col] = f2bf(v - bf2f(hh));
    }
  }
  LOAD_W(W_hsf);
  __syncthreads();
  GEMM32(acc);  // out_hs (pre-bias)
#pragma unroll
  for (int nt = 0; nt < 4; nt++) {
    int col = ch2 + nt * 16 + l15;
    float bv = b_hsf[col];
#pragma unroll
    for (int rg = 0; rg < 4; rg++) {
      int row = rt + quad * 4 + rg;
      size_t off = (size_t)(bm + row) * 128 + col;
      allv[nt][rg] = all_info[off] + lrelu(acc[nt][rg] + bv);
    }
  }
  __syncthreads();
  LOAD_W(W_hsb);
  __syncthreads();
  GEMM32(acc);  // h_back (pre-bias)
  float iv[4][4];
#pragma unroll
  for (int nt = 0; nt < 4; nt++) {
    int col = ch2 + nt * 16 + l15;
    float bv = b_hsb[col];
#pragma unroll
    for (int rg = 0; rg < 4; rg++) {
      int row = rt + quad * 4 + rg;
      size_t off = (size_t)(bm + row) * 128 + col;
      iv[nt][rg] = hbuf[off] - (acc[nt][rg] + bv);
    }
  }
  __syncthreads();
#pragma unroll
  for (int nt = 0; nt < 4; nt++) {
    int col = ch2 + nt * 16 + l15;
#pragma unroll
    for (int rg = 0; rg < 4; rg++) {
      int row = rt + quad * 4 + rg;
      unsigned short hh = f2bf(iv[nt][rg]);
      sAh[row * WP + col] = hh;
      sAl[row * WP + col] = f2bf(iv[nt][rg] - bf2f(hh));
    }
  }
  LOAD_W(W_in);
  __syncthreads();
  GEMM32(acc);  // out_indi (pre-bias)
#pragma unroll
  for (int nt = 0; nt < 4; nt++) {
    int col = ch2 + nt * 16 + l15;
    float bv = b_in[col];
#pragma unroll
    for (int rg = 0; rg < 4; rg++) {
      int row = rt + quad * 4 + rg;
      allv[nt][rg] += lrelu(acc[nt][rg] + bv);
      sF[row][col] = allv[nt][rg];
    }
  }
  __syncthreads();
  {
    int row = tid >> 3, c0 = (tid & 7) * 16;
    float s = 0.f;
#pragma unroll
    for (int q = 0; q < 16; q++) s += sF[row][c0 + q] * W_out[c0 + q];
    s += __shfl_xor(s, 1);
    s += __shfl_xor(s, 2);
    s += __shfl_xor(s, 4);
    if ((tid & 7) == 0) out[bm + row] = s + b_out[0];
  }
}

// ---------------- launch ----------------

extern "C" void kernel_launch(void* const* d_in, const int* in_sizes, int n_in,
                              void* d_out, int out_size, void* d_ws, size_t ws_size,
                              hipStream_t stream) {
  (void)in_sizes; (void)n_in; (void)out_size; (void)ws_size;
  const float* x   = (const float*)d_in[0];
  const float* cm  = (const float*)d_in[1];
  const float* mv  = (const float*)d_in[2];
  const float* W_ps = (const float*)d_in[3],  *b_ps = (const float*)d_in[4];
  const float* W_psf = (const float*)d_in[5], *b_psf = (const float*)d_in[6];
  const float* W_psb = (const float*)d_in[7], *b_psb = (const float*)d_in[8];
  const float* W_hs = (const float*)d_in[9],  *b_hs = (const float*)d_in[10];
  const float* W_hsf = (const float*)d_in[11], *b_hsf = (const float*)d_in[12];
  const float* W_hsb = (const float*)d_in[13], *b_hsb = (const float*)d_in[14];
  const float* W_in = (const float*)d_in[15], *b_in = (const float*)d_in[16];
  const float* W_out = (const float*)d_in[17], *b_out = (const float*)d_in[18];
  float* out = (float*)d_out;

  float* W = (float*)d_ws;
  size_t o = 0;
  auto alloc = [&](size_t n) { float* p = W + o; o += n; return p; };
  float* colsum_c = alloc(C);
  float* colmax   = alloc(C);
  float* colsumexp= alloc(C);
  float* valid1   = alloc(C);
  float* hnorm_ps = alloc(C);
  float* xnorm    = alloc(N);
  float* diagv    = alloc(N);
  float* colsum_m = alloc(N);
  float* valid2f  = alloc(N);
  float* plsum    = alloc((size_t)8 * N);
  float* hidden1  = alloc((size_t)C * H);
  float* hidden_ps= alloc((size_t)C * H);
  float* scores   = alloc((size_t)N * C);
  float* all_info = alloc((size_t)N * H);
  float* hbuf     = alloc((size_t)N * H);   // h
  float* hhat     = alloc((size_t)N * H);
  float* hidden2  = alloc((size_t)N * H);
  unsigned short* xhi    = (unsigned short*)alloc((size_t)N * H / 2);
  unsigned short* xlo    = (unsigned short*)alloc((size_t)N * H / 2);
  unsigned short* hhathi = (unsigned short*)alloc((size_t)N * H / 2);
  unsigned short* hhatlo = (unsigned short*)alloc((size_t)N * H / 2);
  unsigned short* h2hi   = (unsigned short*)alloc((size_t)N * H / 2);
  unsigned short* h2lo   = (unsigned short*)alloc((size_t)N * H / 2);
  unsigned short* h1hi   = (unsigned short*)alloc((size_t)C * H / 2);
  unsigned short* h1lo   = (unsigned short*)alloc((size_t)C * H / 2);
  unsigned short* hpshi  = (unsigned short*)alloc((size_t)C * H / 2);
  unsigned short* hpslo  = (unsigned short*)alloc((size_t)C * H / 2);
  unsigned short* cshi   = (unsigned short*)alloc((size_t)N * C / 2);
  unsigned short* cslo   = (unsigned short*)alloc((size_t)N * C / 2);
  unsigned short* hpst_hi= (unsigned short*)alloc((size_t)H * C / 2);
  unsigned short* hpst_lo= (unsigned short*)alloc((size_t)H * C / 2);
  unsigned short* h2t_hi = (unsigned short*)alloc((size_t)H * N / 2);
  unsigned short* h2t_lo = (unsigned short*)alloc((size_t)H * N / 2);
  unsigned short* xt_hi  = (unsigned short*)alloc((size_t)H * N / 2);
  unsigned short* xt_lo  = (unsigned short*)alloc((size_t)H * N / 2);
  float2* cand    = (float2*)alloc((size_t)N * 128 * 5 * 2);
  float* partial  = W + o;
  const int Z = 8;        // flash split-KV (8*N*128 fp32)
  const int ZG = 64;      // genA split-K (64*C*128 fp32); same region
  const int ZK = 8;       // cs-GEMM split-K (8*N*128 fp32); same region

  dim3 blk(256);
  // --- ps branch ---
  k_xprep<<<dim3(N / 32), blk, 0, stream>>>(x, xhi, xlo, xnorm, xt_hi, xt_lo,
                                            hidden2, colsum_c, colsum_m);
  k_colsum_s2c<<<dim3(C / 64, 16), dim3(64), 0, stream>>>(cm, mv, colsum_c);
  k_mfma_genA<1><<<dim3(1, C / 128, ZG), blk, 0, stream>>>(
      cm, mv, colsum_c, nullptr, xt_hi, xt_lo, partial, N / ZG);
  k_reduce<<<dim3(C * H / 4 / 256), blk, 0, stream>>>(
      partial, hidden1, ZG, (size_t)C * H, (size_t)C * H / 4, nullptr,
      h1hi, h1lo, nullptr, valid1);
  k_mfma_nt<<<dim3(C / 128, N / 64), blk, 0, stream>>>(
      xhi, xlo, h1hi, h1lo, scores, C);
  k_colstats<<<dim3(C), blk, 0, stream>>>(scores, colmax, colsumexp);
  k_mfma_genA<2><<<dim3(1, C / 128, ZG), blk, 0, stream>>>(
      scores, nullptr, colmax, colsumexp, xt_hi, xt_lo, partial, N / ZG);
  k_reduce<<<dim3(C * H / 4 / 256), blk, 0, stream>>>(
      partial, hidden_ps, ZG, (size_t)C * H, (size_t)C * H / 4, valid1,
      hpshi, hpslo, hnorm_ps, nullptr);
  k_mfma_nt<<<dim3(C / 128, N / 64), blk, 0, stream>>>(
      xhi, xlo, hpshi, hpslo, scores, C);
  k_cs_softmax<<<dim3(N), blk, 0, stream>>>(scores, xnorm, hnorm_ps, valid1,
                                            cshi, cslo);
  k_tsplit<<<dim3(C / 32), blk, 0, stream>>>(hidden_ps, hpst_hi, hpst_lo, C);
  k_mfma_kn<<<dim3(1, N / 128, ZK), blk, 0, stream>>>(
      cshi, cslo, hpst_hi, hpst_lo, partial, C, C / ZK);
  k_ps_tail<<<dim3(N / 32), blk, 0, stream>>>(
      partial, ZK, x, W_ps, b_ps, W_psb, b_psb, W_psf, b_psf,
      hbuf, hhat, hhathi, hhatlo, diagv, all_info);
  // --- hs branch ---
  k_snt<<<dim3(N / 128, N / 128), dim3(512), 0, stream>>>(
      hhathi, hhatlo, cand);
  k_rowtop2s<<<dim3(N / 4), blk, 0, stream>>>(cand, hhat, hbuf, hidden2,
                                              colsum_m);
  k_fin2t<<<dim3(N / 32), blk, 0, stream>>>(hbuf, diagv, colsum_m, hidden2,
                                            h2hi, h2lo, valid2f, h2t_hi, h2t_lo);
  k_flash<<<dim3(Z, N / 128), dim3(512), 0, stream>>>(
      hhathi, hhatlo, h2hi, h2lo, h2t_hi, h2t_lo, valid2f, partial, plsum,
      N / Z);
  k_hs_tail<<<dim3(N / 32), blk, 0, stream>>>(
      partial, plsum, Z, hbuf, all_info, W_hs, b_hs, W_hsf, b_hsf, W_hsb, b_hsb,
      W_in, b_in, W_out, b_out, out);
}